// Round 1
// baseline (5015.748 us; speedup 1.0000x reference)
//
#include <hip/hip_runtime.h>
#include <cfloat>
#include <cmath>

#define T_    2048
#define HID_  2048
#define QKVN_ 2112
#define QLR_  1536
#define KVLR_ 512
#define ROPE_ 64
#define NOPE_ 128
#define QKD_  192
#define VD_   128
#define H_    16
#define IDXH_ 32
#define IDXD_ 128
#define TOPK_ 512
#define EPS_  1e-6f
#define SCALING_ 0.07216878364870323f   // 192^-0.5

// ---------------------------------------------------------------- GEMM f32
// C[M,N] = A[M,K] @ B[K,N], row-major, 64x64 tile, BK=16, 4x4 per thread.
__global__ __launch_bounds__(256) void gemm_f32_kernel(
    const float* __restrict__ A, const float* __restrict__ B,
    float* __restrict__ C, int M, int N, int K) {
  __shared__ float As[16][64];
  __shared__ float Bs[16][64];
  const int tid = threadIdx.x;
  const int bm = blockIdx.y * 64;
  const int bn = blockIdx.x * 64;
  const int trow = tid / 16;       // 0..15
  const int tcol = tid % 16;       // 0..15
  float acc[4][4] = {};
  for (int k0 = 0; k0 < K; k0 += 16) {
    for (int idx = tid; idx < 64 * 16; idx += 256) {
      int m = idx / 16, kk = idx % 16;
      int gm = bm + m, gk = k0 + kk;
      As[kk][m] = (gm < M && gk < K) ? A[(size_t)gm * K + gk] : 0.f;
    }
    for (int idx = tid; idx < 16 * 64; idx += 256) {
      int kk = idx / 64, n = idx % 64;
      int gk = k0 + kk, gn = bn + n;
      Bs[kk][n] = (gk < K && gn < N) ? B[(size_t)gk * N + gn] : 0.f;
    }
    __syncthreads();
#pragma unroll
    for (int kk = 0; kk < 16; ++kk) {
      float4 a4 = *(const float4*)&As[kk][trow * 4];
      float4 b4 = *(const float4*)&Bs[kk][tcol * 4];
      float av[4] = {a4.x, a4.y, a4.z, a4.w};
      float bv[4] = {b4.x, b4.y, b4.z, b4.w};
#pragma unroll
      for (int i = 0; i < 4; ++i)
#pragma unroll
        for (int j = 0; j < 4; ++j) acc[i][j] += av[i] * bv[j];
    }
    __syncthreads();
  }
#pragma unroll
  for (int i = 0; i < 4; ++i) {
    int gm = bm + trow * 4 + i;
    if (gm >= M) continue;
#pragma unroll
    for (int j = 0; j < 4; ++j) {
      int gn = bn + tcol * 4 + j;
      if (gn < N) C[(size_t)gm * N + gn] = acc[i][j];
    }
  }
}

// ---------------------------------------------------------------- RMS norms
__global__ __launch_bounds__(256) void rmsnorm_kernel(
    const float* __restrict__ qkv, const float* __restrict__ qw,
    const float* __restrict__ kvw, float* __restrict__ q_cn,
    float* __restrict__ kv_cn) {
  const int t = blockIdx.x, tid = threadIdx.x;
  const float* row = qkv + (size_t)t * QKVN_;
  __shared__ float red[256];
  float ss = 0.f;
  for (int i = tid; i < QLR_; i += 256) { float v = row[i]; ss += v * v; }
  red[tid] = ss; __syncthreads();
  for (int s = 128; s; s >>= 1) { if (tid < s) red[tid] += red[tid + s]; __syncthreads(); }
  float scl = 1.0f / sqrtf(red[0] / (float)QLR_ + EPS_);
  for (int i = tid; i < QLR_; i += 256)
    q_cn[(size_t)t * QLR_ + i] = row[i] * scl * qw[i];
  __syncthreads();
  ss = 0.f;
  for (int i = tid; i < KVLR_; i += 256) { float v = row[QLR_ + i]; ss += v * v; }
  red[tid] = ss; __syncthreads();
  for (int s = 128; s; s >>= 1) { if (tid < s) red[tid] += red[tid + s]; __syncthreads(); }
  scl = 1.0f / sqrtf(red[0] / (float)KVLR_ + EPS_);
  for (int i = tid; i < KVLR_; i += 256)
    kv_cn[(size_t)t * KVLR_ + i] = row[QLR_ + i] * scl * kvw[i];
}

// ---------------------------------------------------------------- RoPE helpers
__device__ __forceinline__ void rope_pair(float pos, int j, float& x0, float& x1) {
  float inv = powf(10000.f, -(float)j * (1.f / 32.f));
  float f = pos * inv;
  float c = cosf(f), s = sinf(f);
  float a = x0, b = x1;
  x0 = a * c - b * s;
  x1 = a * s + b * c;
}

// rope first 64 dims of each of 32 idx heads, in place. qi: (T, 32*128)
__global__ __launch_bounds__(256) void rope_qi_kernel(float* __restrict__ qi) {
  const int t = blockIdx.x, tid = threadIdx.x;
  float pos = (float)t;
  for (int idx = tid; idx < IDXH_ * 32; idx += 256) {
    int hh = idx / 32, j = idx % 32;
    float* p = qi + (size_t)t * (IDXH_ * IDXD_) + hh * IDXD_;
    rope_pair(pos, j, p[2 * j], p[2 * j + 1]);
  }
}

// rope dims [128,192) of each of 16 heads, in place. qfull: (T, 16*192)
__global__ __launch_bounds__(256) void rope_q_kernel(float* __restrict__ qfull) {
  const int t = blockIdx.x, tid = threadIdx.x;
  float pos = (float)t;
  for (int idx = tid; idx < H_ * 32; idx += 256) {
    int hh = idx / 32, j = idx % 32;
    float* p = qfull + (size_t)t * (H_ * QKD_) + hh * QKD_ + NOPE_;
    rope_pair(pos, j, p[2 * j], p[2 * j + 1]);
  }
}

// k_pe (cols 2048..2111 of qkv) -> roped kper (T,64)
__global__ __launch_bounds__(64) void rope_kpe_kernel(
    const float* __restrict__ qkv, float* __restrict__ kper) {
  const int t = blockIdx.x, tid = threadIdx.x;
  if (tid >= 32) return;
  float pos = (float)t;
  const float* p = qkv + (size_t)t * QKVN_ + (QLR_ + KVLR_);
  float x0 = p[2 * tid], x1 = p[2 * tid + 1];
  rope_pair(pos, tid, x0, x1);
  kper[(size_t)t * ROPE_ + 2 * tid] = x0;
  kper[(size_t)t * ROPE_ + 2 * tid + 1] = x1;
}

// ---------------------------------------------------------------- ki: LN + rope
__global__ __launch_bounds__(128) void ki_ln_rope_kernel(
    float* __restrict__ ki, const float* __restrict__ gamma,
    const float* __restrict__ beta) {
  const int t = blockIdx.x, tid = threadIdx.x;  // 128 threads
  __shared__ float x[128];
  __shared__ float red[128];
  float v = ki[(size_t)t * IDXD_ + tid];
  red[tid] = v; __syncthreads();
  for (int s = 64; s; s >>= 1) { if (tid < s) red[tid] += red[tid + s]; __syncthreads(); }
  float mu = red[0] / 128.f;
  __syncthreads();
  float d = v - mu;
  red[tid] = d * d; __syncthreads();
  for (int s = 64; s; s >>= 1) { if (tid < s) red[tid] += red[tid + s]; __syncthreads(); }
  float var = red[0] / 128.f;
  float y = d * (1.0f / sqrtf(var + EPS_)) * gamma[tid] + beta[tid];
  x[tid] = y; __syncthreads();
  float pos = (float)t;
  if (tid < 32) {
    float x0 = x[2 * tid], x1 = x[2 * tid + 1];
    rope_pair(pos, tid, x0, x1);
    ki[(size_t)t * IDXD_ + 2 * tid] = x0;
    ki[(size_t)t * IDXD_ + 2 * tid + 1] = x1;
  } else if (tid >= 64) {
    ki[(size_t)t * IDXD_ + tid] = y;
  }
}

// ---------------------------------------------------------------- w epilogue
__global__ __launch_bounds__(256) void w_epi_kernel(
    float* __restrict__ wgt, const float* __restrict__ b) {
  int idx = blockIdx.x * 256 + threadIdx.x;
  if (idx < T_ * IDXH_)
    wgt[idx] = (wgt[idx] + b[idx & 31]) * 0.015625f;  // 128^-.5 * 32^-.5
}

// ---------------------------------------------------------------- indexer score
// score[t,s] = sum_h w[t,h]*relu(qi[t,h,:]·ki[s,:]) for s<=t else -FLT_MAX
__global__ __launch_bounds__(256) void score_kernel(
    const float* __restrict__ qi, const float* __restrict__ ki,
    const float* __restrict__ wgt, float* __restrict__ score) {
  const int s0 = blockIdx.x * 64;
  const int t0 = blockIdx.y * 16;
  const int tid = threadIdx.x;
  if (s0 > t0 + 15) {  // entirely above diagonal
    for (int idx = tid; idx < 16 * 64; idx += 256) {
      int tt = idx / 64, ss = idx % 64;
      score[(size_t)(t0 + tt) * T_ + s0 + ss] = -FLT_MAX;
    }
    return;
  }
  __shared__ float kis[64][132];
  __shared__ float qis[16][132];
  __shared__ float wts[16][32];
  for (int idx = tid; idx < 64 * 128; idx += 256) {
    int r = idx / 128, c = idx % 128;
    kis[r][c] = ki[(size_t)(s0 + r) * IDXD_ + c];
  }
  for (int idx = tid; idx < 16 * 32; idx += 256)
    wts[idx / 32][idx % 32] = wgt[(size_t)(t0 + idx / 32) * IDXH_ + idx % 32];

  const int tt = tid / 16;       // row within tile
  const int tcol = tid % 16;     // col group; cols tcol+16j
  float acc[4] = {0.f, 0.f, 0.f, 0.f};
  for (int h = 0; h < IDXH_; ++h) {
    __syncthreads();
    for (int idx = tid; idx < 16 * 128; idx += 256) {
      int r = idx / 128, c = idx % 128;
      qis[r][c] = qi[(size_t)(t0 + r) * (IDXH_ * IDXD_) + h * IDXD_ + c];
    }
    __syncthreads();
    float d[4] = {0.f, 0.f, 0.f, 0.f};
    for (int c = 0; c < 128; c += 4) {
      float4 qv = *(const float4*)&qis[tt][c];
#pragma unroll
      for (int j = 0; j < 4; ++j) {
        float4 kvv = *(const float4*)&kis[tcol + 16 * j][c];
        d[j] += qv.x * kvv.x + qv.y * kvv.y + qv.z * kvv.z + qv.w * kvv.w;
      }
    }
    float wv = wts[tt][h];
#pragma unroll
    for (int j = 0; j < 4; ++j) acc[j] += wv * fmaxf(d[j], 0.f);
  }
  const int gt = t0 + tt;
#pragma unroll
  for (int j = 0; j < 4; ++j) {
    int gs = s0 + tcol + 16 * j;
    score[(size_t)gt * T_ + gs] = (gs <= gt) ? acc[j] : -FLT_MAX;
  }
}

// ---------------------------------------------------------------- top-k (exact)
__global__ __launch_bounds__(256) void topk_kernel(
    const float* __restrict__ score, int* __restrict__ selidx,
    int* __restrict__ selcnt) {
  const int t = blockIdx.x;
  const int L = t + 1;
  const int tid = threadIdx.x;
  if (L <= TOPK_) {
    for (int j = tid; j < TOPK_; j += 256)
      selidx[(size_t)t * TOPK_ + j] = (j < L) ? j : 0;
    if (tid == 0) selcnt[t] = L;
    return;
  }
  __shared__ unsigned u[T_];
  __shared__ unsigned hist[16];
  __shared__ unsigned sprefix;
  __shared__ int sk;
  __shared__ int part[256];
  for (int i = tid; i < T_; i += 256) {
    float v = (i < L) ? score[(size_t)t * T_ + i] : -FLT_MAX;
    unsigned b = __float_as_uint(v);
    u[i] = (b & 0x80000000u) ? ~b : (b | 0x80000000u);
  }
  if (tid == 0) { sprefix = 0u; sk = TOPK_; }
  __syncthreads();
  for (int pass = 0; pass < 8; ++pass) {
    const int shift = 28 - 4 * pass;
    if (tid < 16) hist[tid] = 0u;
    __syncthreads();
    unsigned pfx = sprefix;
    for (int i = tid; i < L; i += 256) {
      unsigned val = u[i];
      bool match = (pass == 0) || ((val >> (shift + 4)) == pfx);
      if (match) atomicAdd(&hist[(val >> shift) & 15u], 1u);
    }
    __syncthreads();
    if (tid == 0) {
      int k = sk; unsigned cum = 0u; int bsel = 0;
      for (int bb = 15; bb >= 0; --bb) {
        if (cum + hist[bb] >= (unsigned)k) { bsel = bb; sk = k - (int)cum; break; }
        cum += hist[bb];
      }
      sprefix = (sprefix << 4) | (unsigned)bsel;
    }
    __syncthreads();
  }
  const unsigned thr = sprefix;
  const int kEq = sk;  // #equal-to-thr to take, lowest index first
  const int base = tid * 8;
  // exclusive scan of "== thr" flags (stable tie-break)
  int eqloc[8]; int esum = 0;
  for (int r = 0; r < 8; ++r) {
    int i = base + r;
    int f = (i < L && u[i] == thr) ? 1 : 0;
    eqloc[r] = esum; esum += f;
  }
  part[tid] = esum; __syncthreads();
  for (int off = 1; off < 256; off <<= 1) {
    int v = (tid >= off) ? part[tid - off] : 0;
    __syncthreads();
    part[tid] += v;
    __syncthreads();
  }
  const int ebase = (tid > 0) ? part[tid - 1] : 0;
  __syncthreads();
  // selection + compaction
  int sloc[8], selflag[8]; int ssum = 0;
  for (int r = 0; r < 8; ++r) {
    int i = base + r;
    int f = 0;
    if (i < L) {
      unsigned ui = u[i];
      if (ui > thr) f = 1;
      else if (ui == thr && (ebase + eqloc[r]) < kEq) f = 1;
    }
    selflag[r] = f; sloc[r] = ssum; ssum += f;
  }
  part[tid] = ssum; __syncthreads();
  for (int off = 1; off < 256; off <<= 1) {
    int v = (tid >= off) ? part[tid - off] : 0;
    __syncthreads();
    part[tid] += v;
    __syncthreads();
  }
  const int sbase = (tid > 0) ? part[tid - 1] : 0;
  for (int r = 0; r < 8; ++r)
    if (selflag[r]) selidx[(size_t)t * TOPK_ + sbase + sloc[r]] = base + r;
  if (tid == 0) selcnt[t] = TOPK_;
}

// ---------------------------------------------------------------- attention
// one block per (t, h). gathered keys from selidx.
__global__ __launch_bounds__(256) void attn_kernel(
    const float* __restrict__ qfull, const float* __restrict__ kvb,
    const float* __restrict__ kper, const int* __restrict__ selidx,
    const int* __restrict__ selcnt, float* __restrict__ attno) {
  const int t = blockIdx.x, h = blockIdx.y;
  const int tid = threadIdx.x;
  __shared__ float qs[QKD_];
  __shared__ float logit[TOPK_];
  __shared__ float red[256];
  __shared__ int sidx[TOPK_];
  const int cnt = selcnt[t];
  if (tid < QKD_) qs[tid] = qfull[((size_t)t * H_ + h) * QKD_ + tid];
  for (int j = tid; j < cnt; j += 256) sidx[j] = selidx[(size_t)t * TOPK_ + j];
  __syncthreads();
  const int wave = tid / 64, lane = tid % 64;
  for (int j = wave; j < cnt; j += 4) {
    int s = sidx[j];
    const float* kn = kvb + ((size_t)s * H_ + h) * (NOPE_ + VD_);
    float part = qs[lane] * kn[lane] + qs[64 + lane] * kn[64 + lane] +
                 qs[128 + lane] * kper[(size_t)s * ROPE_ + lane];
#pragma unroll
    for (int off = 32; off; off >>= 1) part += __shfl_xor(part, off);
    if (lane == 0) logit[j] = part * SCALING_;
  }
  __syncthreads();
  float m = -FLT_MAX;
  for (int j = tid; j < cnt; j += 256) m = fmaxf(m, logit[j]);
  red[tid] = m; __syncthreads();
  for (int s = 128; s; s >>= 1) { if (tid < s) red[tid] = fmaxf(red[tid], red[tid + s]); __syncthreads(); }
  m = red[0]; __syncthreads();
  float lsum = 0.f;
  for (int j = tid; j < cnt; j += 256) {
    float e = expf(logit[j] - m);
    logit[j] = e; lsum += e;
  }
  red[tid] = lsum; __syncthreads();
  for (int s = 128; s; s >>= 1) { if (tid < s) red[tid] += red[tid + s]; __syncthreads(); }
  const float inv = 1.f / red[0];
  __syncthreads();
  // PV: two j-halves per output dim
  float accv = 0.f;
  const int halfsel = tid >> 7;
  const int dd = tid & 127;
  for (int j = halfsel; j < cnt; j += 2) {
    int s = sidx[j];
    accv += logit[j] * kvb[((size_t)s * H_ + h) * (NOPE_ + VD_) + NOPE_ + dd];
  }
  red[tid] = accv; __syncthreads();
  if (tid < 128)
    attno[(size_t)t * (H_ * VD_) + h * VD_ + tid] = (red[tid] + red[tid + 128]) * inv;
}

// ---------------------------------------------------------------- launch
extern "C" void kernel_launch(void* const* d_in, const int* in_sizes, int n_in,
                              void* d_out, int out_size, void* d_ws, size_t ws_size,
                              hipStream_t stream) {
  const float* hidden    = (const float*)d_in[1];
  const float* w_qkv_a   = (const float*)d_in[2];
  const float* q_a_ln_w  = (const float*)d_in[3];
  const float* w_qb      = (const float*)d_in[4];
  const float* kv_a_ln_w = (const float*)d_in[5];
  const float* w_kvb     = (const float*)d_in[6];
  const float* w_o       = (const float*)d_in[7];
  const float* w_idx_qb  = (const float*)d_in[8];
  const float* w_idx_k   = (const float*)d_in[9];
  const float* idx_g     = (const float*)d_in[10];
  const float* idx_b     = (const float*)d_in[11];
  const float* w_wproj   = (const float*)d_in[12];
  const float* b_wproj   = (const float*)d_in[13];

  float* ws = (float*)d_ws;
  size_t off = 0;
  auto alloc = [&](size_t n) { float* p = ws + off; off += n; return p; };
  float* qkv   = alloc((size_t)T_ * QKVN_);
  float* q_cn  = alloc((size_t)T_ * QLR_);
  float* kv_cn = alloc((size_t)T_ * KVLR_);
  float* qi    = alloc((size_t)T_ * IDXH_ * IDXD_);
  float* ki    = alloc((size_t)T_ * IDXD_);
  float* wgt   = alloc((size_t)T_ * IDXH_);
  float* score = alloc((size_t)T_ * T_);
  float* qfull = alloc((size_t)T_ * H_ * QKD_);
  float* kvb   = alloc((size_t)T_ * H_ * (NOPE_ + VD_));
  float* kper  = alloc((size_t)T_ * ROPE_);
  float* attno = alloc((size_t)T_ * H_ * VD_);
  int* selidx  = (int*)alloc((size_t)T_ * TOPK_);
  int* selcnt  = (int*)alloc(T_);

  dim3 blk(256);
  auto gg = [](int M, int N) { return dim3((N + 63) / 64, (M + 63) / 64); };

  gemm_f32_kernel<<<gg(T_, QKVN_), blk, 0, stream>>>(hidden, w_qkv_a, qkv, T_, QKVN_, HID_);
  rmsnorm_kernel<<<T_, blk, 0, stream>>>(qkv, q_a_ln_w, kv_a_ln_w, q_cn, kv_cn);
  rope_kpe_kernel<<<T_, 64, 0, stream>>>(qkv, kper);

  gemm_f32_kernel<<<gg(T_, IDXH_ * IDXD_), blk, 0, stream>>>(q_cn, w_idx_qb, qi, T_, IDXH_ * IDXD_, QLR_);
  rope_qi_kernel<<<T_, blk, 0, stream>>>(qi);

  gemm_f32_kernel<<<gg(T_, IDXD_), blk, 0, stream>>>(hidden, w_idx_k, ki, T_, IDXD_, HID_);
  ki_ln_rope_kernel<<<T_, 128, 0, stream>>>(ki, idx_g, idx_b);

  gemm_f32_kernel<<<gg(T_, IDXH_), blk, 0, stream>>>(hidden, w_wproj, wgt, T_, IDXH_, HID_);
  w_epi_kernel<<<(T_ * IDXH_ + 255) / 256, blk, 0, stream>>>(wgt, b_wproj);

  score_kernel<<<dim3(T_ / 64, T_ / 16), blk, 0, stream>>>(qi, ki, wgt, score);
  topk_kernel<<<T_, blk, 0, stream>>>(score, selidx, selcnt);

  gemm_f32_kernel<<<gg(T_, H_ * QKD_), blk, 0, stream>>>(q_cn, w_qb, qfull, T_, H_ * QKD_, QLR_);
  rope_q_kernel<<<T_, blk, 0, stream>>>(qfull);

  gemm_f32_kernel<<<gg(T_, H_ * (NOPE_ + VD_)), blk, 0, stream>>>(kv_cn, w_kvb, kvb, T_, H_ * (NOPE_ + VD_), KVLR_);

  attn_kernel<<<dim3(T_, H_), blk, 0, stream>>>(qfull, kvb, kper, selidx, selcnt, attno);

  gemm_f32_kernel<<<gg(T_, HID_), blk, 0, stream>>>(attno, w_o, (float*)d_out, T_, HID_, H_ * VD_);
}

// Round 4
// 1887.068 us; speedup vs baseline: 2.6580x; 2.6580x over previous
//
#include <hip/hip_runtime.h>
#include <cfloat>
#include <cmath>

#define T_    2048
#define HID_  2048
#define QKVN_ 2112
#define QLR_  1536
#define KVLR_ 512
#define ROPE_ 64
#define NOPE_ 128
#define QKD_  192
#define VD_   128
#define H_    16
#define IDXH_ 32
#define IDXD_ 128
#define TOPK_ 512
#define EPS_  1e-6f
#define SCALING_ 0.07216878364870323f   // 192^-0.5

typedef unsigned int u32;
typedef unsigned short u16;
typedef __bf16 bf16x8 __attribute__((ext_vector_type(8)));
typedef _Float16 f16;
typedef f16 f16x8 __attribute__((ext_vector_type(8)));
typedef float f32x4 __attribute__((ext_vector_type(4)));

__device__ __forceinline__ u16 f2bf(float x) {
  u32 u = __float_as_uint(x);
  u32 r = (u + 0x7fffu + ((u >> 16) & 1u)) >> 16;
  return (u16)r;
}
__device__ __forceinline__ float bf2f(u16 h) { return __uint_as_float(((u32)h) << 16); }
__device__ __forceinline__ u32 pack2(float a, float b) { return (u32)f2bf(a) | ((u32)f2bf(b) << 16); }
__device__ __forceinline__ bf16x8 ld8(const void* p) { return *(const bf16x8*)p; }
__device__ __forceinline__ f32x4 mfma16(bf16x8 a, bf16x8 b, f32x4 c) {
  return __builtin_amdgcn_mfma_f32_16x16x32_bf16(a, b, c, 0, 0, 0);
}
// ---- fp16 helpers (strict path: hi+lo split covers ~22 mantissa bits)
__device__ __forceinline__ u16 hbits(f16 h) { union { f16 h; u16 u; } c; c.h = h; return c.u; }
__device__ __forceinline__ u32 hpack(f16 a, f16 b) { return (u32)hbits(a) | ((u32)hbits(b) << 16); }
__device__ __forceinline__ f16x8 ldh8(const void* p) { return *(const f16x8*)p; }
__device__ __forceinline__ f32x4 mfmah(f16x8 a, f16x8 b, f32x4 c) {
  return __builtin_amdgcn_mfma_f32_16x16x32_f16(a, b, c, 0, 0, 0);
}

// ---------------------------------------------------------------- transposes / converts
__global__ __launch_bounds__(256) void transpose_f32_k(
    const float* __restrict__ in, float* __restrict__ out, int K, int N) {
  __shared__ float t[64][65];
  int k0 = blockIdx.y * 64, n0 = blockIdx.x * 64;
  for (int j = 0; j < 16; ++j) {
    int u = threadIdx.x + 256 * j; int r = u >> 6, c = u & 63;
    t[r][c] = (k0 + r < K && n0 + c < N) ? in[(size_t)(k0 + r) * N + n0 + c] : 0.f;
  }
  __syncthreads();
  for (int j = 0; j < 16; ++j) {
    int u = threadIdx.x + 256 * j; int r = u >> 6, c = u & 63;
    if (n0 + r < N && k0 + c < K) out[(size_t)(n0 + r) * K + k0 + c] = t[c][r];
  }
}

__global__ __launch_bounds__(256) void transpose_bf16_k(
    const float* __restrict__ in, u16* __restrict__ out, int K, int N) {
  __shared__ float t[64][65];
  int k0 = blockIdx.y * 64, n0 = blockIdx.x * 64;
  for (int j = 0; j < 16; ++j) {
    int u = threadIdx.x + 256 * j; int r = u >> 6, c = u & 63;
    t[r][c] = (k0 + r < K && n0 + c < N) ? in[(size_t)(k0 + r) * N + n0 + c] : 0.f;
  }
  __syncthreads();
  for (int j = 0; j < 16; ++j) {
    int u = threadIdx.x + 256 * j; int r = u >> 6, c = u & 63;
    if (n0 + r < N && k0 + c < K) out[(size_t)(n0 + r) * K + k0 + c] = f2bf(t[c][r]);
  }
}

__global__ __launch_bounds__(256) void conv_bf16_k(
    const float* __restrict__ in, u16* __restrict__ out, long n) {
  for (long i = ((long)blockIdx.x * 256 + threadIdx.x) * 4; i < n; i += (long)gridDim.x * 1024) {
    float4 v = *(const float4*)(in + i);
    u32 a = pack2(v.x, v.y), b = pack2(v.z, v.w);
    *(u32*)(out + i) = a; *(u32*)(out + i + 2) = b;
  }
}

// ---------------------------------------------------------------- strict split-f16 GEMM
// C[M,N] f32 = A[M,K] f32 @ Bt[N,K]^T f32 with hi/lo f16 split (3-term MFMA).
__global__ __launch_bounds__(256) void gemm_split(
    const float* __restrict__ A, int lda,
    const float* __restrict__ Bt, int ldb,
    float* __restrict__ C, int ldc, int N, int K) {
  __shared__ u32 Ah[128][20], Al[128][20], Bh[128][20], Bl[128][20];
  const int tid = threadIdx.x;
  const int bm = blockIdx.y * 128, bn = blockIdx.x * 128;
  const int wid = tid >> 6, lane = tid & 63, wr = wid >> 1, wc = wid & 1;
  const int lr = lane & 15, lg = lane >> 4;
  f32x4 acc[4][4] = {};
  for (int k0 = 0; k0 < K; k0 += 32) {
#pragma unroll
    for (int j = 0; j < 4; ++j) {
      int u = tid + 256 * j; int row = u >> 3, p = u & 7;
      float4 v = *(const float4*)(A + (size_t)(bm + row) * lda + k0 + p * 4);
      f16 h0 = (f16)v.x, h1 = (f16)v.y, h2 = (f16)v.z, h3 = (f16)v.w;
      Ah[row][p * 2] = hpack(h0, h1);
      Ah[row][p * 2 + 1] = hpack(h2, h3);
      Al[row][p * 2] = hpack((f16)(v.x - (float)h0), (f16)(v.y - (float)h1));
      Al[row][p * 2 + 1] = hpack((f16)(v.z - (float)h2), (f16)(v.w - (float)h3));
    }
#pragma unroll
    for (int j = 0; j < 4; ++j) {
      int u = tid + 256 * j; int row = u >> 3, p = u & 7;
      float4 v = make_float4(0.f, 0.f, 0.f, 0.f);
      if (bn + row < N) v = *(const float4*)(Bt + (size_t)(bn + row) * ldb + k0 + p * 4);
      f16 h0 = (f16)v.x, h1 = (f16)v.y, h2 = (f16)v.z, h3 = (f16)v.w;
      Bh[row][p * 2] = hpack(h0, h1);
      Bh[row][p * 2 + 1] = hpack(h2, h3);
      Bl[row][p * 2] = hpack((f16)(v.x - (float)h0), (f16)(v.y - (float)h1));
      Bl[row][p * 2 + 1] = hpack((f16)(v.z - (float)h2), (f16)(v.w - (float)h3));
    }
    __syncthreads();
    f16x8 ah[4], al[4], bh[4], bl[4];
#pragma unroll
    for (int i = 0; i < 4; ++i) {
      ah[i] = ldh8(&Ah[wr * 64 + i * 16 + lr][lg * 4]);
      al[i] = ldh8(&Al[wr * 64 + i * 16 + lr][lg * 4]);
      bh[i] = ldh8(&Bh[wc * 64 + i * 16 + lr][lg * 4]);
      bl[i] = ldh8(&Bl[wc * 64 + i * 16 + lr][lg * 4]);
    }
#pragma unroll
    for (int i = 0; i < 4; ++i)
#pragma unroll
      for (int jn = 0; jn < 4; ++jn) {
        acc[i][jn] = mfmah(ah[i], bh[jn], acc[i][jn]);
        acc[i][jn] = mfmah(ah[i], bl[jn], acc[i][jn]);
        acc[i][jn] = mfmah(al[i], bh[jn], acc[i][jn]);
      }
    __syncthreads();
  }
#pragma unroll
  for (int i = 0; i < 4; ++i)
#pragma unroll
    for (int jn = 0; jn < 4; ++jn)
#pragma unroll
      for (int j = 0; j < 4; ++j) {
        int row = bm + wr * 64 + i * 16 + lg * 4 + j;
        int col = bn + wc * 64 + jn * 16 + lr;
        if (col < N) C[(size_t)row * ldc + col] = acc[i][jn][j];
      }
}

// ---------------------------------------------------------------- tolerant bf16 GEMM
template <int AF32, int CBF16>
__global__ __launch_bounds__(256) void gemm_t(
    const void* __restrict__ Ap, int lda, long aoz,
    const u16* __restrict__ Bt, int ldb, long boz,
    void* __restrict__ Cp, int ldc, long coz, int N, int K) {
  __shared__ u32 As[128][20], Bs[128][20];
  const int tid = threadIdx.x;
  const int z = blockIdx.z;
  const int bm = blockIdx.y * 128, bn = blockIdx.x * 128;
  const int wid = tid >> 6, lane = tid & 63, wr = wid >> 1, wc = wid & 1;
  const int lr = lane & 15, lg = lane >> 4;
  f32x4 acc[4][4] = {};
  for (int k0 = 0; k0 < K; k0 += 32) {
    if (AF32) {
      const float* A = (const float*)Ap + aoz * z;
#pragma unroll
      for (int j = 0; j < 4; ++j) {
        int u = tid + 256 * j; int row = u >> 3, p = u & 7;
        float4 v = *(const float4*)(A + (size_t)(bm + row) * lda + k0 + p * 4);
        As[row][p * 2] = pack2(v.x, v.y);
        As[row][p * 2 + 1] = pack2(v.z, v.w);
      }
    } else {
      const u16* A = (const u16*)Ap + aoz * z;
#pragma unroll
      for (int j = 0; j < 2; ++j) {
        int u = tid + 256 * j; int row = u >> 2, p = u & 3;
        uint4 v = *(const uint4*)(A + (size_t)(bm + row) * lda + k0 + p * 8);
        *(uint4*)&As[row][p * 4] = v;
      }
    }
#pragma unroll
    for (int j = 0; j < 2; ++j) {
      int u = tid + 256 * j; int row = u >> 2, p = u & 3;
      uint4 v = make_uint4(0, 0, 0, 0);
      if (bn + row < N) v = *(const uint4*)(Bt + boz * z + (size_t)(bn + row) * ldb + k0 + p * 8);
      *(uint4*)&Bs[row][p * 4] = v;
    }
    __syncthreads();
    bf16x8 af[4], bf[4];
#pragma unroll
    for (int i = 0; i < 4; ++i) {
      af[i] = ld8(&As[wr * 64 + i * 16 + lr][lg * 4]);
      bf[i] = ld8(&Bs[wc * 64 + i * 16 + lr][lg * 4]);
    }
#pragma unroll
    for (int i = 0; i < 4; ++i)
#pragma unroll
      for (int jn = 0; jn < 4; ++jn)
        acc[i][jn] = mfma16(af[i], bf[jn], acc[i][jn]);
    __syncthreads();
  }
#pragma unroll
  for (int i = 0; i < 4; ++i)
#pragma unroll
    for (int jn = 0; jn < 4; ++jn)
#pragma unroll
      for (int j = 0; j < 4; ++j) {
        int row = bm + wr * 64 + i * 16 + lg * 4 + j;
        int col = bn + wc * 64 + jn * 16 + lr;
        if (col < N) {
          if (CBF16) ((u16*)Cp)[coz * z + (size_t)row * ldc + col] = f2bf(acc[i][jn][j]);
          else ((float*)Cp)[coz * z + (size_t)row * ldc + col] = acc[i][jn][j];
        }
      }
}

// ---------------------------------------------------------------- RMS norms
__global__ __launch_bounds__(256) void rmsnorm_kernel(
    const float* __restrict__ qkv, const float* __restrict__ qw,
    const float* __restrict__ kvw, float* __restrict__ q_cn,
    u16* __restrict__ kv_cn) {
  const int t = blockIdx.x, tid = threadIdx.x;
  const float* row = qkv + (size_t)t * QKVN_;
  __shared__ float red[256];
  float ss = 0.f;
  for (int i = tid; i < QLR_; i += 256) { float v = row[i]; ss += v * v; }
  red[tid] = ss; __syncthreads();
  for (int s = 128; s; s >>= 1) { if (tid < s) red[tid] += red[tid + s]; __syncthreads(); }
  float scl = 1.0f / sqrtf(red[0] / (float)QLR_ + EPS_);
  for (int i = tid; i < QLR_; i += 256)
    q_cn[(size_t)t * QLR_ + i] = row[i] * scl * qw[i];
  __syncthreads();
  ss = 0.f;
  for (int i = tid; i < KVLR_; i += 256) { float v = row[QLR_ + i]; ss += v * v; }
  red[tid] = ss; __syncthreads();
  for (int s = 128; s; s >>= 1) { if (tid < s) red[tid] += red[tid + s]; __syncthreads(); }
  scl = 1.0f / sqrtf(red[0] / (float)KVLR_ + EPS_);
  for (int i = tid; i < KVLR_; i += 256)
    kv_cn[(size_t)t * KVLR_ + i] = f2bf(row[QLR_ + i] * scl * kvw[i]);
}

// ---------------------------------------------------------------- RoPE helpers
__device__ __forceinline__ void rope_pair(float pos, int j, float& x0, float& x1) {
  float inv = powf(10000.f, -(float)j * (1.f / 32.f));
  float f = pos * inv;
  float c = cosf(f), s = sinf(f);
  float a = x0, b = x1;
  x0 = a * c - b * s;
  x1 = a * s + b * c;
}

__global__ __launch_bounds__(256) void rope_qi_kernel(float* __restrict__ qi) {
  const int t = blockIdx.x, tid = threadIdx.x;
  float pos = (float)t;
  for (int idx = tid; idx < IDXH_ * 32; idx += 256) {
    int hh = idx / 32, j = idx % 32;
    float* p = qi + (size_t)t * (IDXH_ * IDXD_) + hh * IDXD_;
    rope_pair(pos, j, p[2 * j], p[2 * j + 1]);
  }
}

__global__ __launch_bounds__(256) void rope_q_bf_kernel(u16* __restrict__ qfb) {
  const int t = blockIdx.x, tid = threadIdx.x;
  float pos = (float)t;
  for (int idx = tid; idx < H_ * 32; idx += 256) {
    int hh = idx / 32, j = idx % 32;
    u16* p = qfb + (size_t)t * (H_ * QKD_) + hh * QKD_ + NOPE_ + 2 * j;
    float x0 = bf2f(p[0]), x1 = bf2f(p[1]);
    rope_pair(pos, j, x0, x1);
    p[0] = f2bf(x0); p[1] = f2bf(x1);
  }
}

__global__ __launch_bounds__(64) void rope_kpe_kernel(
    const float* __restrict__ qkv, u16* __restrict__ kper) {
  const int t = blockIdx.x, tid = threadIdx.x;
  if (tid >= 32) return;
  float pos = (float)t;
  const float* p = qkv + (size_t)t * QKVN_ + (QLR_ + KVLR_);
  float x0 = p[2 * tid], x1 = p[2 * tid + 1];
  rope_pair(pos, tid, x0, x1);
  kper[(size_t)t * ROPE_ + 2 * tid] = f2bf(x0);
  kper[(size_t)t * ROPE_ + 2 * tid + 1] = f2bf(x1);
}

// ---------------------------------------------------------------- ki: LN + rope (f32 in place)
__global__ __launch_bounds__(128) void ki_ln_rope_kernel(
    float* __restrict__ ki, const float* __restrict__ gamma,
    const float* __restrict__ beta) {
  const int t = blockIdx.x, tid = threadIdx.x;
  __shared__ float x[128];
  __shared__ float red[128];
  float v = ki[(size_t)t * IDXD_ + tid];
  red[tid] = v; __syncthreads();
  for (int s = 64; s; s >>= 1) { if (tid < s) red[tid] += red[tid + s]; __syncthreads(); }
  float mu = red[0] / 128.f;
  __syncthreads();
  float d = v - mu;
  red[tid] = d * d; __syncthreads();
  for (int s = 64; s; s >>= 1) { if (tid < s) red[tid] += red[tid + s]; __syncthreads(); }
  float var = red[0] / 128.f;
  float y = d * (1.0f / sqrtf(var + EPS_)) * gamma[tid] + beta[tid];
  x[tid] = y; __syncthreads();
  float pos = (float)t;
  if (tid < 32) {
    float x0 = x[2 * tid], x1 = x[2 * tid + 1];
    rope_pair(pos, tid, x0, x1);
    ki[(size_t)t * IDXD_ + 2 * tid] = x0;
    ki[(size_t)t * IDXD_ + 2 * tid + 1] = x1;
  } else if (tid >= 64) {
    ki[(size_t)t * IDXD_ + tid] = y;
  }
}

// ---------------------------------------------------------------- w epilogue
__global__ __launch_bounds__(256) void w_epi_kernel(
    float* __restrict__ wgt, const float* __restrict__ b) {
  int idx = blockIdx.x * 256 + threadIdx.x;
  if (idx < T_ * IDXH_)
    wgt[idx] = (wgt[idx] + b[idx & 31]) * 0.015625f;
}

// ---------------------------------------------------------------- indexer score (split-f16 MFMA)
__global__ __launch_bounds__(256) void score_mfma(
    const float* __restrict__ qi, const float* __restrict__ ki,
    const float* __restrict__ wgt, float* __restrict__ score) {
  const int s0 = blockIdx.x * 64, t0 = blockIdx.y * 64;
  if (s0 > t0 + 63) return;
  __shared__ u32 Kh[64][68], Kl[64][68], Qh[64][68], Ql[64][68];
  __shared__ float wts[64][33];
  const int tid = threadIdx.x;
  const int wid = tid >> 6, lane = tid & 63, wr = wid >> 1, wc = wid & 1;
  const int lr = lane & 15, lg = lane >> 4;
#pragma unroll
  for (int j = 0; j < 8; ++j) {
    int u = tid + 256 * j; int row = u >> 5, p = u & 31;
    float4 v = *(const float4*)(ki + (size_t)(s0 + row) * IDXD_ + p * 4);
    f16 h0 = (f16)v.x, h1 = (f16)v.y, h2 = (f16)v.z, h3 = (f16)v.w;
    Kh[row][p * 2] = hpack(h0, h1);
    Kh[row][p * 2 + 1] = hpack(h2, h3);
    Kl[row][p * 2] = hpack((f16)(v.x - (float)h0), (f16)(v.y - (float)h1));
    Kl[row][p * 2 + 1] = hpack((f16)(v.z - (float)h2), (f16)(v.w - (float)h3));
  }
#pragma unroll
  for (int j = 0; j < 8; ++j) {
    int u = tid + 256 * j; int r = u >> 5, c = u & 31;
    wts[r][c] = wgt[(size_t)(t0 + r) * IDXH_ + c];
  }
  __syncthreads();
  f16x8 bh[2][4], bl[2][4];
#pragma unroll
  for (int ni = 0; ni < 2; ++ni)
#pragma unroll
    for (int kb = 0; kb < 4; ++kb) {
      // fragment k-slice: u16 elem kb*32 + lg*8  ->  u32 index kb*16 + lg*4
      bh[ni][kb] = ldh8(&Kh[wc * 32 + ni * 16 + lr][kb * 16 + lg * 4]);
      bl[ni][kb] = ldh8(&Kl[wc * 32 + ni * 16 + lr][kb * 16 + lg * 4]);
    }
  f32x4 fin[2][2] = {};
  for (int h = 0; h < IDXH_; ++h) {
#pragma unroll
    for (int j = 0; j < 8; ++j) {
      int u = tid + 256 * j; int row = u >> 5, p = u & 31;
      float4 v = *(const float4*)(qi + (size_t)(t0 + row) * (IDXH_ * IDXD_) + h * IDXD_ + p * 4);
      f16 h0 = (f16)v.x, h1 = (f16)v.y, h2 = (f16)v.z, h3 = (f16)v.w;
      Qh[row][p * 2] = hpack(h0, h1);
      Qh[row][p * 2 + 1] = hpack(h2, h3);
      Ql[row][p * 2] = hpack((f16)(v.x - (float)h0), (f16)(v.y - (float)h1));
      Ql[row][p * 2 + 1] = hpack((f16)(v.z - (float)h2), (f16)(v.w - (float)h3));
    }
    __syncthreads();
    f32x4 acch[2][2] = {};
#pragma unroll
    for (int kb = 0; kb < 4; ++kb) {
      f16x8 ah0 = ldh8(&Qh[wr * 32 + lr][kb * 16 + lg * 4]);
      f16x8 ah1 = ldh8(&Qh[wr * 32 + 16 + lr][kb * 16 + lg * 4]);
      f16x8 al0 = ldh8(&Ql[wr * 32 + lr][kb * 16 + lg * 4]);
      f16x8 al1 = ldh8(&Ql[wr * 32 + 16 + lr][kb * 16 + lg * 4]);
#pragma unroll
      for (int ni = 0; ni < 2; ++ni) {
        acch[0][ni] = mfmah(ah0, bh[ni][kb], acch[0][ni]);
        acch[0][ni] = mfmah(ah0, bl[ni][kb], acch[0][ni]);
        acch[0][ni] = mfmah(al0, bh[ni][kb], acch[0][ni]);
        acch[1][ni] = mfmah(ah1, bh[ni][kb], acch[1][ni]);
        acch[1][ni] = mfmah(ah1, bl[ni][kb], acch[1][ni]);
        acch[1][ni] = mfmah(al1, bh[ni][kb], acch[1][ni]);
      }
    }
#pragma unroll
    for (int mi = 0; mi < 2; ++mi)
#pragma unroll
      for (int j = 0; j < 4; ++j) {
        float w = wts[wr * 32 + mi * 16 + lg * 4 + j][h];
        fin[mi][0][j] += w * fmaxf(acch[mi][0][j], 0.f);
        fin[mi][1][j] += w * fmaxf(acch[mi][1][j], 0.f);
      }
    __syncthreads();
  }
#pragma unroll
  for (int mi = 0; mi < 2; ++mi)
#pragma unroll
    for (int ni = 0; ni < 2; ++ni)
#pragma unroll
      for (int j = 0; j < 4; ++j) {
        int row = t0 + wr * 32 + mi * 16 + lg * 4 + j;
        int col = s0 + wc * 32 + ni * 16 + lr;
        score[(size_t)row * T_ + col] = fin[mi][ni][j];
      }
}

// ---------------------------------------------------------------- top-k (exact)
__global__ __launch_bounds__(256) void topk_kernel(
    const float* __restrict__ score, int* __restrict__ selidx,
    int* __restrict__ selcnt) {
  const int t = blockIdx.x;
  const int L = t + 1;
  const int tid = threadIdx.x;
  if (L <= TOPK_) {
    for (int j = tid; j < TOPK_; j += 256)
      selidx[(size_t)t * TOPK_ + j] = (j < L) ? j : 0;
    if (tid == 0) selcnt[t] = L;
    return;
  }
  __shared__ unsigned u[T_];
  __shared__ unsigned hist[16];
  __shared__ unsigned sprefix;
  __shared__ int sk;
  __shared__ int part[256];
  for (int i = tid; i < T_; i += 256) {
    float v = (i < L) ? score[(size_t)t * T_ + i] : -FLT_MAX;
    unsigned b = __float_as_uint(v);
    u[i] = (b & 0x80000000u) ? ~b : (b | 0x80000000u);
  }
  if (tid == 0) { sprefix = 0u; sk = TOPK_; }
  __syncthreads();
  for (int pass = 0; pass < 8; ++pass) {
    const int shift = 28 - 4 * pass;
    if (tid < 16) hist[tid] = 0u;
    __syncthreads();
    unsigned pfx = sprefix;
    for (int i = tid; i < L; i += 256) {
      unsigned val = u[i];
      bool match = (pass == 0) || ((val >> (shift + 4)) == pfx);
      if (match) atomicAdd(&hist[(val >> shift) & 15u], 1u);
    }
    __syncthreads();
    if (tid == 0) {
      int k = sk; unsigned cum = 0u; int bsel = 0;
      for (int bb = 15; bb >= 0; --bb) {
        if (cum + hist[bb] >= (unsigned)k) { bsel = bb; sk = k - (int)cum; break; }
        cum += hist[bb];
      }
      sprefix = (sprefix << 4) | (unsigned)bsel;
    }
    __syncthreads();
  }
  const unsigned thr = sprefix;
  const int kEq = sk;
  const int base = tid * 8;
  int eqloc[8]; int esum = 0;
  for (int r = 0; r < 8; ++r) {
    int i = base + r;
    int f = (i < L && u[i] == thr) ? 1 : 0;
    eqloc[r] = esum; esum += f;
  }
  part[tid] = esum; __syncthreads();
  for (int off = 1; off < 256; off <<= 1) {
    int v = (tid >= off) ? part[tid - off] : 0;
    __syncthreads();
    part[tid] += v;
    __syncthreads();
  }
  const int ebase = (tid > 0) ? part[tid - 1] : 0;
  __syncthreads();
  int sloc[8], selflag[8]; int ssum = 0;
  for (int r = 0; r < 8; ++r) {
    int i = base + r;
    int f = 0;
    if (i < L) {
      unsigned ui = u[i];
      if (ui > thr) f = 1;
      else if (ui == thr && (ebase + eqloc[r]) < kEq) f = 1;
    }
    selflag[r] = f; sloc[r] = ssum; ssum += f;
  }
  part[tid] = ssum; __syncthreads();
  for (int off = 1; off < 256; off <<= 1) {
    int v = (tid >= off) ? part[tid - off] : 0;
    __syncthreads();
    part[tid] += v;
    __syncthreads();
  }
  const int sbase = (tid > 0) ? part[tid - 1] : 0;
  for (int r = 0; r < 8; ++r)
    if (selflag[r]) selidx[(size_t)t * TOPK_ + sbase + sloc[r]] = base + r;
  if (tid == 0) selcnt[t] = TOPK_;
}

// ---------------------------------------------------------------- MLA attention (absorbed, MFMA)
__global__ __launch_bounds__(256, 1) void attn_mla_kernel(
    const u16* __restrict__ qeff, const u16* __restrict__ qfb,
    const u16* __restrict__ kvcn, const u16* __restrict__ kper,
    const int* __restrict__ selidx, const int* __restrict__ selcnt,
    u16* __restrict__ Olat) {
  const int t = blockIdx.x;
  const int tid = threadIdx.x;
  const int wid = tid >> 6, lane = tid & 63;
  const int lr = lane & 15, lg = lane >> 4;
  __shared__ u16 Ks[64][584];
  __shared__ u16 Pb[16][520];
  __shared__ int sidxs[512];
  __shared__ float redm[4][16];
  __shared__ float reds[4][16];
  const int cnt = selcnt[t];
  for (int j = tid; j < 512; j += 256) sidxs[j] = selidx[(size_t)t * TOPK_ + j];
  bf16x8 qf[18];
  {
    const u16* qe = qeff + (size_t)t * (H_ * 512);
    const u16* qp = qfb + (size_t)t * (H_ * QKD_);
#pragma unroll
    for (int kb = 0; kb < 16; ++kb)
      qf[kb] = ld8(qe + lr * 512 + kb * 32 + lg * 8);
#pragma unroll
    for (int kb = 16; kb < 18; ++kb)
      qf[kb] = ld8(qp + lr * QKD_ + NOPE_ + (kb - 16) * 32 + lg * 8);
  }
  __syncthreads();

  f32x4 lgv[8];
  uint4 hold[18];
#pragma unroll
  for (int j = 0; j < 18; ++j) {
    int u = tid + 256 * j; int row = u / 72, piece = u % 72;
    int s = sidxs[row];
    hold[j] = (piece < 64) ? *(const uint4*)(kvcn + (size_t)s * 512 + piece * 8)
                           : *(const uint4*)(kper + (size_t)s * 64 + (piece - 64) * 8);
  }
  for (int c = 0; c < 8; ++c) {
#pragma unroll
    for (int j = 0; j < 18; ++j) {
      int u = tid + 256 * j; int row = u / 72, piece = u % 72;
      *(uint4*)&Ks[row][piece * 8] = hold[j];
    }
    __syncthreads();
    if (c < 7) {
#pragma unroll
      for (int j = 0; j < 18; ++j) {
        int u = tid + 256 * j; int row = u / 72, piece = u % 72;
        int s = sidxs[(c + 1) * 64 + row];
        hold[j] = (piece < 64) ? *(const uint4*)(kvcn + (size_t)s * 512 + piece * 8)
                               : *(const uint4*)(kper + (size_t)s * 64 + (piece - 64) * 8);
      }
    }
    f32x4 a = {0.f, 0.f, 0.f, 0.f};
#pragma unroll
    for (int kb = 0; kb < 18; ++kb) {
      bf16x8 kf = ld8(&Ks[wid * 16 + lr][kb * 32 + lg * 8]);
      a = mfma16(kf, qf[kb], a);
    }
    lgv[c] = a;
    __syncthreads();
  }

  float mx = -FLT_MAX;
#pragma unroll
  for (int c = 0; c < 8; ++c)
#pragma unroll
    for (int j = 0; j < 4; ++j) {
      int slot = c * 64 + wid * 16 + lg * 4 + j;
      float v = (slot < cnt) ? lgv[c][j] * SCALING_ : -FLT_MAX;
      lgv[c][j] = v;
      mx = fmaxf(mx, v);
    }
  mx = fmaxf(mx, __shfl_xor(mx, 16));
  mx = fmaxf(mx, __shfl_xor(mx, 32));
  if (lane < 16) redm[wid][lane] = mx;
  __syncthreads();
  float hm = fmaxf(fmaxf(redm[0][lr], redm[1][lr]), fmaxf(redm[2][lr], redm[3][lr]));
  float sm = 0.f;
#pragma unroll
  for (int c = 0; c < 8; ++c)
#pragma unroll
    for (int j = 0; j < 4; ++j) {
      int slot = c * 64 + wid * 16 + lg * 4 + j;
      float e = (slot < cnt) ? expf(lgv[c][j] - hm) : 0.f;
      lgv[c][j] = e; sm += e;
    }
  sm += __shfl_xor(sm, 16);
  sm += __shfl_xor(sm, 32);
  if (lane < 16) reds[wid][lane] = sm;
  __syncthreads();
  float inv = 1.f / (reds[0][lr] + reds[1][lr] + reds[2][lr] + reds[3][lr]);
#pragma unroll
  for (int c = 0; c < 8; ++c) {
    int sl0 = c * 64 + wid * 16 + lg * 4;
    *(u32*)&Pb[lr][sl0] = pack2(lgv[c][0] * inv, lgv[c][1] * inv);
    *(u32*)&Pb[lr][sl0 + 2] = pack2(lgv[c][2] * inv, lgv[c][3] * inv);
  }
  __syncthreads();

  u16 (*KVs)[520] = (u16(*)[520]) & Ks[0][0];
  f32x4 oacc[8] = {};
  uint4 vh[8];
#pragma unroll
  for (int j = 0; j < 8; ++j) {
    int u = tid + 256 * j; int row = u >> 6, piece = u & 63;
    int s = sidxs[row];
    vh[j] = *(const uint4*)(kvcn + (size_t)s * 512 + piece * 8);
  }
  for (int c = 0; c < 16; ++c) {
#pragma unroll
    for (int j = 0; j < 8; ++j) {
      int u = tid + 256 * j; int row = u >> 6, piece = u & 63;
      *(uint4*)&KVs[row][piece * 8] = vh[j];
    }
    __syncthreads();
    if (c < 15) {
#pragma unroll
      for (int j = 0; j < 8; ++j) {
        int u = tid + 256 * j; int row = u >> 6, piece = u & 63;
        int s = sidxs[(c + 1) * 32 + row];
        vh[j] = *(const uint4*)(kvcn + (size_t)s * 512 + piece * 8);
      }
    }
    bf16x8 pa = ld8(&Pb[lr][c * 32 + lg * 8]);
    const int wcol = wid * 128;
#pragma unroll
    for (int C = 0; C < 8; ++C) {
      union { u32 u[4]; bf16x8 v; } bb;
#pragma unroll
      for (int e = 0; e < 4; ++e)
        bb.u[e] = (u32)KVs[lg * 8 + 2 * e][wcol + C * 16 + lr] |
                  ((u32)KVs[lg * 8 + 2 * e + 1][wcol + C * 16 + lr] << 16);
      oacc[C] = mfma16(pa, bb.v, oacc[C]);
    }
    __syncthreads();
  }
#pragma unroll
  for (int C = 0; C < 8; ++C)
#pragma unroll
    for (int j = 0; j < 4; ++j) {
      int h = lg * 4 + j;
      Olat[(size_t)t * (H_ * 512) + h * 512 + wid * 128 + C * 16 + lr] = f2bf(oacc[C][j]);
    }
}

// ---------------------------------------------------------------- launch
extern "C" void kernel_launch(void* const* d_in, const int* in_sizes, int n_in,
                              void* d_out, int out_size, void* d_ws, size_t ws_size,
                              hipStream_t stream) {
  const float* hidden    = (const float*)d_in[1];
  const float* w_qkv_a   = (const float*)d_in[2];
  const float* q_a_ln_w  = (const float*)d_in[3];
  const float* w_qb      = (const float*)d_in[4];
  const float* kv_a_ln_w = (const float*)d_in[5];
  const float* w_kvb     = (const float*)d_in[6];
  const float* w_o       = (const float*)d_in[7];
  const float* w_idx_qb  = (const float*)d_in[8];
  const float* w_idx_k   = (const float*)d_in[9];
  const float* idx_g     = (const float*)d_in[10];
  const float* idx_b     = (const float*)d_in[11];
  const float* w_wproj   = (const float*)d_in[12];
  const float* b_wproj   = (const float*)d_in[13];

  char* W = (char*)d_ws;
  size_t o = 0;
  auto alloc = [&](size_t bytes) { void* p = W + o; o += (bytes + 255) & ~(size_t)255; return p; };
  float* q_cn   = (float*)alloc((size_t)T_ * QLR_ * 4);
  u16*   kv_cn  = (u16*)alloc((size_t)T_ * KVLR_ * 2);
  u16*   kper   = (u16*)alloc((size_t)T_ * ROPE_ * 2);
  int*   selidx = (int*)alloc((size_t)T_ * TOPK_ * 4);
  int*   selcnt = (int*)alloc((size_t)T_ * 4);
  float* wgt    = (float*)alloc((size_t)T_ * IDXH_ * 4);
  float* ki     = (float*)alloc((size_t)T_ * IDXD_ * 4);
  float* qi     = (float*)alloc((size_t)T_ * IDXH_ * IDXD_ * 4);
  u16*   qeff   = (u16*)qi;
  float* score  = (float*)alloc((size_t)T_ * T_ * 4);
  u16*   attno  = (u16*)score;
  float* wqat   = (float*)alloc((size_t)QKVN_ * HID_ * 4);
  float* qkv    = (float*)alloc((size_t)T_ * QKVN_ * 4);
  u16*   Olat   = (u16*)wqat;
  float* wiqt   = (float*)alloc((size_t)(IDXH_ * IDXD_) * QLR_ * 4);
  u16*   qfb    = (u16*)wiqt;
  float* wikt   = (float*)alloc((size_t)IDXD_ * HID_ * 4);
  float* wwpt   = (float*)alloc((size_t)IDXH_ * HID_ * 4);
  u16*   wqbt   = (u16*)alloc((size_t)(H_ * QKD_) * QLR_ * 2);
  u16*   wkvb   = (u16*)alloc((size_t)KVLR_ * (H_ * 256) * 2);
  u16*   wkvbt  = (u16*)alloc((size_t)(H_ * 256) * KVLR_ * 2);
  u16*   wot    = (u16*)alloc((size_t)(H_ * VD_) * HID_ * 2);

  dim3 blk(256);
  auto g2 = [](int M, int N, int Z) { return dim3((N + 127) / 128, M / 128, Z); };

  // weight prep
  transpose_f32_k<<<dim3(33, 32), blk, 0, stream>>>(w_qkv_a, wqat, HID_, QKVN_);
  transpose_f32_k<<<dim3(64, 24), blk, 0, stream>>>(w_idx_qb, wiqt, QLR_, IDXH_ * IDXD_);
  transpose_f32_k<<<dim3(2, 32), blk, 0, stream>>>(w_idx_k, wikt, HID_, IDXD_);
  transpose_f32_k<<<dim3(1, 32), blk, 0, stream>>>(w_wproj, wwpt, HID_, IDXH_);
  transpose_bf16_k<<<dim3(48, 24), blk, 0, stream>>>(w_qb, wqbt, QLR_, H_ * QKD_);
  transpose_bf16_k<<<dim3(64, 8), blk, 0, stream>>>(w_kvb, wkvbt, KVLR_, H_ * 256);
  transpose_bf16_k<<<dim3(32, 32), blk, 0, stream>>>(w_o, wot, H_ * VD_, HID_);
  conv_bf16_k<<<2048, blk, 0, stream>>>(w_kvb, wkvb, (long)KVLR_ * H_ * 256);

  // strict path (f16-split MFMA)
  gemm_split<<<g2(T_, QKVN_, 1), blk, 0, stream>>>(hidden, HID_, wqat, HID_, qkv, QKVN_, QKVN_, HID_);
  rmsnorm_kernel<<<T_, blk, 0, stream>>>(qkv, q_a_ln_w, kv_a_ln_w, q_cn, kv_cn);
  rope_kpe_kernel<<<T_, 64, 0, stream>>>(qkv, kper);

  gemm_split<<<g2(T_, IDXH_ * IDXD_, 1), blk, 0, stream>>>(q_cn, QLR_, wiqt, QLR_, qi, IDXH_ * IDXD_, IDXH_ * IDXD_, QLR_);
  rope_qi_kernel<<<T_, blk, 0, stream>>>(qi);
  gemm_split<<<g2(T_, IDXD_, 1), blk, 0, stream>>>(hidden, HID_, wikt, HID_, ki, IDXD_, IDXD_, HID_);
  ki_ln_rope_kernel<<<T_, 128, 0, stream>>>(ki, idx_g, idx_b);
  gemm_split<<<g2(T_, IDXH_, 1), blk, 0, stream>>>(hidden, HID_, wwpt, HID_, wgt, IDXH_, IDXH_, HID_);
  w_epi_kernel<<<(T_ * IDXH_ + 255) / 256, blk, 0, stream>>>(wgt, b_wproj);

  score_mfma<<<dim3(32, 32), blk, 0, stream>>>(qi, ki, wgt, score);
  topk_kernel<<<T_, blk, 0, stream>>>(score, selidx, selcnt);

  // tolerant path (bf16 MFMA)
  gemm_t<1, 1><<<g2(T_, H_ * QKD_, 1), blk, 0, stream>>>(q_cn, QLR_, 0, wqbt, QLR_, 0, qfb, H_ * QKD_, 0, H_ * QKD_, QLR_);
  rope_q_bf_kernel<<<T_, blk, 0, stream>>>(qfb);
  gemm_t<0, 1><<<g2(T_, 512, H_), blk, 0, stream>>>(qfb, H_ * QKD_, QKD_, wkvb, H_ * 256, 256, qeff, H_ * 512, 512, 512, NOPE_);
  attn_mla_kernel<<<T_, blk, 0, stream>>>(qeff, qfb, kv_cn, kper, selidx, selcnt, Olat);
  gemm_t<0, 1><<<g2(T_, VD_, H_), blk, 0, stream>>>(Olat, H_ * 512, 512, wkvbt + 128 * 512, KVLR_, 256 * 512, attno, H_ * VD_, VD_, VD_, 512);
  gemm_t<0, 0><<<g2(T_, HID_, 1), blk, 0, stream>>>(attno, H_ * VD_, 0, wot, H_ * VD_, 0, d_out, HID_, 0, HID_, H_ * VD_);
}

// Round 5
// 1513.377 us; speedup vs baseline: 3.3143x; 1.2469x over previous
//
#include <hip/hip_runtime.h>
#include <cfloat>
#include <cmath>

#define T_    2048
#define HID_  2048
#define QKVN_ 2112
#define QLR_  1536
#define KVLR_ 512
#define ROPE_ 64
#define NOPE_ 128
#define QKD_  192
#define VD_   128
#define H_    16
#define IDXH_ 32
#define IDXD_ 128
#define TOPK_ 512
#define EPS_  1e-6f
#define SCALING_ 0.07216878364870323f   // 192^-0.5

typedef unsigned int u32;
typedef unsigned short u16;
typedef __bf16 bf16x8 __attribute__((ext_vector_type(8)));
typedef _Float16 f16;
typedef f16 f16x8 __attribute__((ext_vector_type(8)));
typedef float f32x4 __attribute__((ext_vector_type(4)));

__device__ __forceinline__ u16 f2bf(float x) {
  u32 u = __float_as_uint(x);
  u32 r = (u + 0x7fffu + ((u >> 16) & 1u)) >> 16;
  return (u16)r;
}
__device__ __forceinline__ float bf2f(u16 h) { return __uint_as_float(((u32)h) << 16); }
__device__ __forceinline__ u32 pack2(float a, float b) { return (u32)f2bf(a) | ((u32)f2bf(b) << 16); }
__device__ __forceinline__ bf16x8 ld8(const void* p) { return *(const bf16x8*)p; }
__device__ __forceinline__ f32x4 mfma16(bf16x8 a, bf16x8 b, f32x4 c) {
  return __builtin_amdgcn_mfma_f32_16x16x32_bf16(a, b, c, 0, 0, 0);
}
// ---- fp16 helpers (strict path: hi+lo split covers ~22 mantissa bits)
__device__ __forceinline__ u16 hbits(f16 h) { union { f16 h; u16 u; } c; c.h = h; return c.u; }
__device__ __forceinline__ u32 hpack(f16 a, f16 b) { return (u32)hbits(a) | ((u32)hbits(b) << 16); }
__device__ __forceinline__ f16x8 ldh8(const void* p) { return *(const f16x8*)p; }
__device__ __forceinline__ f32x4 mfmah(f16x8 a, f16x8 b, f32x4 c) {
  return __builtin_amdgcn_mfma_f32_16x16x32_f16(a, b, c, 0, 0, 0);
}

// ---------------------------------------------------------------- transposes / converts
__global__ __launch_bounds__(256) void transpose_f32_k(
    const float* __restrict__ in, float* __restrict__ out, int K, int N) {
  __shared__ float t[64][65];
  int k0 = blockIdx.y * 64, n0 = blockIdx.x * 64;
  for (int j = 0; j < 16; ++j) {
    int u = threadIdx.x + 256 * j; int r = u >> 6, c = u & 63;
    t[r][c] = (k0 + r < K && n0 + c < N) ? in[(size_t)(k0 + r) * N + n0 + c] : 0.f;
  }
  __syncthreads();
  for (int j = 0; j < 16; ++j) {
    int u = threadIdx.x + 256 * j; int r = u >> 6, c = u & 63;
    if (n0 + r < N && k0 + c < K) out[(size_t)(n0 + r) * K + k0 + c] = t[c][r];
  }
}

__global__ __launch_bounds__(256) void transpose_bf16_k(
    const float* __restrict__ in, u16* __restrict__ out, int K, int N) {
  __shared__ float t[64][65];
  int k0 = blockIdx.y * 64, n0 = blockIdx.x * 64;
  for (int j = 0; j < 16; ++j) {
    int u = threadIdx.x + 256 * j; int r = u >> 6, c = u & 63;
    t[r][c] = (k0 + r < K && n0 + c < N) ? in[(size_t)(k0 + r) * N + n0 + c] : 0.f;
  }
  __syncthreads();
  for (int j = 0; j < 16; ++j) {
    int u = threadIdx.x + 256 * j; int r = u >> 6, c = u & 63;
    if (n0 + r < N && k0 + c < K) out[(size_t)(n0 + r) * K + k0 + c] = f2bf(t[c][r]);
  }
}

__global__ __launch_bounds__(256) void conv_bf16_k(
    const float* __restrict__ in, u16* __restrict__ out, long n) {
  for (long i = ((long)blockIdx.x * 256 + threadIdx.x) * 4; i < n; i += (long)gridDim.x * 1024) {
    float4 v = *(const float4*)(in + i);
    u32 a = pack2(v.x, v.y), b = pack2(v.z, v.w);
    *(u32*)(out + i) = a; *(u32*)(out + i + 2) = b;
  }
}

// ---------------------------------------------------------------- strict split-f16 GEMM
__global__ __launch_bounds__(256) void gemm_split(
    const float* __restrict__ A, int lda,
    const float* __restrict__ Bt, int ldb,
    float* __restrict__ C, int ldc, int N, int K) {
  __shared__ u32 Ah[128][20], Al[128][20], Bh[128][20], Bl[128][20];
  const int tid = threadIdx.x;
  const int bm = blockIdx.y * 128, bn = blockIdx.x * 128;
  const int wid = tid >> 6, lane = tid & 63, wr = wid >> 1, wc = wid & 1;
  const int lr = lane & 15, lg = lane >> 4;
  f32x4 acc[4][4] = {};
  for (int k0 = 0; k0 < K; k0 += 32) {
#pragma unroll
    for (int j = 0; j < 4; ++j) {
      int u = tid + 256 * j; int row = u >> 3, p = u & 7;
      float4 v = *(const float4*)(A + (size_t)(bm + row) * lda + k0 + p * 4);
      f16 h0 = (f16)v.x, h1 = (f16)v.y, h2 = (f16)v.z, h3 = (f16)v.w;
      Ah[row][p * 2] = hpack(h0, h1);
      Ah[row][p * 2 + 1] = hpack(h2, h3);
      Al[row][p * 2] = hpack((f16)(v.x - (float)h0), (f16)(v.y - (float)h1));
      Al[row][p * 2 + 1] = hpack((f16)(v.z - (float)h2), (f16)(v.w - (float)h3));
    }
#pragma unroll
    for (int j = 0; j < 4; ++j) {
      int u = tid + 256 * j; int row = u >> 3, p = u & 7;
      float4 v = make_float4(0.f, 0.f, 0.f, 0.f);
      if (bn + row < N) v = *(const float4*)(Bt + (size_t)(bn + row) * ldb + k0 + p * 4);
      f16 h0 = (f16)v.x, h1 = (f16)v.y, h2 = (f16)v.z, h3 = (f16)v.w;
      Bh[row][p * 2] = hpack(h0, h1);
      Bh[row][p * 2 + 1] = hpack(h2, h3);
      Bl[row][p * 2] = hpack((f16)(v.x - (float)h0), (f16)(v.y - (float)h1));
      Bl[row][p * 2 + 1] = hpack((f16)(v.z - (float)h2), (f16)(v.w - (float)h3));
    }
    __syncthreads();
    f16x8 ah[4], al[4], bh[4], bl[4];
#pragma unroll
    for (int i = 0; i < 4; ++i) {
      ah[i] = ldh8(&Ah[wr * 64 + i * 16 + lr][lg * 4]);
      al[i] = ldh8(&Al[wr * 64 + i * 16 + lr][lg * 4]);
      bh[i] = ldh8(&Bh[wc * 64 + i * 16 + lr][lg * 4]);
      bl[i] = ldh8(&Bl[wc * 64 + i * 16 + lr][lg * 4]);
    }
#pragma unroll
    for (int i = 0; i < 4; ++i)
#pragma unroll
      for (int jn = 0; jn < 4; ++jn) {
        acc[i][jn] = mfmah(ah[i], bh[jn], acc[i][jn]);
        acc[i][jn] = mfmah(ah[i], bl[jn], acc[i][jn]);
        acc[i][jn] = mfmah(al[i], bh[jn], acc[i][jn]);
      }
    __syncthreads();
  }
#pragma unroll
  for (int i = 0; i < 4; ++i)
#pragma unroll
    for (int jn = 0; jn < 4; ++jn)
#pragma unroll
      for (int j = 0; j < 4; ++j) {
        int row = bm + wr * 64 + i * 16 + lg * 4 + j;
        int col = bn + wc * 64 + jn * 16 + lr;
        if (col < N) C[(size_t)row * ldc + col] = acc[i][jn][j];
      }
}

// ---------------------------------------------------------------- tolerant bf16 GEMM
template <int AF32, int CBF16>
__global__ __launch_bounds__(256) void gemm_t(
    const void* __restrict__ Ap, int lda, long aoz,
    const u16* __restrict__ Bt, int ldb, long boz,
    void* __restrict__ Cp, int ldc, long coz, int N, int K) {
  __shared__ u32 As[128][20], Bs[128][20];
  const int tid = threadIdx.x;
  const int z = blockIdx.z;
  const int bm = blockIdx.y * 128, bn = blockIdx.x * 128;
  const int wid = tid >> 6, lane = tid & 63, wr = wid >> 1, wc = wid & 1;
  const int lr = lane & 15, lg = lane >> 4;
  f32x4 acc[4][4] = {};
  for (int k0 = 0; k0 < K; k0 += 32) {
    if (AF32) {
      const float* A = (const float*)Ap + aoz * z;
#pragma unroll
      for (int j = 0; j < 4; ++j) {
        int u = tid + 256 * j; int row = u >> 3, p = u & 7;
        float4 v = *(const float4*)(A + (size_t)(bm + row) * lda + k0 + p * 4);
        As[row][p * 2] = pack2(v.x, v.y);
        As[row][p * 2 + 1] = pack2(v.z, v.w);
      }
    } else {
      const u16* A = (const u16*)Ap + aoz * z;
#pragma unroll
      for (int j = 0; j < 2; ++j) {
        int u = tid + 256 * j; int row = u >> 2, p = u & 3;
        uint4 v = *(const uint4*)(A + (size_t)(bm + row) * lda + k0 + p * 8);
        *(uint4*)&As[row][p * 4] = v;
      }
    }
#pragma unroll
    for (int j = 0; j < 2; ++j) {
      int u = tid + 256 * j; int row = u >> 2, p = u & 3;
      uint4 v = make_uint4(0, 0, 0, 0);
      if (bn + row < N) v = *(const uint4*)(Bt + boz * z + (size_t)(bn + row) * ldb + k0 + p * 8);
      *(uint4*)&Bs[row][p * 4] = v;
    }
    __syncthreads();
    bf16x8 af[4], bf[4];
#pragma unroll
    for (int i = 0; i < 4; ++i) {
      af[i] = ld8(&As[wr * 64 + i * 16 + lr][lg * 4]);
      bf[i] = ld8(&Bs[wc * 64 + i * 16 + lr][lg * 4]);
    }
#pragma unroll
    for (int i = 0; i < 4; ++i)
#pragma unroll
      for (int jn = 0; jn < 4; ++jn)
        acc[i][jn] = mfma16(af[i], bf[jn], acc[i][jn]);
    __syncthreads();
  }
#pragma unroll
  for (int i = 0; i < 4; ++i)
#pragma unroll
    for (int jn = 0; jn < 4; ++jn)
#pragma unroll
      for (int j = 0; j < 4; ++j) {
        int row = bm + wr * 64 + i * 16 + lg * 4 + j;
        int col = bn + wc * 64 + jn * 16 + lr;
        if (col < N) {
          if (CBF16) ((u16*)Cp)[coz * z + (size_t)row * ldc + col] = f2bf(acc[i][jn][j]);
          else ((float*)Cp)[coz * z + (size_t)row * ldc + col] = acc[i][jn][j];
        }
      }
}

// ---------------------------------------------------------------- RMS norms
__global__ __launch_bounds__(256) void rmsnorm_kernel(
    const float* __restrict__ qkv, const float* __restrict__ qw,
    const float* __restrict__ kvw, float* __restrict__ q_cn,
    u16* __restrict__ kv_cn) {
  const int t = blockIdx.x, tid = threadIdx.x;
  const float* row = qkv + (size_t)t * QKVN_;
  __shared__ float red[256];
  float ss = 0.f;
  for (int i = tid; i < QLR_; i += 256) { float v = row[i]; ss += v * v; }
  red[tid] = ss; __syncthreads();
  for (int s = 128; s; s >>= 1) { if (tid < s) red[tid] += red[tid + s]; __syncthreads(); }
  float scl = 1.0f / sqrtf(red[0] / (float)QLR_ + EPS_);
  for (int i = tid; i < QLR_; i += 256)
    q_cn[(size_t)t * QLR_ + i] = row[i] * scl * qw[i];
  __syncthreads();
  ss = 0.f;
  for (int i = tid; i < KVLR_; i += 256) { float v = row[QLR_ + i]; ss += v * v; }
  red[tid] = ss; __syncthreads();
  for (int s = 128; s; s >>= 1) { if (tid < s) red[tid] += red[tid + s]; __syncthreads(); }
  scl = 1.0f / sqrtf(red[0] / (float)KVLR_ + EPS_);
  for (int i = tid; i < KVLR_; i += 256)
    kv_cn[(size_t)t * KVLR_ + i] = f2bf(row[QLR_ + i] * scl * kvw[i]);
}

// ---------------------------------------------------------------- RoPE helpers
__device__ __forceinline__ void rope_pair(float pos, int j, float& x0, float& x1) {
  float inv = powf(10000.f, -(float)j * (1.f / 32.f));
  float f = pos * inv;
  float c = cosf(f), s = sinf(f);
  float a = x0, b = x1;
  x0 = a * c - b * s;
  x1 = a * s + b * c;
}

__global__ __launch_bounds__(256) void rope_qi_kernel(float* __restrict__ qi) {
  const int t = blockIdx.x, tid = threadIdx.x;
  float pos = (float)t;
  for (int idx = tid; idx < IDXH_ * 32; idx += 256) {
    int hh = idx / 32, j = idx % 32;
    float* p = qi + (size_t)t * (IDXH_ * IDXD_) + hh * IDXD_;
    rope_pair(pos, j, p[2 * j], p[2 * j + 1]);
  }
}

__global__ __launch_bounds__(256) void rope_q_bf_kernel(u16* __restrict__ qfb) {
  const int t = blockIdx.x, tid = threadIdx.x;
  float pos = (float)t;
  for (int idx = tid; idx < H_ * 32; idx += 256) {
    int hh = idx / 32, j = idx % 32;
    u16* p = qfb + (size_t)t * (H_ * QKD_) + hh * QKD_ + NOPE_ + 2 * j;
    float x0 = bf2f(p[0]), x1 = bf2f(p[1]);
    rope_pair(pos, j, x0, x1);
    p[0] = f2bf(x0); p[1] = f2bf(x1);
  }
}

__global__ __launch_bounds__(64) void rope_kpe_kernel(
    const float* __restrict__ qkv, u16* __restrict__ kper) {
  const int t = blockIdx.x, tid = threadIdx.x;
  if (tid >= 32) return;
  float pos = (float)t;
  const float* p = qkv + (size_t)t * QKVN_ + (QLR_ + KVLR_);
  float x0 = p[2 * tid], x1 = p[2 * tid + 1];
  rope_pair(pos, tid, x0, x1);
  kper[(size_t)t * ROPE_ + 2 * tid] = f2bf(x0);
  kper[(size_t)t * ROPE_ + 2 * tid + 1] = f2bf(x1);
}

// ---------------------------------------------------------------- ki: LN + rope (f32 in place)
__global__ __launch_bounds__(128) void ki_ln_rope_kernel(
    float* __restrict__ ki, const float* __restrict__ gamma,
    const float* __restrict__ beta) {
  const int t = blockIdx.x, tid = threadIdx.x;
  __shared__ float x[128];
  __shared__ float red[128];
  float v = ki[(size_t)t * IDXD_ + tid];
  red[tid] = v; __syncthreads();
  for (int s = 64; s; s >>= 1) { if (tid < s) red[tid] += red[tid + s]; __syncthreads(); }
  float mu = red[0] / 128.f;
  __syncthreads();
  float d = v - mu;
  red[tid] = d * d; __syncthreads();
  for (int s = 64; s; s >>= 1) { if (tid < s) red[tid] += red[tid + s]; __syncthreads(); }
  float var = red[0] / 128.f;
  float y = d * (1.0f / sqrtf(var + EPS_)) * gamma[tid] + beta[tid];
  x[tid] = y; __syncthreads();
  float pos = (float)t;
  if (tid < 32) {
    float x0 = x[2 * tid], x1 = x[2 * tid + 1];
    rope_pair(pos, tid, x0, x1);
    ki[(size_t)t * IDXD_ + 2 * tid] = x0;
    ki[(size_t)t * IDXD_ + 2 * tid + 1] = x1;
  } else if (tid >= 64) {
    ki[(size_t)t * IDXD_ + tid] = y;
  }
}

// ---------------------------------------------------------------- w epilogue
__global__ __launch_bounds__(256) void w_epi_kernel(
    float* __restrict__ wgt, const float* __restrict__ b) {
  int idx = blockIdx.x * 256 + threadIdx.x;
  if (idx < T_ * IDXH_)
    wgt[idx] = (wgt[idx] + b[idx & 31]) * 0.015625f;
}

// ---------------------------------------------------------------- indexer score (split-f16 MFMA)
__global__ __launch_bounds__(256) void score_mfma(
    const float* __restrict__ qi, const float* __restrict__ ki,
    const float* __restrict__ wgt, float* __restrict__ score) {
  const int s0 = blockIdx.x * 64, t0 = blockIdx.y * 64;
  if (s0 > t0 + 63) return;
  __shared__ u32 Kh[64][68], Kl[64][68], Qh[64][68], Ql[64][68];
  __shared__ float wts[64][33];
  const int tid = threadIdx.x;
  const int wid = tid >> 6, lane = tid & 63, wr = wid >> 1, wc = wid & 1;
  const int lr = lane & 15, lg = lane >> 4;
#pragma unroll
  for (int j = 0; j < 8; ++j) {
    int u = tid + 256 * j; int row = u >> 5, p = u & 31;
    float4 v = *(const float4*)(ki + (size_t)(s0 + row) * IDXD_ + p * 4);
    f16 h0 = (f16)v.x, h1 = (f16)v.y, h2 = (f16)v.z, h3 = (f16)v.w;
    Kh[row][p * 2] = hpack(h0, h1);
    Kh[row][p * 2 + 1] = hpack(h2, h3);
    Kl[row][p * 2] = hpack((f16)(v.x - (float)h0), (f16)(v.y - (float)h1));
    Kl[row][p * 2 + 1] = hpack((f16)(v.z - (float)h2), (f16)(v.w - (float)h3));
  }
#pragma unroll
  for (int j = 0; j < 8; ++j) {
    int u = tid + 256 * j; int r = u >> 5, c = u & 31;
    wts[r][c] = wgt[(size_t)(t0 + r) * IDXH_ + c];
  }
  __syncthreads();
  f16x8 bh[2][4], bl[2][4];
#pragma unroll
  for (int ni = 0; ni < 2; ++ni)
#pragma unroll
    for (int kb = 0; kb < 4; ++kb) {
      bh[ni][kb] = ldh8(&Kh[wc * 32 + ni * 16 + lr][kb * 16 + lg * 4]);
      bl[ni][kb] = ldh8(&Kl[wc * 32 + ni * 16 + lr][kb * 16 + lg * 4]);
    }
  f32x4 fin[2][2] = {};
  for (int h = 0; h < IDXH_; ++h) {
#pragma unroll
    for (int j = 0; j < 8; ++j) {
      int u = tid + 256 * j; int row = u >> 5, p = u & 31;
      float4 v = *(const float4*)(qi + (size_t)(t0 + row) * (IDXH_ * IDXD_) + h * IDXD_ + p * 4);
      f16 h0 = (f16)v.x, h1 = (f16)v.y, h2 = (f16)v.z, h3 = (f16)v.w;
      Qh[row][p * 2] = hpack(h0, h1);
      Qh[row][p * 2 + 1] = hpack(h2, h3);
      Ql[row][p * 2] = hpack((f16)(v.x - (float)h0), (f16)(v.y - (float)h1));
      Ql[row][p * 2 + 1] = hpack((f16)(v.z - (float)h2), (f16)(v.w - (float)h3));
    }
    __syncthreads();
    f32x4 acch[2][2] = {};
#pragma unroll
    for (int kb = 0; kb < 4; ++kb) {
      f16x8 ah0 = ldh8(&Qh[wr * 32 + lr][kb * 16 + lg * 4]);
      f16x8 ah1 = ldh8(&Qh[wr * 32 + 16 + lr][kb * 16 + lg * 4]);
      f16x8 al0 = ldh8(&Ql[wr * 32 + lr][kb * 16 + lg * 4]);
      f16x8 al1 = ldh8(&Ql[wr * 32 + 16 + lr][kb * 16 + lg * 4]);
#pragma unroll
      for (int ni = 0; ni < 2; ++ni) {
        acch[0][ni] = mfmah(ah0, bh[ni][kb], acch[0][ni]);
        acch[0][ni] = mfmah(ah0, bl[ni][kb], acch[0][ni]);
        acch[0][ni] = mfmah(al0, bh[ni][kb], acch[0][ni]);
        acch[1][ni] = mfmah(ah1, bh[ni][kb], acch[1][ni]);
        acch[1][ni] = mfmah(ah1, bl[ni][kb], acch[1][ni]);
        acch[1][ni] = mfmah(al1, bh[ni][kb], acch[1][ni]);
      }
    }
#pragma unroll
    for (int mi = 0; mi < 2; ++mi)
#pragma unroll
      for (int j = 0; j < 4; ++j) {
        float w = wts[wr * 32 + mi * 16 + lg * 4 + j][h];
        fin[mi][0][j] += w * fmaxf(acch[mi][0][j], 0.f);
        fin[mi][1][j] += w * fmaxf(acch[mi][1][j], 0.f);
      }
    __syncthreads();
  }
#pragma unroll
  for (int mi = 0; mi < 2; ++mi)
#pragma unroll
    for (int ni = 0; ni < 2; ++ni)
#pragma unroll
      for (int j = 0; j < 4; ++j) {
        int row = t0 + wr * 32 + mi * 16 + lg * 4 + j;
        int col = s0 + wc * 32 + ni * 16 + lr;
        score[(size_t)row * T_ + col] = fin[mi][ni][j];
      }
}

// ---------------------------------------------------------------- top-k (exact)
__global__ __launch_bounds__(256) void topk_kernel(
    const float* __restrict__ score, int* __restrict__ selidx,
    int* __restrict__ selcnt) {
  const int t = blockIdx.x;
  const int L = t + 1;
  const int tid = threadIdx.x;
  if (L <= TOPK_) {
    for (int j = tid; j < TOPK_; j += 256)
      selidx[(size_t)t * TOPK_ + j] = (j < L) ? j : 0;
    if (tid == 0) selcnt[t] = L;
    return;
  }
  __shared__ unsigned u[T_];
  __shared__ unsigned hist[16];
  __shared__ unsigned sprefix;
  __shared__ int sk;
  __shared__ int part[256];
  for (int i = tid; i < T_; i += 256) {
    float v = (i < L) ? score[(size_t)t * T_ + i] : -FLT_MAX;
    unsigned b = __float_as_uint(v);
    u[i] = (b & 0x80000000u) ? ~b : (b | 0x80000000u);
  }
  if (tid == 0) { sprefix = 0u; sk = TOPK_; }
  __syncthreads();
  for (int pass = 0; pass < 8; ++pass) {
    const int shift = 28 - 4 * pass;
    if (tid < 16) hist[tid] = 0u;
    __syncthreads();
    unsigned pfx = sprefix;
    for (int i = tid; i < L; i += 256) {
      unsigned val = u[i];
      bool match = (pass == 0) || ((val >> (shift + 4)) == pfx);
      if (match) atomicAdd(&hist[(val >> shift) & 15u], 1u);
    }
    __syncthreads();
    if (tid == 0) {
      int k = sk; unsigned cum = 0u; int bsel = 0;
      for (int bb = 15; bb >= 0; --bb) {
        if (cum + hist[bb] >= (unsigned)k) { bsel = bb; sk = k - (int)cum; break; }
        cum += hist[bb];
      }
      sprefix = (sprefix << 4) | (unsigned)bsel;
    }
    __syncthreads();
  }
  const unsigned thr = sprefix;
  const int kEq = sk;
  const int base = tid * 8;
  int eqloc[8]; int esum = 0;
  for (int r = 0; r < 8; ++r) {
    int i = base + r;
    int f = (i < L && u[i] == thr) ? 1 : 0;
    eqloc[r] = esum; esum += f;
  }
  part[tid] = esum; __syncthreads();
  for (int off = 1; off < 256; off <<= 1) {
    int v = (tid >= off) ? part[tid - off] : 0;
    __syncthreads();
    part[tid] += v;
    __syncthreads();
  }
  const int ebase = (tid > 0) ? part[tid - 1] : 0;
  __syncthreads();
  int sloc[8], selflag[8]; int ssum = 0;
  for (int r = 0; r < 8; ++r) {
    int i = base + r;
    int f = 0;
    if (i < L) {
      unsigned ui = u[i];
      if (ui > thr) f = 1;
      else if (ui == thr && (ebase + eqloc[r]) < kEq) f = 1;
    }
    selflag[r] = f; sloc[r] = ssum; ssum += f;
  }
  part[tid] = ssum; __syncthreads();
  for (int off = 1; off < 256; off <<= 1) {
    int v = (tid >= off) ? part[tid - off] : 0;
    __syncthreads();
    part[tid] += v;
    __syncthreads();
  }
  const int sbase = (tid > 0) ? part[tid - 1] : 0;
  for (int r = 0; r < 8; ++r)
    if (selflag[r]) selidx[(size_t)t * TOPK_ + sbase + sloc[r]] = base + r;
  if (tid == 0) selcnt[t] = TOPK_;
}

// ---------------------------------------------------------------- MLA attention v2
// QK^T: K fragments straight from L2 (kvcn is 2MB, L2-resident). Each wave owns
// 128 keys. PV: 32-key chunks staged in LDS with XOR swizzle (conflict-free
// transpose read). LDS ~51KB -> 3 blocks/CU.
__global__ __launch_bounds__(256, 3) void attn_mla_kernel(
    const u16* __restrict__ qeff, const u16* __restrict__ qfb,
    const u16* __restrict__ kvcn, const u16* __restrict__ kper,
    const int* __restrict__ selidx, const int* __restrict__ selcnt,
    u16* __restrict__ Olat) {
  const int t = blockIdx.x;
  const int tid = threadIdx.x;
  const int wid = tid >> 6, lane = tid & 63;
  const int lr = lane & 15, lg = lane >> 4;
  __shared__ int sidxs[512];
  __shared__ u16 Pb[16][520];
  __shared__ u16 Vs[32 * 512];            // XOR-swizzled: idx ^= ((row>>3)&3)<<4
  __shared__ float redm[4][16];
  __shared__ float reds[4][16];
  const int cnt = selcnt[t];
  for (int j = tid; j < 512; j += 256) sidxs[j] = selidx[(size_t)t * TOPK_ + j];
  __syncthreads();

  // ---- QK^T: wave wid owns keys [wid*128, wid*128+128), 8 M-tiles of 16
  int srow[8];
#pragma unroll
  for (int m = 0; m < 8; ++m) srow[m] = sidxs[wid * 128 + m * 16 + lr];

  const u16* qe = qeff + (size_t)t * (H_ * 512) + lr * 512;
  const u16* qp = qfb + (size_t)t * (H_ * QKD_) + lr * QKD_ + NOPE_;
  f32x4 lgv[8] = {};
#pragma unroll
  for (int kb = 0; kb < 18; ++kb) {
    bf16x8 qfk = (kb < 16) ? ld8(qe + kb * 32 + lg * 8)
                           : ld8(qp + (kb - 16) * 32 + lg * 8);
#pragma unroll
    for (int m = 0; m < 8; ++m) {
      const u16* kr = (kb < 16)
          ? (kvcn + (size_t)srow[m] * 512 + kb * 32 + lg * 8)
          : (kper + (size_t)srow[m] * 64 + (kb - 16) * 32 + lg * 8);
      lgv[m] = mfma16(ld8(kr), qfk, lgv[m]);
    }
  }

  // ---- softmax (head = lr; slot = wid*128 + m*16 + lg*4 + j)
  float mx = -FLT_MAX;
#pragma unroll
  for (int m = 0; m < 8; ++m)
#pragma unroll
    for (int j = 0; j < 4; ++j) {
      int slot = wid * 128 + m * 16 + lg * 4 + j;
      float v = (slot < cnt) ? lgv[m][j] * SCALING_ : -FLT_MAX;
      lgv[m][j] = v;
      mx = fmaxf(mx, v);
    }
  mx = fmaxf(mx, __shfl_xor(mx, 16));
  mx = fmaxf(mx, __shfl_xor(mx, 32));
  if (lane < 16) redm[wid][lane] = mx;
  __syncthreads();
  float hm = fmaxf(fmaxf(redm[0][lr], redm[1][lr]), fmaxf(redm[2][lr], redm[3][lr]));
  float sm = 0.f;
#pragma unroll
  for (int m = 0; m < 8; ++m)
#pragma unroll
    for (int j = 0; j < 4; ++j) {
      int slot = wid * 128 + m * 16 + lg * 4 + j;
      float e = (slot < cnt) ? expf(lgv[m][j] - hm) : 0.f;
      lgv[m][j] = e; sm += e;
    }
  sm += __shfl_xor(sm, 16);
  sm += __shfl_xor(sm, 32);
  if (lane < 16) reds[wid][lane] = sm;
  __syncthreads();
  float inv = 1.f / (reds[0][lr] + reds[1][lr] + reds[2][lr] + reds[3][lr]);
#pragma unroll
  for (int m = 0; m < 8; ++m) {
    int sl = wid * 128 + m * 16 + lg * 4;
    *(u32*)&Pb[lr][sl] = pack2(lgv[m][0] * inv, lgv[m][1] * inv);
    *(u32*)&Pb[lr][sl + 2] = pack2(lgv[m][2] * inv, lgv[m][3] * inv);
  }

  // ---- PV: O[16 heads, 512 dims] = P @ V, 16 chunks of 32 keys
  f32x4 oacc[8] = {};
  uint4 vh[8];
#pragma unroll
  for (int j = 0; j < 8; ++j) {            // prefetch chunk 0
    int u = tid + 256 * j; int row = u >> 6, piece = u & 63;
    int s = sidxs[row];
    vh[j] = *(const uint4*)(kvcn + (size_t)s * 512 + piece * 8);
  }
  const int colb = wid * 128 + lr;
  for (int c = 0; c < 16; ++c) {
#pragma unroll
    for (int j = 0; j < 8; ++j) {          // swizzled store of chunk c
      int u = tid + 256 * j; int row = u >> 6, piece = u & 63;
      int idx = (row * 512 + piece * 8) ^ (((row >> 3) & 3) << 4);
      *(uint4*)&Vs[idx] = vh[j];
    }
    __syncthreads();
    if (c < 15) {
#pragma unroll
      for (int j = 0; j < 8; ++j) {        // prefetch chunk c+1
        int u = tid + 256 * j; int row = u >> 6, piece = u & 63;
        int s = sidxs[(c + 1) * 32 + row];
        vh[j] = *(const uint4*)(kvcn + (size_t)s * 512 + piece * 8);
      }
    }
    bf16x8 pa = ld8(&Pb[lr][c * 32 + lg * 8]);
#pragma unroll
    for (int C = 0; C < 8; ++C) {
      union { u32 u[4]; bf16x8 v; } bb;
#pragma unroll
      for (int e = 0; e < 4; ++e) {
        int r0 = lg * 8 + 2 * e;
        int sw = ((r0 >> 3) & 3) << 4;     // same for r0 and r0+1
        int base = r0 * 512 + colb + C * 16;
        bb.u[e] = (u32)Vs[base ^ sw] | ((u32)Vs[(base + 512) ^ sw] << 16);
      }
      oacc[C] = mfma16(pa, bb.v, oacc[C]);
    }
    __syncthreads();
  }
#pragma unroll
  for (int C = 0; C < 8; ++C)
#pragma unroll
    for (int j = 0; j < 4; ++j) {
      int h = lg * 4 + j;
      Olat[(size_t)t * (H_ * 512) + h * 512 + wid * 128 + C * 16 + lr] = f2bf(oacc[C][j]);
    }
}

// ---------------------------------------------------------------- launch
extern "C" void kernel_launch(void* const* d_in, const int* in_sizes, int n_in,
                              void* d_out, int out_size, void* d_ws, size_t ws_size,
                              hipStream_t stream) {
  const float* hidden    = (const float*)d_in[1];
  const float* w_qkv_a   = (const float*)d_in[2];
  const float* q_a_ln_w  = (const float*)d_in[3];
  const float* w_qb      = (const float*)d_in[4];
  const float* kv_a_ln_w = (const float*)d_in[5];
  const float* w_kvb     = (const float*)d_in[6];
  const float* w_o       = (const float*)d_in[7];
  const float* w_idx_qb  = (const float*)d_in[8];
  const float* w_idx_k   = (const float*)d_in[9];
  const float* idx_g     = (const float*)d_in[10];
  const float* idx_b     = (const float*)d_in[11];
  const float* w_wproj   = (const float*)d_in[12];
  const float* b_wproj   = (const float*)d_in[13];

  char* W = (char*)d_ws;
  size_t o = 0;
  auto alloc = [&](size_t bytes) { void* p = W + o; o += (bytes + 255) & ~(size_t)255; return p; };
  float* q_cn   = (float*)alloc((size_t)T_ * QLR_ * 4);
  u16*   kv_cn  = (u16*)alloc((size_t)T_ * KVLR_ * 2);
  u16*   kper   = (u16*)alloc((size_t)T_ * ROPE_ * 2);
  int*   selidx = (int*)alloc((size_t)T_ * TOPK_ * 4);
  int*   selcnt = (int*)alloc((size_t)T_ * 4);
  float* wgt    = (float*)alloc((size_t)T_ * IDXH_ * 4);
  float* ki     = (float*)alloc((size_t)T_ * IDXD_ * 4);
  float* qi     = (float*)alloc((size_t)T_ * IDXH_ * IDXD_ * 4);
  u16*   qeff   = (u16*)qi;
  float* score  = (float*)alloc((size_t)T_ * T_ * 4);
  u16*   attno  = (u16*)score;
  float* wqat   = (float*)alloc((size_t)QKVN_ * HID_ * 4);
  float* qkv    = (float*)alloc((size_t)T_ * QKVN_ * 4);
  u16*   Olat   = (u16*)wqat;
  float* wiqt   = (float*)alloc((size_t)(IDXH_ * IDXD_) * QLR_ * 4);
  u16*   qfb    = (u16*)wiqt;
  float* wikt   = (float*)alloc((size_t)IDXD_ * HID_ * 4);
  float* wwpt   = (float*)alloc((size_t)IDXH_ * HID_ * 4);
  u16*   wqbt   = (u16*)alloc((size_t)(H_ * QKD_) * QLR_ * 2);
  u16*   wkvb   = (u16*)alloc((size_t)KVLR_ * (H_ * 256) * 2);
  u16*   wkvbt  = (u16*)alloc((size_t)(H_ * 256) * KVLR_ * 2);
  u16*   wot    = (u16*)alloc((size_t)(H_ * VD_) * HID_ * 2);

  dim3 blk(256);
  auto g2 = [](int M, int N, int Z) { return dim3((N + 127) / 128, M / 128, Z); };

  // weight prep
  transpose_f32_k<<<dim3(33, 32), blk, 0, stream>>>(w_qkv_a, wqat, HID_, QKVN_);
  transpose_f32_k<<<dim3(64, 24), blk, 0, stream>>>(w_idx_qb, wiqt, QLR_, IDXH_ * IDXD_);
  transpose_f32_k<<<dim3(2, 32), blk, 0, stream>>>(w_idx_k, wikt, HID_, IDXD_);
  transpose_f32_k<<<dim3(1, 32), blk, 0, stream>>>(w_wproj, wwpt, HID_, IDXH_);
  transpose_bf16_k<<<dim3(48, 24), blk, 0, stream>>>(w_qb, wqbt, QLR_, H_ * QKD_);
  transpose_bf16_k<<<dim3(64, 8), blk, 0, stream>>>(w_kvb, wkvbt, KVLR_, H_ * 256);
  transpose_bf16_k<<<dim3(32, 32), blk, 0, stream>>>(w_o, wot, H_ * VD_, HID_);
  conv_bf16_k<<<2048, blk, 0, stream>>>(w_kvb, wkvb, (long)KVLR_ * H_ * 256);

  // strict path (f16-split MFMA)
  gemm_split<<<g2(T_, QKVN_, 1), blk, 0, stream>>>(hidden, HID_, wqat, HID_, qkv, QKVN_, QKVN_, HID_);
  rmsnorm_kernel<<<T_, blk, 0, stream>>>(qkv, q_a_ln_w, kv_a_ln_w, q_cn, kv_cn);
  rope_kpe_kernel<<<T_, 64, 0, stream>>>(qkv, kper);

  gemm_split<<<g2(T_, IDXH_ * IDXD_, 1), blk, 0, stream>>>(q_cn, QLR_, wiqt, QLR_, qi, IDXH_ * IDXD_, IDXH_ * IDXD_, QLR_);
  rope_qi_kernel<<<T_, blk, 0, stream>>>(qi);
  gemm_split<<<g2(T_, IDXD_, 1), blk, 0, stream>>>(hidden, HID_, wikt, HID_, ki, IDXD_, IDXD_, HID_);
  ki_ln_rope_kernel<<<T_, 128, 0, stream>>>(ki, idx_g, idx_b);
  gemm_split<<<g2(T_, IDXH_, 1), blk, 0, stream>>>(hidden, HID_, wwpt, HID_, wgt, IDXH_, IDXH_, HID_);
  w_epi_kernel<<<(T_ * IDXH_ + 255) / 256, blk, 0, stream>>>(wgt, b_wproj);

  score_mfma<<<dim3(32, 32), blk, 0, stream>>>(qi, ki, wgt, score);
  topk_kernel<<<T_, blk, 0, stream>>>(score, selidx, selcnt);

  // tolerant path (bf16 MFMA)
  gemm_t<1, 1><<<g2(T_, H_ * QKD_, 1), blk, 0, stream>>>(q_cn, QLR_, 0, wqbt, QLR_, 0, qfb, H_ * QKD_, 0, H_ * QKD_, QLR_);
  rope_q_bf_kernel<<<T_, blk, 0, stream>>>(qfb);
  gemm_t<0, 1><<<g2(T_, 512, H_), blk, 0, stream>>>(qfb, H_ * QKD_, QKD_, wkvb, H_ * 256, 256, qeff, H_ * 512, 512, 512, NOPE_);
  attn_mla_kernel<<<T_, blk, 0, stream>>>(qeff, qfb, kv_cn, kper, selidx, selcnt, Olat);
  gemm_t<0, 1><<<g2(T_, VD_, H_), blk, 0, stream>>>(Olat, H_ * 512, 512, wkvbt + 128 * 512, KVLR_, 256 * 512, attno, H_ * VD_, VD_, VD_, 512);
  gemm_t<0, 0><<<g2(T_, HID_, 1), blk, 0, stream>>>(attno, H_ * VD_, 0, wot, H_ * VD_, 0, d_out, HID_, 0, HID_, H_ * VD_);
}

// Round 6
// 1252.424 us; speedup vs baseline: 4.0048x; 1.2084x over previous
//
#include <hip/hip_runtime.h>
#include <cfloat>
#include <cmath>

#define T_    2048
#define HID_  2048
#define QKVN_ 2112
#define QLR_  1536
#define KVLR_ 512
#define ROPE_ 64
#define NOPE_ 128
#define QKD_  192
#define VD_   128
#define H_    16
#define IDXH_ 32
#define IDXD_ 128
#define TOPK_ 512
#define EPS_  1e-6f
#define SCALING_ 0.07216878364870323f   // 192^-0.5

typedef unsigned int u32;
typedef unsigned short u16;
typedef __bf16 bf16x8 __attribute__((ext_vector_type(8)));
typedef _Float16 f16;
typedef f16 f16x8 __attribute__((ext_vector_type(8)));
typedef float f32x4 __attribute__((ext_vector_type(4)));

__device__ __forceinline__ u16 f2bf(float x) {
  u32 u = __float_as_uint(x);
  u32 r = (u + 0x7fffu + ((u >> 16) & 1u)) >> 16;
  return (u16)r;
}
__device__ __forceinline__ float bf2f(u16 h) { return __uint_as_float(((u32)h) << 16); }
__device__ __forceinline__ u32 pack2(float a, float b) { return (u32)f2bf(a) | ((u32)f2bf(b) << 16); }
__device__ __forceinline__ bf16x8 ld8(const void* p) { return *(const bf16x8*)p; }
__device__ __forceinline__ f32x4 mfma16(bf16x8 a, bf16x8 b, f32x4 c) {
  return __builtin_amdgcn_mfma_f32_16x16x32_bf16(a, b, c, 0, 0, 0);
}
// ---- fp16 helpers (strict path: hi+lo split covers ~22 mantissa bits)
__device__ __forceinline__ u16 hbits(f16 h) { union { f16 h; u16 u; } c; c.h = h; return c.u; }
__device__ __forceinline__ u32 hpack(f16 a, f16 b) { return (u32)hbits(a) | ((u32)hbits(b) << 16); }
__device__ __forceinline__ f16x8 ldh8(const void* p) { return *(const f16x8*)p; }
__device__ __forceinline__ f32x4 mfmah(f16x8 a, f16x8 b, f32x4 c) {
  return __builtin_amdgcn_mfma_f32_16x16x32_f16(a, b, c, 0, 0, 0);
}
// ---- async global->LDS 16B DMA (no VGPR staging, nothing to spill)
__device__ __forceinline__ void gload16(const u16* g, u16* l) {
  __builtin_amdgcn_global_load_lds(
      (__attribute__((address_space(1))) void*)(g),
      (__attribute__((address_space(3))) void*)(l), 16, 0, 0);
}

// ---------------------------------------------------------------- transposes / converts
__global__ __launch_bounds__(256) void transpose_f32_k(
    const float* __restrict__ in, float* __restrict__ out, int K, int N) {
  __shared__ float t[64][65];
  int k0 = blockIdx.y * 64, n0 = blockIdx.x * 64;
  for (int j = 0; j < 16; ++j) {
    int u = threadIdx.x + 256 * j; int r = u >> 6, c = u & 63;
    t[r][c] = (k0 + r < K && n0 + c < N) ? in[(size_t)(k0 + r) * N + n0 + c] : 0.f;
  }
  __syncthreads();
  for (int j = 0; j < 16; ++j) {
    int u = threadIdx.x + 256 * j; int r = u >> 6, c = u & 63;
    if (n0 + r < N && k0 + c < K) out[(size_t)(n0 + r) * K + k0 + c] = t[c][r];
  }
}

__global__ __launch_bounds__(256) void transpose_bf16_k(
    const float* __restrict__ in, u16* __restrict__ out, int K, int N) {
  __shared__ float t[64][65];
  int k0 = blockIdx.y * 64, n0 = blockIdx.x * 64;
  for (int j = 0; j < 16; ++j) {
    int u = threadIdx.x + 256 * j; int r = u >> 6, c = u & 63;
    t[r][c] = (k0 + r < K && n0 + c < N) ? in[(size_t)(k0 + r) * N + n0 + c] : 0.f;
  }
  __syncthreads();
  for (int j = 0; j < 16; ++j) {
    int u = threadIdx.x + 256 * j; int r = u >> 6, c = u & 63;
    if (n0 + r < N && k0 + c < K) out[(size_t)(n0 + r) * K + k0 + c] = f2bf(t[c][r]);
  }
}

__global__ __launch_bounds__(256) void conv_bf16_k(
    const float* __restrict__ in, u16* __restrict__ out, long n) {
  for (long i = ((long)blockIdx.x * 256 + threadIdx.x) * 4; i < n; i += (long)gridDim.x * 1024) {
    float4 v = *(const float4*)(in + i);
    u32 a = pack2(v.x, v.y), b = pack2(v.z, v.w);
    *(u32*)(out + i) = a; *(u32*)(out + i + 2) = b;
  }
}

// ---------------------------------------------------------------- strict split-f16 GEMM
__global__ __launch_bounds__(256) void gemm_split(
    const float* __restrict__ A, int lda,
    const float* __restrict__ Bt, int ldb,
    float* __restrict__ C, int ldc, int N, int K) {
  __shared__ u32 Ah[128][20], Al[128][20], Bh[128][20], Bl[128][20];
  const int tid = threadIdx.x;
  const int bm = blockIdx.y * 128, bn = blockIdx.x * 128;
  const int wid = tid >> 6, lane = tid & 63, wr = wid >> 1, wc = wid & 1;
  const int lr = lane & 15, lg = lane >> 4;
  f32x4 acc[4][4] = {};
  for (int k0 = 0; k0 < K; k0 += 32) {
#pragma unroll
    for (int j = 0; j < 4; ++j) {
      int u = tid + 256 * j; int row = u >> 3, p = u & 7;
      float4 v = *(const float4*)(A + (size_t)(bm + row) * lda + k0 + p * 4);
      f16 h0 = (f16)v.x, h1 = (f16)v.y, h2 = (f16)v.z, h3 = (f16)v.w;
      Ah[row][p * 2] = hpack(h0, h1);
      Ah[row][p * 2 + 1] = hpack(h2, h3);
      Al[row][p * 2] = hpack((f16)(v.x - (float)h0), (f16)(v.y - (float)h1));
      Al[row][p * 2 + 1] = hpack((f16)(v.z - (float)h2), (f16)(v.w - (float)h3));
    }
#pragma unroll
    for (int j = 0; j < 4; ++j) {
      int u = tid + 256 * j; int row = u >> 3, p = u & 7;
      float4 v = make_float4(0.f, 0.f, 0.f, 0.f);
      if (bn + row < N) v = *(const float4*)(Bt + (size_t)(bn + row) * ldb + k0 + p * 4);
      f16 h0 = (f16)v.x, h1 = (f16)v.y, h2 = (f16)v.z, h3 = (f16)v.w;
      Bh[row][p * 2] = hpack(h0, h1);
      Bh[row][p * 2 + 1] = hpack(h2, h3);
      Bl[row][p * 2] = hpack((f16)(v.x - (float)h0), (f16)(v.y - (float)h1));
      Bl[row][p * 2 + 1] = hpack((f16)(v.z - (float)h2), (f16)(v.w - (float)h3));
    }
    __syncthreads();
    f16x8 ah[4], al[4], bh[4], bl[4];
#pragma unroll
    for (int i = 0; i < 4; ++i) {
      ah[i] = ldh8(&Ah[wr * 64 + i * 16 + lr][lg * 4]);
      al[i] = ldh8(&Al[wr * 64 + i * 16 + lr][lg * 4]);
      bh[i] = ldh8(&Bh[wc * 64 + i * 16 + lr][lg * 4]);
      bl[i] = ldh8(&Bl[wc * 64 + i * 16 + lr][lg * 4]);
    }
#pragma unroll
    for (int i = 0; i < 4; ++i)
#pragma unroll
      for (int jn = 0; jn < 4; ++jn) {
        acc[i][jn] = mfmah(ah[i], bh[jn], acc[i][jn]);
        acc[i][jn] = mfmah(ah[i], bl[jn], acc[i][jn]);
        acc[i][jn] = mfmah(al[i], bh[jn], acc[i][jn]);
      }
    __syncthreads();
  }
#pragma unroll
  for (int i = 0; i < 4; ++i)
#pragma unroll
    for (int jn = 0; jn < 4; ++jn)
#pragma unroll
      for (int j = 0; j < 4; ++j) {
        int row = bm + wr * 64 + i * 16 + lg * 4 + j;
        int col = bn + wc * 64 + jn * 16 + lr;
        if (col < N) C[(size_t)row * ldc + col] = acc[i][jn][j];
      }
}

// ---------------------------------------------------------------- tolerant bf16 GEMM
template <int AF32, int CBF16>
__global__ __launch_bounds__(256) void gemm_t(
    const void* __restrict__ Ap, int lda, long aoz,
    const u16* __restrict__ Bt, int ldb, long boz,
    void* __restrict__ Cp, int ldc, long coz, int N, int K) {
  __shared__ u32 As[128][20], Bs[128][20];
  const int tid = threadIdx.x;
  const int z = blockIdx.z;
  const int bm = blockIdx.y * 128, bn = blockIdx.x * 128;
  const int wid = tid >> 6, lane = tid & 63, wr = wid >> 1, wc = wid & 1;
  const int lr = lane & 15, lg = lane >> 4;
  f32x4 acc[4][4] = {};
  for (int k0 = 0; k0 < K; k0 += 32) {
    if (AF32) {
      const float* A = (const float*)Ap + aoz * z;
#pragma unroll
      for (int j = 0; j < 4; ++j) {
        int u = tid + 256 * j; int row = u >> 3, p = u & 7;
        float4 v = *(const float4*)(A + (size_t)(bm + row) * lda + k0 + p * 4);
        As[row][p * 2] = pack2(v.x, v.y);
        As[row][p * 2 + 1] = pack2(v.z, v.w);
      }
    } else {
      const u16* A = (const u16*)Ap + aoz * z;
#pragma unroll
      for (int j = 0; j < 2; ++j) {
        int u = tid + 256 * j; int row = u >> 2, p = u & 3;
        uint4 v = *(const uint4*)(A + (size_t)(bm + row) * lda + k0 + p * 8);
        *(uint4*)&As[row][p * 4] = v;
      }
    }
#pragma unroll
    for (int j = 0; j < 2; ++j) {
      int u = tid + 256 * j; int row = u >> 2, p = u & 3;
      uint4 v = make_uint4(0, 0, 0, 0);
      if (bn + row < N) v = *(const uint4*)(Bt + boz * z + (size_t)(bn + row) * ldb + k0 + p * 8);
      *(uint4*)&Bs[row][p * 4] = v;
    }
    __syncthreads();
    bf16x8 af[4], bf[4];
#pragma unroll
    for (int i = 0; i < 4; ++i) {
      af[i] = ld8(&As[wr * 64 + i * 16 + lr][lg * 4]);
      bf[i] = ld8(&Bs[wc * 64 + i * 16 + lr][lg * 4]);
    }
#pragma unroll
    for (int i = 0; i < 4; ++i)
#pragma unroll
      for (int jn = 0; jn < 4; ++jn)
        acc[i][jn] = mfma16(af[i], bf[jn], acc[i][jn]);
    __syncthreads();
  }
#pragma unroll
  for (int i = 0; i < 4; ++i)
#pragma unroll
    for (int jn = 0; jn < 4; ++jn)
#pragma unroll
      for (int j = 0; j < 4; ++j) {
        int row = bm + wr * 64 + i * 16 + lg * 4 + j;
        int col = bn + wc * 64 + jn * 16 + lr;
        if (col < N) {
          if (CBF16) ((u16*)Cp)[coz * z + (size_t)row * ldc + col] = f2bf(acc[i][jn][j]);
          else ((float*)Cp)[coz * z + (size_t)row * ldc + col] = acc[i][jn][j];
        }
      }
}

// ---------------------------------------------------------------- RMS norms
__global__ __launch_bounds__(256) void rmsnorm_kernel(
    const float* __restrict__ qkv, const float* __restrict__ qw,
    const float* __restrict__ kvw, float* __restrict__ q_cn,
    u16* __restrict__ kv_cn) {
  const int t = blockIdx.x, tid = threadIdx.x;
  const float* row = qkv + (size_t)t * QKVN_;
  __shared__ float red[256];
  float ss = 0.f;
  for (int i = tid; i < QLR_; i += 256) { float v = row[i]; ss += v * v; }
  red[tid] = ss; __syncthreads();
  for (int s = 128; s; s >>= 1) { if (tid < s) red[tid] += red[tid + s]; __syncthreads(); }
  float scl = 1.0f / sqrtf(red[0] / (float)QLR_ + EPS_);
  for (int i = tid; i < QLR_; i += 256)
    q_cn[(size_t)t * QLR_ + i] = row[i] * scl * qw[i];
  __syncthreads();
  ss = 0.f;
  for (int i = tid; i < KVLR_; i += 256) { float v = row[QLR_ + i]; ss += v * v; }
  red[tid] = ss; __syncthreads();
  for (int s = 128; s; s >>= 1) { if (tid < s) red[tid] += red[tid + s]; __syncthreads(); }
  scl = 1.0f / sqrtf(red[0] / (float)KVLR_ + EPS_);
  for (int i = tid; i < KVLR_; i += 256)
    kv_cn[(size_t)t * KVLR_ + i] = f2bf(row[QLR_ + i] * scl * kvw[i]);
}

// ---------------------------------------------------------------- RoPE helpers
__device__ __forceinline__ void rope_pair(float pos, int j, float& x0, float& x1) {
  float inv = powf(10000.f, -(float)j * (1.f / 32.f));
  float f = pos * inv;
  float c = cosf(f), s = sinf(f);
  float a = x0, b = x1;
  x0 = a * c - b * s;
  x1 = a * s + b * c;
}

__global__ __launch_bounds__(256) void rope_qi_kernel(float* __restrict__ qi) {
  const int t = blockIdx.x, tid = threadIdx.x;
  float pos = (float)t;
  for (int idx = tid; idx < IDXH_ * 32; idx += 256) {
    int hh = idx / 32, j = idx % 32;
    float* p = qi + (size_t)t * (IDXH_ * IDXD_) + hh * IDXD_;
    rope_pair(pos, j, p[2 * j], p[2 * j + 1]);
  }
}

__global__ __launch_bounds__(256) void rope_q_bf_kernel(u16* __restrict__ qfb) {
  const int t = blockIdx.x, tid = threadIdx.x;
  float pos = (float)t;
  for (int idx = tid; idx < H_ * 32; idx += 256) {
    int hh = idx / 32, j = idx % 32;
    u16* p = qfb + (size_t)t * (H_ * QKD_) + hh * QKD_ + NOPE_ + 2 * j;
    float x0 = bf2f(p[0]), x1 = bf2f(p[1]);
    rope_pair(pos, j, x0, x1);
    p[0] = f2bf(x0); p[1] = f2bf(x1);
  }
}

__global__ __launch_bounds__(64) void rope_kpe_kernel(
    const float* __restrict__ qkv, u16* __restrict__ kper) {
  const int t = blockIdx.x, tid = threadIdx.x;
  if (tid >= 32) return;
  float pos = (float)t;
  const float* p = qkv + (size_t)t * QKVN_ + (QLR_ + KVLR_);
  float x0 = p[2 * tid], x1 = p[2 * tid + 1];
  rope_pair(pos, tid, x0, x1);
  kper[(size_t)t * ROPE_ + 2 * tid] = f2bf(x0);
  kper[(size_t)t * ROPE_ + 2 * tid + 1] = f2bf(x1);
}

// ---------------------------------------------------------------- ki: LN + rope (f32 in place)
__global__ __launch_bounds__(128) void ki_ln_rope_kernel(
    float* __restrict__ ki, const float* __restrict__ gamma,
    const float* __restrict__ beta) {
  const int t = blockIdx.x, tid = threadIdx.x;
  __shared__ float x[128];
  __shared__ float red[128];
  float v = ki[(size_t)t * IDXD_ + tid];
  red[tid] = v; __syncthreads();
  for (int s = 64; s; s >>= 1) { if (tid < s) red[tid] += red[tid + s]; __syncthreads(); }
  float mu = red[0] / 128.f;
  __syncthreads();
  float d = v - mu;
  red[tid] = d * d; __syncthreads();
  for (int s = 64; s; s >>= 1) { if (tid < s) red[tid] += red[tid + s]; __syncthreads(); }
  float var = red[0] / 128.f;
  float y = d * (1.0f / sqrtf(var + EPS_)) * gamma[tid] + beta[tid];
  x[tid] = y; __syncthreads();
  float pos = (float)t;
  if (tid < 32) {
    float x0 = x[2 * tid], x1 = x[2 * tid + 1];
    rope_pair(pos, tid, x0, x1);
    ki[(size_t)t * IDXD_ + 2 * tid] = x0;
    ki[(size_t)t * IDXD_ + 2 * tid + 1] = x1;
  } else if (tid >= 64) {
    ki[(size_t)t * IDXD_ + tid] = y;
  }
}

// ---------------------------------------------------------------- w epilogue
__global__ __launch_bounds__(256) void w_epi_kernel(
    float* __restrict__ wgt, const float* __restrict__ b) {
  int idx = blockIdx.x * 256 + threadIdx.x;
  if (idx < T_ * IDXH_)
    wgt[idx] = (wgt[idx] + b[idx & 31]) * 0.015625f;
}

// ---------------------------------------------------------------- indexer score (split-f16 MFMA)
__global__ __launch_bounds__(256) void score_mfma(
    const float* __restrict__ qi, const float* __restrict__ ki,
    const float* __restrict__ wgt, float* __restrict__ score) {
  const int s0 = blockIdx.x * 64, t0 = blockIdx.y * 64;
  if (s0 > t0 + 63) return;
  __shared__ u32 Kh[64][68], Kl[64][68], Qh[64][68], Ql[64][68];
  __shared__ float wts[64][33];
  const int tid = threadIdx.x;
  const int wid = tid >> 6, lane = tid & 63, wr = wid >> 1, wc = wid & 1;
  const int lr = lane & 15, lg = lane >> 4;
#pragma unroll
  for (int j = 0; j < 8; ++j) {
    int u = tid + 256 * j; int row = u >> 5, p = u & 31;
    float4 v = *(const float4*)(ki + (size_t)(s0 + row) * IDXD_ + p * 4);
    f16 h0 = (f16)v.x, h1 = (f16)v.y, h2 = (f16)v.z, h3 = (f16)v.w;
    Kh[row][p * 2] = hpack(h0, h1);
    Kh[row][p * 2 + 1] = hpack(h2, h3);
    Kl[row][p * 2] = hpack((f16)(v.x - (float)h0), (f16)(v.y - (float)h1));
    Kl[row][p * 2 + 1] = hpack((f16)(v.z - (float)h2), (f16)(v.w - (float)h3));
  }
#pragma unroll
  for (int j = 0; j < 8; ++j) {
    int u = tid + 256 * j; int r = u >> 5, c = u & 31;
    wts[r][c] = wgt[(size_t)(t0 + r) * IDXH_ + c];
  }
  __syncthreads();
  f16x8 bh[2][4], bl[2][4];
#pragma unroll
  for (int ni = 0; ni < 2; ++ni)
#pragma unroll
    for (int kb = 0; kb < 4; ++kb) {
      bh[ni][kb] = ldh8(&Kh[wc * 32 + ni * 16 + lr][kb * 16 + lg * 4]);
      bl[ni][kb] = ldh8(&Kl[wc * 32 + ni * 16 + lr][kb * 16 + lg * 4]);
    }
  f32x4 fin[2][2] = {};
  for (int h = 0; h < IDXH_; ++h) {
#pragma unroll
    for (int j = 0; j < 8; ++j) {
      int u = tid + 256 * j; int row = u >> 5, p = u & 31;
      float4 v = *(const float4*)(qi + (size_t)(t0 + row) * (IDXH_ * IDXD_) + h * IDXD_ + p * 4);
      f16 h0 = (f16)v.x, h1 = (f16)v.y, h2 = (f16)v.z, h3 = (f16)v.w;
      Qh[row][p * 2] = hpack(h0, h1);
      Qh[row][p * 2 + 1] = hpack(h2, h3);
      Ql[row][p * 2] = hpack((f16)(v.x - (float)h0), (f16)(v.y - (float)h1));
      Ql[row][p * 2 + 1] = hpack((f16)(v.z - (float)h2), (f16)(v.w - (float)h3));
    }
    __syncthreads();
    f32x4 acch[2][2] = {};
#pragma unroll
    for (int kb = 0; kb < 4; ++kb) {
      f16x8 ah0 = ldh8(&Qh[wr * 32 + lr][kb * 16 + lg * 4]);
      f16x8 ah1 = ldh8(&Qh[wr * 32 + 16 + lr][kb * 16 + lg * 4]);
      f16x8 al0 = ldh8(&Ql[wr * 32 + lr][kb * 16 + lg * 4]);
      f16x8 al1 = ldh8(&Ql[wr * 32 + 16 + lr][kb * 16 + lg * 4]);
#pragma unroll
      for (int ni = 0; ni < 2; ++ni) {
        acch[0][ni] = mfmah(ah0, bh[ni][kb], acch[0][ni]);
        acch[0][ni] = mfmah(ah0, bl[ni][kb], acch[0][ni]);
        acch[0][ni] = mfmah(al0, bh[ni][kb], acch[0][ni]);
        acch[1][ni] = mfmah(ah1, bh[ni][kb], acch[1][ni]);
        acch[1][ni] = mfmah(ah1, bl[ni][kb], acch[1][ni]);
        acch[1][ni] = mfmah(al1, bh[ni][kb], acch[1][ni]);
      }
    }
#pragma unroll
    for (int mi = 0; mi < 2; ++mi)
#pragma unroll
      for (int j = 0; j < 4; ++j) {
        float w = wts[wr * 32 + mi * 16 + lg * 4 + j][h];
        fin[mi][0][j] += w * fmaxf(acch[mi][0][j], 0.f);
        fin[mi][1][j] += w * fmaxf(acch[mi][1][j], 0.f);
      }
    __syncthreads();
  }
#pragma unroll
  for (int mi = 0; mi < 2; ++mi)
#pragma unroll
    for (int ni = 0; ni < 2; ++ni)
#pragma unroll
      for (int j = 0; j < 4; ++j) {
        int row = t0 + wr * 32 + mi * 16 + lg * 4 + j;
        int col = s0 + wc * 32 + ni * 16 + lr;
        score[(size_t)row * T_ + col] = fin[mi][ni][j];
      }
}

// ---------------------------------------------------------------- top-k (exact)
__global__ __launch_bounds__(256) void topk_kernel(
    const float* __restrict__ score, int* __restrict__ selidx,
    int* __restrict__ selcnt) {
  const int t = blockIdx.x;
  const int L = t + 1;
  const int tid = threadIdx.x;
  if (L <= TOPK_) {
    for (int j = tid; j < TOPK_; j += 256)
      selidx[(size_t)t * TOPK_ + j] = (j < L) ? j : 0;
    if (tid == 0) selcnt[t] = L;
    return;
  }
  __shared__ unsigned u[T_];
  __shared__ unsigned hist[16];
  __shared__ unsigned sprefix;
  __shared__ int sk;
  __shared__ int part[256];
  for (int i = tid; i < T_; i += 256) {
    float v = (i < L) ? score[(size_t)t * T_ + i] : -FLT_MAX;
    unsigned b = __float_as_uint(v);
    u[i] = (b & 0x80000000u) ? ~b : (b | 0x80000000u);
  }
  if (tid == 0) { sprefix = 0u; sk = TOPK_; }
  __syncthreads();
  for (int pass = 0; pass < 8; ++pass) {
    const int shift = 28 - 4 * pass;
    if (tid < 16) hist[tid] = 0u;
    __syncthreads();
    unsigned pfx = sprefix;
    for (int i = tid; i < L; i += 256) {
      unsigned val = u[i];
      bool match = (pass == 0) || ((val >> (shift + 4)) == pfx);
      if (match) atomicAdd(&hist[(val >> shift) & 15u], 1u);
    }
    __syncthreads();
    if (tid == 0) {
      int k = sk; unsigned cum = 0u; int bsel = 0;
      for (int bb = 15; bb >= 0; --bb) {
        if (cum + hist[bb] >= (unsigned)k) { bsel = bb; sk = k - (int)cum; break; }
        cum += hist[bb];
      }
      sprefix = (sprefix << 4) | (unsigned)bsel;
    }
    __syncthreads();
  }
  const unsigned thr = sprefix;
  const int kEq = sk;
  const int base = tid * 8;
  int eqloc[8]; int esum = 0;
  for (int r = 0; r < 8; ++r) {
    int i = base + r;
    int f = (i < L && u[i] == thr) ? 1 : 0;
    eqloc[r] = esum; esum += f;
  }
  part[tid] = esum; __syncthreads();
  for (int off = 1; off < 256; off <<= 1) {
    int v = (tid >= off) ? part[tid - off] : 0;
    __syncthreads();
    part[tid] += v;
    __syncthreads();
  }
  const int ebase = (tid > 0) ? part[tid - 1] : 0;
  __syncthreads();
  int sloc[8], selflag[8]; int ssum = 0;
  for (int r = 0; r < 8; ++r) {
    int i = base + r;
    int f = 0;
    if (i < L) {
      unsigned ui = u[i];
      if (ui > thr) f = 1;
      else if (ui == thr && (ebase + eqloc[r]) < kEq) f = 1;
    }
    selflag[r] = f; sloc[r] = ssum; ssum += f;
  }
  part[tid] = ssum; __syncthreads();
  for (int off = 1; off < 256; off <<= 1) {
    int v = (tid >= off) ? part[tid - off] : 0;
    __syncthreads();
    part[tid] += v;
    __syncthreads();
  }
  const int sbase = (tid > 0) ? part[tid - 1] : 0;
  for (int r = 0; r < 8; ++r)
    if (selflag[r]) selidx[(size_t)t * TOPK_ + sbase + sloc[r]] = base + r;
  if (tid == 0) selcnt[t] = TOPK_;
}

// ---------------------------------------------------------------- MLA attention v3
// QK^T: K fragments straight from L2 (kvcn 2MB, L2-resident), hoisted bases.
// PV: V staged to LDS via global_load_lds DMA (no staging VGPRs -> no spill);
// swizzle realized by permuting the per-lane GLOBAL source piece (rule #21).
__global__ __launch_bounds__(256, 3) void attn_mla_kernel(
    const u16* __restrict__ qeff, const u16* __restrict__ qfb,
    const u16* __restrict__ kvcn, const u16* __restrict__ kper,
    const int* __restrict__ selidx, const int* __restrict__ selcnt,
    u16* __restrict__ Olat) {
  const int t = blockIdx.x;
  const int tid = threadIdx.x;
  const int wid = tid >> 6, lane = tid & 63;
  const int lr = lane & 15, lg = lane >> 4;
  __shared__ int sidxs[512];
  __shared__ u16 Pb[16][520];
  __shared__ u16 Vs[32 * 512];            // logical: u16 idx = (row*512+d) ^ (((row>>3)&3)<<4)
  __shared__ float redm[4][16];
  __shared__ float reds[4][16];
  const int cnt = selcnt[t];
  for (int j = tid; j < 512; j += 256) sidxs[j] = selidx[(size_t)t * TOPK_ + j];
  __syncthreads();

  // ---- QK^T: wave wid owns keys [wid*128, wid*128+128), 8 M-tiles of 16
  int srow[8];
  const u16* kb8[8];
#pragma unroll
  for (int m = 0; m < 8; ++m) {
    srow[m] = sidxs[wid * 128 + m * 16 + lr];
    kb8[m] = kvcn + (size_t)srow[m] * 512 + lg * 8;
  }
  const u16* qe = qeff + (size_t)t * (H_ * 512) + lr * 512 + lg * 8;
  const u16* qp = qfb + (size_t)t * (H_ * QKD_) + lr * QKD_ + NOPE_ + lg * 8;
  f32x4 lgv[8] = {};
#pragma unroll
  for (int kb = 0; kb < 16; ++kb) {
    bf16x8 qfk = ld8(qe + kb * 32);
#pragma unroll
    for (int m = 0; m < 8; ++m)
      lgv[m] = mfma16(ld8(kb8[m] + kb * 32), qfk, lgv[m]);
  }
#pragma unroll
  for (int m = 0; m < 8; ++m) kb8[m] = kper + (size_t)srow[m] * 64 + lg * 8;
#pragma unroll
  for (int kb = 0; kb < 2; ++kb) {
    bf16x8 qfk = ld8(qp + kb * 32);
#pragma unroll
    for (int m = 0; m < 8; ++m)
      lgv[m] = mfma16(ld8(kb8[m] + kb * 32), qfk, lgv[m]);
  }

  // ---- softmax (head = lr; slot = wid*128 + m*16 + lg*4 + j)
  float mx = -FLT_MAX;
#pragma unroll
  for (int m = 0; m < 8; ++m)
#pragma unroll
    for (int j = 0; j < 4; ++j) {
      int slot = wid * 128 + m * 16 + lg * 4 + j;
      float v = (slot < cnt) ? lgv[m][j] * SCALING_ : -FLT_MAX;
      lgv[m][j] = v;
      mx = fmaxf(mx, v);
    }
  mx = fmaxf(mx, __shfl_xor(mx, 16));
  mx = fmaxf(mx, __shfl_xor(mx, 32));
  if (lane < 16) redm[wid][lane] = mx;
  __syncthreads();
  float hm = fmaxf(fmaxf(redm[0][lr], redm[1][lr]), fmaxf(redm[2][lr], redm[3][lr]));
  float sm = 0.f;
#pragma unroll
  for (int m = 0; m < 8; ++m)
#pragma unroll
    for (int j = 0; j < 4; ++j) {
      int slot = wid * 128 + m * 16 + lg * 4 + j;
      float e = (slot < cnt) ? expf(lgv[m][j] - hm) : 0.f;
      lgv[m][j] = e; sm += e;
    }
  sm += __shfl_xor(sm, 16);
  sm += __shfl_xor(sm, 32);
  if (lane < 16) reds[wid][lane] = sm;
  __syncthreads();
  float inv = 1.f / (reds[0][lr] + reds[1][lr] + reds[2][lr] + reds[3][lr]);
#pragma unroll
  for (int m = 0; m < 8; ++m) {
    int sl = wid * 128 + m * 16 + lg * 4;
    *(u32*)&Pb[lr][sl] = pack2(lgv[m][0] * inv, lgv[m][1] * inv);
    *(u32*)&Pb[lr][sl + 2] = pack2(lgv[m][2] * inv, lgv[m][3] * inv);
  }

  // ---- PV: O[16 heads, 512 dims] = P @ V, 16 chunks of 32 keys
  f32x4 oacc[8] = {};
  const int colb = wid * 128 + lr;
  for (int c = 0; c < 16; ++c) {
    // stage chunk c via DMA: wave stages rows {i*4+wid}; lane's source piece is
    // permuted so the linear LDS write realizes the XOR swizzle.
#pragma unroll
    for (int i = 0; i < 8; ++i) {
      int row = i * 4 + wid;
      int s = sidxs[c * 32 + row];
      int piece = lane ^ ((((row >> 3) & 3)) << 1);   // 16B units within the 1KB row
      gload16(kvcn + (size_t)s * 512 + piece * 8, &Vs[row * 512]);
    }
    __syncthreads();   // drains vmcnt (DMA complete) + lgkm
    bf16x8 pa = ld8(&Pb[lr][c * 32 + lg * 8]);
#pragma unroll
    for (int C = 0; C < 8; ++C) {
      union { u32 u[4]; bf16x8 v; } bb;
#pragma unroll
      for (int e = 0; e < 4; ++e) {
        int r0 = lg * 8 + 2 * e;
        int sw = ((r0 >> 3) & 3) << 4;     // same for r0 and r0+1
        int base = r0 * 512 + colb + C * 16;
        bb.u[e] = (u32)Vs[base ^ sw] | ((u32)Vs[(base + 512) ^ sw] << 16);
      }
      oacc[C] = mfma16(pa, bb.v, oacc[C]);
    }
    __syncthreads();
  }
#pragma unroll
  for (int C = 0; C < 8; ++C)
#pragma unroll
    for (int j = 0; j < 4; ++j) {
      int h = lg * 4 + j;
      Olat[(size_t)t * (H_ * 512) + h * 512 + wid * 128 + C * 16 + lr] = f2bf(oacc[C][j]);
    }
}

// ---------------------------------------------------------------- launch
extern "C" void kernel_launch(void* const* d_in, const int* in_sizes, int n_in,
                              void* d_out, int out_size, void* d_ws, size_t ws_size,
                              hipStream_t stream) {
  const float* hidden    = (const float*)d_in[1];
  const float* w_qkv_a   = (const float*)d_in[2];
  const float* q_a_ln_w  = (const float*)d_in[3];
  const float* w_qb      = (const float*)d_in[4];
  const float* kv_a_ln_w = (const float*)d_in[5];
  const float* w_kvb     = (const float*)d_in[6];
  const float* w_o       = (const float*)d_in[7];
  const float* w_idx_qb  = (const float*)d_in[8];
  const float* w_idx_k   = (const float*)d_in[9];
  const float* idx_g     = (const float*)d_in[10];
  const float* idx_b     = (const float*)d_in[11];
  const float* w_wproj   = (const float*)d_in[12];
  const float* b_wproj   = (const float*)d_in[13];

  char* W = (char*)d_ws;
  size_t o = 0;
  auto alloc = [&](size_t bytes) { void* p = W + o; o += (bytes + 255) & ~(size_t)255; return p; };
  float* q_cn   = (float*)alloc((size_t)T_ * QLR_ * 4);
  u16*   kv_cn  = (u16*)alloc((size_t)T_ * KVLR_ * 2);
  u16*   kper   = (u16*)alloc((size_t)T_ * ROPE_ * 2);
  int*   selidx = (int*)alloc((size_t)T_ * TOPK_ * 4);
  int*   selcnt = (int*)alloc((size_t)T_ * 4);
  float* wgt    = (float*)alloc((size_t)T_ * IDXH_ * 4);
  float* ki     = (float*)alloc((size_t)T_ * IDXD_ * 4);
  float* qi     = (float*)alloc((size_t)T_ * IDXH_ * IDXD_ * 4);
  u16*   qeff   = (u16*)qi;
  float* score  = (float*)alloc((size_t)T_ * T_ * 4);
  u16*   attno  = (u16*)score;
  float* wqat   = (float*)alloc((size_t)QKVN_ * HID_ * 4);
  float* qkv    = (float*)alloc((size_t)T_ * QKVN_ * 4);
  u16*   Olat   = (u16*)wqat;
  float* wiqt   = (float*)alloc((size_t)(IDXH_ * IDXD_) * QLR_ * 4);
  u16*   qfb    = (u16*)wiqt;
  float* wikt   = (float*)alloc((size_t)IDXD_ * HID_ * 4);
  float* wwpt   = (float*)alloc((size_t)IDXH_ * HID_ * 4);
  u16*   wqbt   = (u16*)alloc((size_t)(H_ * QKD_) * QLR_ * 2);
  u16*   wkvb   = (u16*)alloc((size_t)KVLR_ * (H_ * 256) * 2);
  u16*   wkvbt  = (u16*)alloc((size_t)(H_ * 256) * KVLR_ * 2);
  u16*   wot    = (u16*)alloc((size_t)(H_ * VD_) * HID_ * 2);

  dim3 blk(256);
  auto g2 = [](int M, int N, int Z) { return dim3((N + 127) / 128, M / 128, Z); };

  // weight prep
  transpose_f32_k<<<dim3(33, 32), blk, 0, stream>>>(w_qkv_a, wqat, HID_, QKVN_);
  transpose_f32_k<<<dim3(64, 24), blk, 0, stream>>>(w_idx_qb, wiqt, QLR_, IDXH_ * IDXD_);
  transpose_f32_k<<<dim3(2, 32), blk, 0, stream>>>(w_idx_k, wikt, HID_, IDXD_);
  transpose_f32_k<<<dim3(1, 32), blk, 0, stream>>>(w_wproj, wwpt, HID_, IDXH_);
  transpose_bf16_k<<<dim3(48, 24), blk, 0, stream>>>(w_qb, wqbt, QLR_, H_ * QKD_);
  transpose_bf16_k<<<dim3(64, 8), blk, 0, stream>>>(w_kvb, wkvbt, KVLR_, H_ * 256);
  transpose_bf16_k<<<dim3(32, 32), blk, 0, stream>>>(w_o, wot, H_ * VD_, HID_);
  conv_bf16_k<<<2048, blk, 0, stream>>>(w_kvb, wkvb, (long)KVLR_ * H_ * 256);

  // strict path (f16-split MFMA)
  gemm_split<<<g2(T_, QKVN_, 1), blk, 0, stream>>>(hidden, HID_, wqat, HID_, qkv, QKVN_, QKVN_, HID_);
  rmsnorm_kernel<<<T_, blk, 0, stream>>>(qkv, q_a_ln_w, kv_a_ln_w, q_cn, kv_cn);
  rope_kpe_kernel<<<T_, 64, 0, stream>>>(qkv, kper);

  gemm_split<<<g2(T_, IDXH_ * IDXD_, 1), blk, 0, stream>>>(q_cn, QLR_, wiqt, QLR_, qi, IDXH_ * IDXD_, IDXH_ * IDXD_, QLR_);
  rope_qi_kernel<<<T_, blk, 0, stream>>>(qi);
  gemm_split<<<g2(T_, IDXD_, 1), blk, 0, stream>>>(hidden, HID_, wikt, HID_, ki, IDXD_, IDXD_, HID_);
  ki_ln_rope_kernel<<<T_, 128, 0, stream>>>(ki, idx_g, idx_b);
  gemm_split<<<g2(T_, IDXH_, 1), blk, 0, stream>>>(hidden, HID_, wwpt, HID_, wgt, IDXH_, IDXH_, HID_);
  w_epi_kernel<<<(T_ * IDXH_ + 255) / 256, blk, 0, stream>>>(wgt, b_wproj);

  score_mfma<<<dim3(32, 32), blk, 0, stream>>>(qi, ki, wgt, score);
  topk_kernel<<<T_, blk, 0, stream>>>(score, selidx, selcnt);

  // tolerant path (bf16 MFMA)
  gemm_t<1, 1><<<g2(T_, H_ * QKD_, 1), blk, 0, stream>>>(q_cn, QLR_, 0, wqbt, QLR_, 0, qfb, H_ * QKD_, 0, H_ * QKD_, QLR_);
  rope_q_bf_kernel<<<T_, blk, 0, stream>>>(qfb);
  gemm_t<0, 1><<<g2(T_, 512, H_), blk, 0, stream>>>(qfb, H_ * QKD_, QKD_, wkvb, H_ * 256, 256, qeff, H_ * 512, 512, 512, NOPE_);
  attn_mla_kernel<<<T_, blk, 0, stream>>>(qeff, qfb, kv_cn, kper, selidx, selcnt, Olat);
  gemm_t<0, 1><<<g2(T_, VD_, H_), blk, 0, stream>>>(Olat, H_ * 512, 512, wkvbt + 128 * 512, KVLR_, 256 * 512, attno, H_ * VD_, VD_, VD_, 512);
  gemm_t<0, 0><<<g2(T_, HID_, 1), blk, 0, stream>>>(attno, H_ * VD_, 0, wot, H_ * VD_, 0, d_out, HID_, 0, HID_, H_ * VD_);
}

// Round 8
// 1010.613 us; speedup vs baseline: 4.9631x; 1.2393x over previous
//
#include <hip/hip_runtime.h>
#include <cfloat>
#include <cmath>

#define T_    2048
#define HID_  2048
#define QKVN_ 2112
#define QLR_  1536
#define KVLR_ 512
#define ROPE_ 64
#define NOPE_ 128
#define QKD_  192
#define VD_   128
#define H_    16
#define IDXH_ 32
#define IDXD_ 128
#define TOPK_ 512
#define EPS_  1e-6f
#define SCALING_ 0.07216878364870323f   // 192^-0.5

typedef unsigned int u32;
typedef unsigned short u16;
typedef __bf16 bf16x8 __attribute__((ext_vector_type(8)));
typedef _Float16 f16;
typedef f16 f16x8 __attribute__((ext_vector_type(8)));
typedef float f32x4 __attribute__((ext_vector_type(4)));

__device__ __forceinline__ u16 f2bf(float x) {
  u32 u = __float_as_uint(x);
  u32 r = (u + 0x7fffu + ((u >> 16) & 1u)) >> 16;
  return (u16)r;
}
__device__ __forceinline__ float bf2f(u16 h) { return __uint_as_float(((u32)h) << 16); }
__device__ __forceinline__ u32 pack2(float a, float b) { return (u32)f2bf(a) | ((u32)f2bf(b) << 16); }
__device__ __forceinline__ bf16x8 ld8(const void* p) { return *(const bf16x8*)p; }
__device__ __forceinline__ f32x4 mfma16(bf16x8 a, bf16x8 b, f32x4 c) {
  return __builtin_amdgcn_mfma_f32_16x16x32_bf16(a, b, c, 0, 0, 0);
}
__device__ __forceinline__ u16 hbits(f16 h) { union { f16 h; u16 u; } c; c.h = h; return c.u; }
__device__ __forceinline__ u32 hpack(f16 a, f16 b) { return (u32)hbits(a) | ((u32)hbits(b) << 16); }
__device__ __forceinline__ f16x8 ldh8(const void* p) { return *(const f16x8*)p; }
__device__ __forceinline__ f32x4 mfmah(f16x8 a, f16x8 b, f32x4 c) {
  return __builtin_amdgcn_mfma_f32_16x16x32_f16(a, b, c, 0, 0, 0);
}
__device__ __forceinline__ void gload16(const u16* g, u16* l) {
  __builtin_amdgcn_global_load_lds(
      (__attribute__((address_space(1))) void*)(g),
      (__attribute__((address_space(3))) void*)(l), 16, 0, 0);
}

// ---------------------------------------------------------------- split / transpose prep
__global__ __launch_bounds__(256) void split_f16_k(
    const float* __restrict__ in, u16* __restrict__ hi, u16* __restrict__ lo, long n) {
  for (long i = ((long)blockIdx.x * 256 + threadIdx.x) * 4; i < n; i += (long)gridDim.x * 1024) {
    float4 v = *(const float4*)(in + i);
    f16 a = (f16)v.x, b = (f16)v.y, c = (f16)v.z, d = (f16)v.w;
    *(u32*)(hi + i) = hpack(a, b);
    *(u32*)(hi + i + 2) = hpack(c, d);
    *(u32*)(lo + i) = hpack((f16)(v.x - (float)a), (f16)(v.y - (float)b));
    *(u32*)(lo + i + 2) = hpack((f16)(v.z - (float)c), (f16)(v.w - (float)d));
  }
}

// in[K,N] f32 -> oh/ol[N,K] f16 hi/lo
__global__ __launch_bounds__(256) void transpose_split_f16_k(
    const float* __restrict__ in, u16* __restrict__ oh, u16* __restrict__ ol,
    int K, int N) {
  __shared__ float t[64][65];
  int k0 = blockIdx.y * 64, n0 = blockIdx.x * 64;
  for (int j = 0; j < 16; ++j) {
    int u = threadIdx.x + 256 * j; int r = u >> 6, c = u & 63;
    t[r][c] = (k0 + r < K && n0 + c < N) ? in[(size_t)(k0 + r) * N + n0 + c] : 0.f;
  }
  __syncthreads();
  for (int j = 0; j < 16; ++j) {
    int u = threadIdx.x + 256 * j; int r = u >> 6, c = u & 63;
    if (n0 + r < N && k0 + c < K) {
      float v = t[c][r];
      f16 h = (f16)v;
      oh[(size_t)(n0 + r) * K + k0 + c] = hbits(h);
      ol[(size_t)(n0 + r) * K + k0 + c] = hbits((f16)(v - (float)h));
    }
  }
}

__global__ __launch_bounds__(256) void transpose_bf16_k(
    const float* __restrict__ in, u16* __restrict__ out, int K, int N) {
  __shared__ float t[64][65];
  int k0 = blockIdx.y * 64, n0 = blockIdx.x * 64;
  for (int j = 0; j < 16; ++j) {
    int u = threadIdx.x + 256 * j; int r = u >> 6, c = u & 63;
    t[r][c] = (k0 + r < K && n0 + c < N) ? in[(size_t)(k0 + r) * N + n0 + c] : 0.f;
  }
  __syncthreads();
  for (int j = 0; j < 16; ++j) {
    int u = threadIdx.x + 256 * j; int r = u >> 6, c = u & 63;
    if (n0 + r < N && k0 + c < K) out[(size_t)(n0 + r) * K + k0 + c] = f2bf(t[c][r]);
  }
}

__global__ __launch_bounds__(256) void conv_bf16_k(
    const float* __restrict__ in, u16* __restrict__ out, long n) {
  for (long i = ((long)blockIdx.x * 256 + threadIdx.x) * 4; i < n; i += (long)gridDim.x * 1024) {
    float4 v = *(const float4*)(in + i);
    *(u32*)(out + i) = pack2(v.x, v.y);
    *(u32*)(out + i + 2) = pack2(v.z, v.w);
  }
}

// ---------------------------------------------------------------- strict GEMM from pre-split hi/lo
__global__ __launch_bounds__(256) void gemm_hl(
    const u16* __restrict__ Ah_, const u16* __restrict__ Al_, int lda,
    const u16* __restrict__ Bh_, const u16* __restrict__ Bl_, int ldb,
    float* __restrict__ C, int ldc, int N, int K) {
  __shared__ u32 Ah[128][20], Al[128][20], Bh[128][20], Bl[128][20];
  const int tid = threadIdx.x;
  const int bm = blockIdx.y * 128, bn = blockIdx.x * 128;
  const int wid = tid >> 6, lane = tid & 63, wr = wid >> 1, wc = wid & 1;
  const int lr = lane & 15, lg = lane >> 4;
  f32x4 acc[4][4] = {};
  for (int k0 = 0; k0 < K; k0 += 32) {
#pragma unroll
    for (int j = 0; j < 2; ++j) {
      int u = tid + 256 * j; int row = u >> 2, p = u & 3;
      size_t ga = (size_t)(bm + row) * lda + k0 + p * 8;
      *(uint4*)&Ah[row][p * 4] = *(const uint4*)(Ah_ + ga);
      *(uint4*)&Al[row][p * 4] = *(const uint4*)(Al_ + ga);
      uint4 vh = make_uint4(0, 0, 0, 0), vl = make_uint4(0, 0, 0, 0);
      if (bn + row < N) {
        size_t gb = (size_t)(bn + row) * ldb + k0 + p * 8;
        vh = *(const uint4*)(Bh_ + gb);
        vl = *(const uint4*)(Bl_ + gb);
      }
      *(uint4*)&Bh[row][p * 4] = vh;
      *(uint4*)&Bl[row][p * 4] = vl;
    }
    __syncthreads();
    f16x8 ah[4], al[4], bh[4], bl[4];
#pragma unroll
    for (int i = 0; i < 4; ++i) {
      ah[i] = ldh8(&Ah[wr * 64 + i * 16 + lr][lg * 4]);
      al[i] = ldh8(&Al[wr * 64 + i * 16 + lr][lg * 4]);
      bh[i] = ldh8(&Bh[wc * 64 + i * 16 + lr][lg * 4]);
      bl[i] = ldh8(&Bl[wc * 64 + i * 16 + lr][lg * 4]);
    }
#pragma unroll
    for (int i = 0; i < 4; ++i)
#pragma unroll
      for (int jn = 0; jn < 4; ++jn) {
        acc[i][jn] = mfmah(ah[i], bh[jn], acc[i][jn]);
        acc[i][jn] = mfmah(ah[i], bl[jn], acc[i][jn]);
        acc[i][jn] = mfmah(al[i], bh[jn], acc[i][jn]);
      }
    __syncthreads();
  }
#pragma unroll
  for (int i = 0; i < 4; ++i)
#pragma unroll
    for (int jn = 0; jn < 4; ++jn)
#pragma unroll
      for (int j = 0; j < 4; ++j) {
        int row = bm + wr * 64 + i * 16 + lg * 4 + j;
        int col = bn + wc * 64 + jn * 16 + lr;
        if (col < N) C[(size_t)row * ldc + col] = acc[i][jn][j];
      }
}

// ---------------------------------------------------------------- tolerant bf16 GEMM
template <int AF32, int CBF16>
__global__ __launch_bounds__(256) void gemm_t(
    const void* __restrict__ Ap, int lda, long aoz,
    const u16* __restrict__ Bt, int ldb, long boz,
    void* __restrict__ Cp, int ldc, long coz, int N, int K) {
  __shared__ u32 As[128][20], Bs[128][20];
  const int tid = threadIdx.x;
  const int z = blockIdx.z;
  const int bm = blockIdx.y * 128, bn = blockIdx.x * 128;
  const int wid = tid >> 6, lane = tid & 63, wr = wid >> 1, wc = wid & 1;
  const int lr = lane & 15, lg = lane >> 4;
  f32x4 acc[4][4] = {};
  for (int k0 = 0; k0 < K; k0 += 32) {
    if (AF32) {
      const float* A = (const float*)Ap + aoz * z;
#pragma unroll
      for (int j = 0; j < 4; ++j) {
        int u = tid + 256 * j; int row = u >> 3, p = u & 7;
        float4 v = *(const float4*)(A + (size_t)(bm + row) * lda + k0 + p * 4);
        As[row][p * 2] = pack2(v.x, v.y);
        As[row][p * 2 + 1] = pack2(v.z, v.w);
      }
    } else {
      const u16* A = (const u16*)Ap + aoz * z;
#pragma unroll
      for (int j = 0; j < 2; ++j) {
        int u = tid + 256 * j; int row = u >> 2, p = u & 3;
        uint4 v = *(const uint4*)(A + (size_t)(bm + row) * lda + k0 + p * 8);
        *(uint4*)&As[row][p * 4] = v;
      }
    }
#pragma unroll
    for (int j = 0; j < 2; ++j) {
      int u = tid + 256 * j; int row = u >> 2, p = u & 3;
      uint4 v = make_uint4(0, 0, 0, 0);
      if (bn + row < N) v = *(const uint4*)(Bt + boz * z + (size_t)(bn + row) * ldb + k0 + p * 8);
      *(uint4*)&Bs[row][p * 4] = v;
    }
    __syncthreads();
    bf16x8 af[4], bf[4];
#pragma unroll
    for (int i = 0; i < 4; ++i) {
      af[i] = ld8(&As[wr * 64 + i * 16 + lr][lg * 4]);
      bf[i] = ld8(&Bs[wc * 64 + i * 16 + lr][lg * 4]);
    }
#pragma unroll
    for (int i = 0; i < 4; ++i)
#pragma unroll
      for (int jn = 0; jn < 4; ++jn)
        acc[i][jn] = mfma16(af[i], bf[jn], acc[i][jn]);
    __syncthreads();
  }
#pragma unroll
  for (int i = 0; i < 4; ++i)
#pragma unroll
    for (int jn = 0; jn < 4; ++jn)
#pragma unroll
      for (int j = 0; j < 4; ++j) {
        int row = bm + wr * 64 + i * 16 + lg * 4 + j;
        int col = bn + wc * 64 + jn * 16 + lr;
        if (col < N) {
          if (CBF16) ((u16*)Cp)[coz * z + (size_t)row * ldc + col] = f2bf(acc[i][jn][j]);
          else ((float*)Cp)[coz * z + (size_t)row * ldc + col] = acc[i][jn][j];
        }
      }
}

// ---------------------------------------------------------------- RMS norms (+ q_cn f16 split)
__global__ __launch_bounds__(256) void rmsnorm_kernel(
    const float* __restrict__ qkv, const float* __restrict__ qw,
    const float* __restrict__ kvw, float* __restrict__ q_cn,
    u16* __restrict__ qch, u16* __restrict__ qcl, u16* __restrict__ kv_cn) {
  const int t = blockIdx.x, tid = threadIdx.x;
  const float* row = qkv + (size_t)t * QKVN_;
  __shared__ float red[256];
  float ss = 0.f;
  for (int i = tid; i < QLR_; i += 256) { float v = row[i]; ss += v * v; }
  red[tid] = ss; __syncthreads();
  for (int s = 128; s; s >>= 1) { if (tid < s) red[tid] += red[tid + s]; __syncthreads(); }
  float scl = 1.0f / sqrtf(red[0] / (float)QLR_ + EPS_);
  for (int i = tid; i < QLR_; i += 256) {
    float val = row[i] * scl * qw[i];
    q_cn[(size_t)t * QLR_ + i] = val;
    f16 h = (f16)val;
    qch[(size_t)t * QLR_ + i] = hbits(h);
    qcl[(size_t)t * QLR_ + i] = hbits((f16)(val - (float)h));
  }
  __syncthreads();
  ss = 0.f;
  for (int i = tid; i < KVLR_; i += 256) { float v = row[QLR_ + i]; ss += v * v; }
  red[tid] = ss; __syncthreads();
  for (int s = 128; s; s >>= 1) { if (tid < s) red[tid] += red[tid + s]; __syncthreads(); }
  scl = 1.0f / sqrtf(red[0] / (float)KVLR_ + EPS_);
  for (int i = tid; i < KVLR_; i += 256)
    kv_cn[(size_t)t * KVLR_ + i] = f2bf(row[QLR_ + i] * scl * kvw[i]);
}

// ---------------------------------------------------------------- RoPE helpers
__device__ __forceinline__ void rope_pair(float pos, int j, float& x0, float& x1) {
  float inv = powf(10000.f, -(float)j * (1.f / 32.f));
  float f = pos * inv;
  float c = cosf(f), s = sinf(f);
  float a = x0, b = x1;
  x0 = a * c - b * s;
  x1 = a * s + b * c;
}

// qi f32 -> roped + f16 hi/lo split (full row)
__global__ __launch_bounds__(256) void rope_qi_split_kernel(
    const float* __restrict__ qi, u16* __restrict__ qih, u16* __restrict__ qil) {
  const int t = blockIdx.x, tid = threadIdx.x;
  float pos = (float)t;
  const float* src = qi + (size_t)t * (IDXH_ * IDXD_);
  u16* dh = qih + (size_t)t * (IDXH_ * IDXD_);
  u16* dl = qil + (size_t)t * (IDXH_ * IDXD_);
  for (int p = tid; p < IDXH_ * IDXD_ / 2; p += 256) {
    int d = p & 63;
    float x0 = src[2 * p], x1 = src[2 * p + 1];
    if (d < 32) rope_pair(pos, d, x0, x1);
    f16 h0 = (f16)x0, h1 = (f16)x1;
    *(u32*)(dh + 2 * p) = hpack(h0, h1);
    *(u32*)(dl + 2 * p) = hpack((f16)(x0 - (float)h0), (f16)(x1 - (float)h1));
  }
}

__global__ __launch_bounds__(256) void rope_q_bf_kernel(u16* __restrict__ qfb) {
  const int t = blockIdx.x, tid = threadIdx.x;
  float pos = (float)t;
  for (int idx = tid; idx < H_ * 32; idx += 256) {
    int hh = idx / 32, j = idx % 32;
    u16* p = qfb + (size_t)t * (H_ * QKD_) + hh * QKD_ + NOPE_ + 2 * j;
    float x0 = bf2f(p[0]), x1 = bf2f(p[1]);
    rope_pair(pos, j, x0, x1);
    p[0] = f2bf(x0); p[1] = f2bf(x1);
  }
}

__global__ __launch_bounds__(64) void rope_kpe_kernel(
    const float* __restrict__ qkv, u16* __restrict__ kper) {
  const int t = blockIdx.x, tid = threadIdx.x;
  if (tid >= 32) return;
  float pos = (float)t;
  const float* p = qkv + (size_t)t * QKVN_ + (QLR_ + KVLR_);
  float x0 = p[2 * tid], x1 = p[2 * tid + 1];
  rope_pair(pos, tid, x0, x1);
  kper[(size_t)t * ROPE_ + 2 * tid] = f2bf(x0);
  kper[(size_t)t * ROPE_ + 2 * tid + 1] = f2bf(x1);
}

// ---------------------------------------------------------------- ki: LN + rope -> f16 hi/lo
__global__ __launch_bounds__(128) void ki_ln_rope_kernel(
    const float* __restrict__ ki, const float* __restrict__ gamma,
    const float* __restrict__ beta, u16* __restrict__ kih, u16* __restrict__ kil) {
  const int t = blockIdx.x, tid = threadIdx.x;
  __shared__ float x[128];
  __shared__ float red[128];
  float v = ki[(size_t)t * IDXD_ + tid];
  red[tid] = v; __syncthreads();
  for (int s = 64; s; s >>= 1) { if (tid < s) red[tid] += red[tid + s]; __syncthreads(); }
  float mu = red[0] / 128.f;
  __syncthreads();
  float d = v - mu;
  red[tid] = d * d; __syncthreads();
  for (int s = 64; s; s >>= 1) { if (tid < s) red[tid] += red[tid + s]; __syncthreads(); }
  float var = red[0] / 128.f;
  float y = d * (1.0f / sqrtf(var + EPS_)) * gamma[tid] + beta[tid];
  x[tid] = y; __syncthreads();
  float pos = (float)t;
  if (tid < 32) {
    float x0 = x[2 * tid], x1 = x[2 * tid + 1];
    rope_pair(pos, tid, x0, x1);
    x[2 * tid] = x0; x[2 * tid + 1] = x1;
  }
  __syncthreads();
  float fv = x[tid];
  f16 h = (f16)fv;
  kih[(size_t)t * IDXD_ + tid] = hbits(h);
  kil[(size_t)t * IDXD_ + tid] = hbits((f16)(fv - (float)h));
}

// ---------------------------------------------------------------- w epilogue
__global__ __launch_bounds__(256) void w_epi_kernel(
    float* __restrict__ wgt, const float* __restrict__ b) {
  int idx = blockIdx.x * 256 + threadIdx.x;
  if (idx < T_ * IDXH_)
    wgt[idx] = (wgt[idx] + b[idx & 31]) * 0.015625f;
}

// ---------------------------------------------------------------- indexer score (pre-split f16 MFMA)
__global__ __launch_bounds__(256) void score_mfma(
    const u16* __restrict__ qih, const u16* __restrict__ qil,
    const u16* __restrict__ kih, const u16* __restrict__ kil,
    const float* __restrict__ wgt, float* __restrict__ score) {
  const int s0 = blockIdx.x * 64, t0 = blockIdx.y * 64;
  if (s0 > t0 + 63) return;
  __shared__ u32 Kh[64][68], Kl[64][68], Qh[64][68], Ql[64][68];
  __shared__ float wts[64][33];
  const int tid = threadIdx.x;
  const int wid = tid >> 6, lane = tid & 63, wr = wid >> 1, wc = wid & 1;
  const int lr = lane & 15, lg = lane >> 4;
  // 64 rows x 128 u16 = 16 uint4 pieces/row -> 1024 (row,piece) pairs
#pragma unroll
  for (int j = 0; j < 4; ++j) {
    int u = tid + 256 * j; int row = u >> 4, p = u & 15;
    *(uint4*)&Kh[row][p * 4] = *(const uint4*)(kih + (size_t)(s0 + row) * IDXD_ + p * 8);
    *(uint4*)&Kl[row][p * 4] = *(const uint4*)(kil + (size_t)(s0 + row) * IDXD_ + p * 8);
  }
#pragma unroll
  for (int j = 0; j < 8; ++j) {
    int u = tid + 256 * j; int r = u >> 5, c = u & 31;
    wts[r][c] = wgt[(size_t)(t0 + r) * IDXH_ + c];
  }
  __syncthreads();
  f16x8 bh[2][4], bl[2][4];
#pragma unroll
  for (int ni = 0; ni < 2; ++ni)
#pragma unroll
    for (int kb = 0; kb < 4; ++kb) {
      bh[ni][kb] = ldh8(&Kh[wc * 32 + ni * 16 + lr][kb * 16 + lg * 4]);
      bl[ni][kb] = ldh8(&Kl[wc * 32 + ni * 16 + lr][kb * 16 + lg * 4]);
    }
  f32x4 fin[2][2] = {};
  for (int h = 0; h < IDXH_; ++h) {
#pragma unroll
    for (int j = 0; j < 4; ++j) {
      int u = tid + 256 * j; int row = u >> 4, p = u & 15;
      size_t g = (size_t)(t0 + row) * (IDXH_ * IDXD_) + h * IDXD_ + p * 8;
      *(uint4*)&Qh[row][p * 4] = *(const uint4*)(qih + g);
      *(uint4*)&Ql[row][p * 4] = *(const uint4*)(qil + g);
    }
    __syncthreads();
    f32x4 acch[2][2] = {};
#pragma unroll
    for (int kb = 0; kb < 4; ++kb) {
      f16x8 ah0 = ldh8(&Qh[wr * 32 + lr][kb * 16 + lg * 4]);
      f16x8 ah1 = ldh8(&Qh[wr * 32 + 16 + lr][kb * 16 + lg * 4]);
      f16x8 al0 = ldh8(&Ql[wr * 32 + lr][kb * 16 + lg * 4]);
      f16x8 al1 = ldh8(&Ql[wr * 32 + 16 + lr][kb * 16 + lg * 4]);
#pragma unroll
      for (int ni = 0; ni < 2; ++ni) {
        acch[0][ni] = mfmah(ah0, bh[ni][kb], acch[0][ni]);
        acch[0][ni] = mfmah(ah0, bl[ni][kb], acch[0][ni]);
        acch[0][ni] = mfmah(al0, bh[ni][kb], acch[0][ni]);
        acch[1][ni] = mfmah(ah1, bh[ni][kb], acch[1][ni]);
        acch[1][ni] = mfmah(ah1, bl[ni][kb], acch[1][ni]);
        acch[1][ni] = mfmah(al1, bh[ni][kb], acch[1][ni]);
      }
    }
#pragma unroll
    for (int mi = 0; mi < 2; ++mi)
#pragma unroll
      for (int j = 0; j < 4; ++j) {
        float w = wts[wr * 32 + mi * 16 + lg * 4 + j][h];
        fin[mi][0][j] += w * fmaxf(acch[mi][0][j], 0.f);
        fin[mi][1][j] += w * fmaxf(acch[mi][1][j], 0.f);
      }
    __syncthreads();
  }
#pragma unroll
  for (int mi = 0; mi < 2; ++mi)
#pragma unroll
    for (int ni = 0; ni < 2; ++ni)
#pragma unroll
      for (int j = 0; j < 4; ++j) {
        int row = t0 + wr * 32 + mi * 16 + lg * 4 + j;
        int col = s0 + wc * 32 + ni * 16 + lr;
        score[(size_t)row * T_ + col] = fin[mi][ni][j];
      }
}

// ---------------------------------------------------------------- top-k (exact)
__global__ __launch_bounds__(256) void topk_kernel(
    const float* __restrict__ score, int* __restrict__ selidx,
    int* __restrict__ selcnt) {
  const int t = blockIdx.x;
  const int L = t + 1;
  const int tid = threadIdx.x;
  if (L <= TOPK_) {
    for (int j = tid; j < TOPK_; j += 256)
      selidx[(size_t)t * TOPK_ + j] = (j < L) ? j : 0;
    if (tid == 0) selcnt[t] = L;
    return;
  }
  __shared__ unsigned u[T_];
  __shared__ unsigned hist[16];
  __shared__ unsigned sprefix;
  __shared__ int sk;
  __shared__ int part[256];
  for (int i = tid; i < T_; i += 256) {
    float v = (i < L) ? score[(size_t)t * T_ + i] : -FLT_MAX;
    unsigned b = __float_as_uint(v);
    u[i] = (b & 0x80000000u) ? ~b : (b | 0x80000000u);
  }
  if (tid == 0) { sprefix = 0u; sk = TOPK_; }
  __syncthreads();
  for (int pass = 0; pass < 8; ++pass) {
    const int shift = 28 - 4 * pass;
    if (tid < 16) hist[tid] = 0u;
    __syncthreads();
    unsigned pfx = sprefix;
    for (int i = tid; i < L; i += 256) {
      unsigned val = u[i];
      bool match = (pass == 0) || ((val >> (shift + 4)) == pfx);
      if (match) atomicAdd(&hist[(val >> shift) & 15u], 1u);
    }
    __syncthreads();
    if (tid == 0) {
      int k = sk; unsigned cum = 0u; int bsel = 0;
      for (int bb = 15; bb >= 0; --bb) {
        if (cum + hist[bb] >= (unsigned)k) { bsel = bb; sk = k - (int)cum; break; }
        cum += hist[bb];
      }
      sprefix = (sprefix << 4) | (unsigned)bsel;
    }
    __syncthreads();
  }
  const unsigned thr = sprefix;
  const int kEq = sk;
  const int base = tid * 8;
  int eqloc[8]; int esum = 0;
  for (int r = 0; r < 8; ++r) {
    int i = base + r;
    int f = (i < L && u[i] == thr) ? 1 : 0;
    eqloc[r] = esum; esum += f;
  }
  part[tid] = esum; __syncthreads();
  for (int off = 1; off < 256; off <<= 1) {
    int v = (tid >= off) ? part[tid - off] : 0;
    __syncthreads();
    part[tid] += v;
    __syncthreads();
  }
  const int ebase = (tid > 0) ? part[tid - 1] : 0;
  __syncthreads();
  int sloc[8], selflag[8]; int ssum = 0;
  for (int r = 0; r < 8; ++r) {
    int i = base + r;
    int f = 0;
    if (i < L) {
      unsigned ui = u[i];
      if (ui > thr) f = 1;
      else if (ui == thr && (ebase + eqloc[r]) < kEq) f = 1;
    }
    selflag[r] = f; sloc[r] = ssum; ssum += f;
  }
  part[tid] = ssum; __syncthreads();
  for (int off = 1; off < 256; off <<= 1) {
    int v = (tid >= off) ? part[tid - off] : 0;
    __syncthreads();
    part[tid] += v;
    __syncthreads();
  }
  const int sbase = (tid > 0) ? part[tid - 1] : 0;
  for (int r = 0; r < 8; ++r)
    if (selflag[r]) selidx[(size_t)t * TOPK_ + sbase + sloc[r]] = base + r;
  if (tid == 0) selcnt[t] = TOPK_;
}

// ---------------------------------------------------------------- MLA attention (as round 6)
__global__ __launch_bounds__(256, 3) void attn_mla_kernel(
    const u16* __restrict__ qeff, const u16* __restrict__ qfb,
    const u16* __restrict__ kvcn, const u16* __restrict__ kper,
    const int* __restrict__ selidx, const int* __restrict__ selcnt,
    u16* __restrict__ Olat) {
  const int t = blockIdx.x;
  const int tid = threadIdx.x;
  const int wid = tid >> 6, lane = tid & 63;
  const int lr = lane & 15, lg = lane >> 4;
  __shared__ int sidxs[512];
  __shared__ u16 Pb[16][520];
  __shared__ u16 Vs[32 * 512];
  __shared__ float redm[4][16];
  __shared__ float reds[4][16];
  const int cnt = selcnt[t];
  for (int j = tid; j < 512; j += 256) sidxs[j] = selidx[(size_t)t * TOPK_ + j];
  __syncthreads();

  int srow[8];
  const u16* kb8[8];
#pragma unroll
  for (int m = 0; m < 8; ++m) {
    srow[m] = sidxs[wid * 128 + m * 16 + lr];
    kb8[m] = kvcn + (size_t)srow[m] * 512 + lg * 8;
  }
  const u16* qe = qeff + (size_t)t * (H_ * 512) + lr * 512 + lg * 8;
  const u16* qp = qfb + (size_t)t * (H_ * QKD_) + lr * QKD_ + NOPE_ + lg * 8;
  f32x4 lgv[8] = {};
#pragma unroll
  for (int kb = 0; kb < 16; ++kb) {
    bf16x8 qfk = ld8(qe + kb * 32);
#pragma unroll
    for (int m = 0; m < 8; ++m)
      lgv[m] = mfma16(ld8(kb8[m] + kb * 32), qfk, lgv[m]);
  }
#pragma unroll
  for (int m = 0; m < 8; ++m) kb8[m] = kper + (size_t)srow[m] * 64 + lg * 8;
#pragma unroll
  for (int kb = 0; kb < 2; ++kb) {
    bf16x8 qfk = ld8(qp + kb * 32);
#pragma unroll
    for (int m = 0; m < 8; ++m)
      lgv[m] = mfma16(ld8(kb8[m] + kb * 32), qfk, lgv[m]);
  }

  float mx = -FLT_MAX;
#pragma unroll
  for (int m = 0; m < 8; ++m)
#pragma unroll
    for (int j = 0; j < 4; ++j) {
      int slot = wid * 128 + m * 16 + lg * 4 + j;
      float v = (slot < cnt) ? lgv[m][j] * SCALING_ : -FLT_MAX;
      lgv[m][j] = v;
      mx = fmaxf(mx, v);
    }
  mx = fmaxf(mx, __shfl_xor(mx, 16));
  mx = fmaxf(mx, __shfl_xor(mx, 32));
  if (lane < 16) redm[wid][lane] = mx;
  __syncthreads();
  float hm = fmaxf(fmaxf(redm[0][lr], redm[1][lr]), fmaxf(redm[2][lr], redm[3][lr]));
  float sm = 0.f;
#pragma unroll
  for (int m = 0; m < 8; ++m)
#pragma unroll
    for (int j = 0; j < 4; ++j) {
      int slot = wid * 128 + m * 16 + lg * 4 + j;
      float e = (slot < cnt) ? expf(lgv[m][j] - hm) : 0.f;
      lgv[m][j] = e; sm += e;
    }
  sm += __shfl_xor(sm, 16);
  sm += __shfl_xor(sm, 32);
  if (lane < 16) reds[wid][lane] = sm;
  __syncthreads();
  float inv = 1.f / (reds[0][lr] + reds[1][lr] + reds[2][lr] + reds[3][lr]);
#pragma unroll
  for (int m = 0; m < 8; ++m) {
    int sl = wid * 128 + m * 16 + lg * 4;
    *(u32*)&Pb[lr][sl] = pack2(lgv[m][0] * inv, lgv[m][1] * inv);
    *(u32*)&Pb[lr][sl + 2] = pack2(lgv[m][2] * inv, lgv[m][3] * inv);
  }

  f32x4 oacc[8] = {};
  const int colb = wid * 128 + lr;
  for (int c = 0; c < 16; ++c) {
#pragma unroll
    for (int i = 0; i < 8; ++i) {
      int row = i * 4 + wid;
      int s = sidxs[c * 32 + row];
      int piece = lane ^ ((((row >> 3) & 3)) << 1);
      gload16(kvcn + (size_t)s * 512 + piece * 8, &Vs[row * 512]);
    }
    __syncthreads();
    bf16x8 pa = ld8(&Pb[lr][c * 32 + lg * 8]);
#pragma unroll
    for (int C = 0; C < 8; ++C) {
      union { u32 u[4]; bf16x8 v; } bb;
#pragma unroll
      for (int e = 0; e < 4; ++e) {
        int r0 = lg * 8 + 2 * e;
        int sw = ((r0 >> 3) & 3) << 4;
        int base = r0 * 512 + colb + C * 16;
        bb.u[e] = (u32)Vs[base ^ sw] | ((u32)Vs[(base + 512) ^ sw] << 16);
      }
      oacc[C] = mfma16(pa, bb.v, oacc[C]);
    }
    __syncthreads();
  }
#pragma unroll
  for (int C = 0; C < 8; ++C)
#pragma unroll
    for (int j = 0; j < 4; ++j) {
      int h = lg * 4 + j;
      Olat[(size_t)t * (H_ * 512) + h * 512 + wid * 128 + C * 16 + lr] = f2bf(oacc[C][j]);
    }
}

// ---------------------------------------------------------------- launch
extern "C" void kernel_launch(void* const* d_in, const int* in_sizes, int n_in,
                              void* d_out, int out_size, void* d_ws, size_t ws_size,
                              hipStream_t stream) {
  const float* hidden    = (const float*)d_in[1];
  const float* w_qkv_a   = (const float*)d_in[2];
  const float* q_a_ln_w  = (const float*)d_in[3];
  const float* w_qb      = (const float*)d_in[4];
  const float* kv_a_ln_w = (const float*)d_in[5];
  const float* w_kvb     = (const float*)d_in[6];
  const float* w_o       = (const float*)d_in[7];
  const float* w_idx_qb  = (const float*)d_in[8];
  const float* w_idx_k   = (const float*)d_in[9];
  const float* idx_g     = (const float*)d_in[10];
  const float* idx_b     = (const float*)d_in[11];
  const float* w_wproj   = (const float*)d_in[12];
  const float* b_wproj   = (const float*)d_in[13];

  char* W = (char*)d_ws;
  size_t o = 0;
  auto alloc = [&](size_t bytes) { void* p = W + o; o += (bytes + 255) & ~(size_t)255; return p; };
  float* q_cn  = (float*)alloc((size_t)T_ * QLR_ * 4);
  u16* kv_cn   = (u16*)alloc((size_t)T_ * KVLR_ * 2);
  u16* kper    = (u16*)alloc((size_t)T_ * ROPE_ * 2);
  int* selidx  = (int*)alloc((size_t)T_ * TOPK_ * 4);
  int* selcnt  = (int*)alloc((size_t)T_ * 4);
  float* wgt   = (float*)alloc((size_t)T_ * IDXH_ * 4);
  float* ki    = (float*)alloc((size_t)T_ * IDXD_ * 4);
  u16* kih     = (u16*)alloc((size_t)T_ * IDXD_ * 2);
  u16* kil     = (u16*)alloc((size_t)T_ * IDXD_ * 2);
  u16* hidh    = (u16*)alloc((size_t)T_ * HID_ * 2);
  u16* hidl    = (u16*)alloc((size_t)T_ * HID_ * 2);
  // region S: q_cn splits + wiq splits; reused later as qi splits
  u16* qch     = (u16*)alloc((size_t)T_ * QLR_ * 2);
  u16* qcl     = (u16*)alloc((size_t)T_ * QLR_ * 2);
  u16* wiqh    = (u16*)alloc((size_t)(IDXH_ * IDXD_) * QLR_ * 2);
  u16* wiql    = (u16*)alloc((size_t)(IDXH_ * IDXD_) * QLR_ * 2);
  u16* qih     = qch;                                   // alias (after qi gemm)
  u16* qil     = qch + (size_t)T_ * IDXH_ * IDXD_;
  float* qi    = (float*)alloc((size_t)T_ * IDXH_ * IDXD_ * 4);   // reused: qeff
  u16* qeff    = (u16*)qi;
  float* score = (float*)alloc((size_t)T_ * T_ * 4);    // reused: qfb then attno
  u16* qfb     = (u16*)score;
  u16* attno   = (u16*)score;
  // region R: wqat splits + qkv f32; reused as Olat
  u16* wqath   = (u16*)alloc((size_t)QKVN_ * HID_ * 2);
  u16* wqatl   = (u16*)alloc((size_t)QKVN_ * HID_ * 2);
  float* qkv   = (float*)alloc((size_t)T_ * QKVN_ * 4);
  u16* Olat    = wqath;                                 // alias (after rope_qi_split)
  u16* wikh    = (u16*)alloc((size_t)IDXD_ * HID_ * 2);
  u16* wikl    = (u16*)alloc((size_t)IDXD_ * HID_ * 2);
  u16* wwph    = (u16*)alloc((size_t)IDXH_ * HID_ * 2);
  u16* wwpl    = (u16*)alloc((size_t)IDXH_ * HID_ * 2);
  u16* wqbt    = (u16*)alloc((size_t)(H_ * QKD_) * QLR_ * 2);
  u16* wkvb    = (u16*)alloc((size_t)KVLR_ * (H_ * 256) * 2);
  u16* wkvbt   = (u16*)alloc((size_t)(H_ * 256) * KVLR_ * 2);
  u16* wot     = (u16*)alloc((size_t)(H_ * VD_) * HID_ * 2);

  dim3 blk(256);
  auto g2 = [](int M, int N, int Z) { return dim3((N + 127) / 128, M / 128, Z); };

  // weight / activation prep
  transpose_split_f16_k<<<dim3(33, 32), blk, 0, stream>>>(w_qkv_a, wqath, wqatl, HID_, QKVN_);
  transpose_split_f16_k<<<dim3(64, 24), blk, 0, stream>>>(w_idx_qb, wiqh, wiql, QLR_, IDXH_ * IDXD_);
  transpose_split_f16_k<<<dim3(2, 32), blk, 0, stream>>>(w_idx_k, wikh, wikl, HID_, IDXD_);
  transpose_split_f16_k<<<dim3(1, 32), blk, 0, stream>>>(w_wproj, wwph, wwpl, HID_, IDXH_);
  split_f16_k<<<2048, blk, 0, stream>>>(hidden, hidh, hidl, (long)T_ * HID_);
  transpose_bf16_k<<<dim3(48, 24), blk, 0, stream>>>(w_qb, wqbt, QLR_, H_ * QKD_);
  transpose_bf16_k<<<dim3(64, 8), blk, 0, stream>>>(w_kvb, wkvbt, KVLR_, H_ * 256);
  transpose_bf16_k<<<dim3(32, 32), blk, 0, stream>>>(w_o, wot, H_ * VD_, HID_);
  conv_bf16_k<<<2048, blk, 0, stream>>>(w_kvb, wkvb, (long)KVLR_ * H_ * 256);

  // strict path (pre-split f16 MFMA)
  gemm_hl<<<g2(T_, QKVN_, 1), blk, 0, stream>>>(hidh, hidl, HID_, wqath, wqatl, HID_, qkv, QKVN_, QKVN_, HID_);
  rmsnorm_kernel<<<T_, blk, 0, stream>>>(qkv, q_a_ln_w, kv_a_ln_w, q_cn, qch, qcl, kv_cn);
  rope_kpe_kernel<<<T_, 64, 0, stream>>>(qkv, kper);

  gemm_hl<<<g2(T_, IDXH_ * IDXD_, 1), blk, 0, stream>>>(qch, qcl, QLR_, wiqh, wiql, QLR_, qi, IDXH_ * IDXD_, IDXH_ * IDXD_, QLR_);
  gemm_hl<<<g2(T_, IDXD_, 1), blk, 0, stream>>>(hidh, hidl, HID_, wikh, wikl, HID_, ki, IDXD_, IDXD_, HID_);
  ki_ln_rope_kernel<<<T_, 128, 0, stream>>>(ki, idx_g, idx_b, kih, kil);
  gemm_hl<<<g2(T_, IDXH_, 1), blk, 0, stream>>>(hidh, hidl, HID_, wwph, wwpl, HID_, wgt, IDXH_, IDXH_, HID_);
  w_epi_kernel<<<(T_ * IDXH_ + 255) / 256, blk, 0, stream>>>(wgt, b_wproj);
  rope_qi_split_kernel<<<T_, blk, 0, stream>>>(qi, qih, qil);   // overwrites qch/wiq region (dead)

  score_mfma<<<dim3(32, 32), blk, 0, stream>>>(qih, qil, kih, kil, wgt, score);
  topk_kernel<<<T_, blk, 0, stream>>>(score, selidx, selcnt);

  // tolerant path (bf16 MFMA)
  gemm_t<1, 1><<<g2(T_, H_ * QKD_, 1), blk, 0, stream>>>(q_cn, QLR_, 0, wqbt, QLR_, 0, qfb, H_ * QKD_, 0, H_ * QKD_, QLR_);
  rope_q_bf_kernel<<<T_, blk, 0, stream>>>(qfb);
  gemm_t<0, 1><<<g2(T_, 512, H_), blk, 0, stream>>>(qfb, H_ * QKD_, QKD_, wkvb, H_ * 256, 256, qeff, H_ * 512, 512, 512, NOPE_);
  attn_mla_kernel<<<T_, blk, 0, stream>>>(qeff, qfb, kv_cn, kper, selidx, selcnt, Olat);
  gemm_t<0, 1><<<g2(T_, VD_, H_), blk, 0, stream>>>(Olat, H_ * 512, 512, wkvbt + 128 * 512, KVLR_, 256 * 512, attno, H_ * VD_, VD_, VD_, 512);
  gemm_t<0, 0><<<g2(T_, HID_, 1), blk, 0, stream>>>(attno, H_ * VD_, 0, wot, H_ * VD_, 0, d_out, HID_, 0, HID_, H_ * VD_);
}

// Round 9
// 829.756 us; speedup vs baseline: 6.0448x; 1.2180x over previous
//
#include <hip/hip_runtime.h>
#include <cfloat>
#include <cmath>

#define T_    2048
#define HID_  2048
#define QKVN_ 2112
#define QKVX_ 2272   // fused: 2112 qkv | 128 ki | 32 wgt
#define QLR_  1536
#define KVLR_ 512
#define ROPE_ 64
#define NOPE_ 128
#define QKD_  192
#define VD_   128
#define H_    16
#define IDXH_ 32
#define IDXD_ 128
#define TOPK_ 512
#define EPS_  1e-6f
#define SCALING_ 0.07216878364870323f   // 192^-0.5

typedef unsigned int u32;
typedef unsigned short u16;
typedef __bf16 bf16x8 __attribute__((ext_vector_type(8)));
typedef _Float16 f16;
typedef f16 f16x8 __attribute__((ext_vector_type(8)));
typedef float f32x4 __attribute__((ext_vector_type(4)));

__device__ __forceinline__ u16 f2bf(float x) {
  u32 u = __float_as_uint(x);
  u32 r = (u + 0x7fffu + ((u >> 16) & 1u)) >> 16;
  return (u16)r;
}
__device__ __forceinline__ float bf2f(u16 h) { return __uint_as_float(((u32)h) << 16); }
__device__ __forceinline__ u32 pack2(float a, float b) { return (u32)f2bf(a) | ((u32)f2bf(b) << 16); }
__device__ __forceinline__ bf16x8 ld8(const void* p) { return *(const bf16x8*)p; }
__device__ __forceinline__ f32x4 mfma16(bf16x8 a, bf16x8 b, f32x4 c) {
  return __builtin_amdgcn_mfma_f32_16x16x32_bf16(a, b, c, 0, 0, 0);
}
__device__ __forceinline__ u16 hbits(f16 h) { union { f16 h; u16 u; } c; c.h = h; return c.u; }
__device__ __forceinline__ u32 hpack(f16 a, f16 b) { return (u32)hbits(a) | ((u32)hbits(b) << 16); }
__device__ __forceinline__ f16x8 ldh8(const void* p) { return *(const f16x8*)p; }
__device__ __forceinline__ f32x4 mfmah(f16x8 a, f16x8 b, f32x4 c) {
  return __builtin_amdgcn_mfma_f32_16x16x32_f16(a, b, c, 0, 0, 0);
}
__device__ __forceinline__ void gload16(const u16* g, u16* l) {
  __builtin_amdgcn_global_load_lds(
      (__attribute__((address_space(1))) void*)(g),
      (__attribute__((address_space(3))) void*)(l), 16, 0, 0);
}

// ---------------------------------------------------------------- prep (multi-job)
struct TSJob { const float* src; u16* oh; u16* ol; int K; int N; };
// in[K,N] f32 -> oh/ol[N,K] f16 hi/lo
__global__ __launch_bounds__(256) void transpose_split_multi(
    TSJob j0, TSJob j1, TSJob j2, TSJob j3) {
  TSJob jb = (blockIdx.z == 0) ? j0 : (blockIdx.z == 1) ? j1 : (blockIdx.z == 2) ? j2 : j3;
  int k0 = blockIdx.y * 64, n0 = blockIdx.x * 64;
  if (k0 >= jb.K || n0 >= jb.N) return;
  __shared__ float t[64][65];
  for (int j = 0; j < 16; ++j) {
    int u = threadIdx.x + 256 * j; int r = u >> 6, c = u & 63;
    t[r][c] = (k0 + r < jb.K && n0 + c < jb.N) ? jb.src[(size_t)(k0 + r) * jb.N + n0 + c] : 0.f;
  }
  __syncthreads();
  for (int j = 0; j < 16; ++j) {
    int u = threadIdx.x + 256 * j; int r = u >> 6, c = u & 63;
    if (n0 + r < jb.N && k0 + c < jb.K) {
      float v = t[c][r];
      f16 h = (f16)v;
      jb.oh[(size_t)(n0 + r) * jb.K + k0 + c] = hbits(h);
      jb.ol[(size_t)(n0 + r) * jb.K + k0 + c] = hbits((f16)(v - (float)h));
    }
  }
}

struct TBJob { const float* src; u16* out; int K; int N; };
__global__ __launch_bounds__(256) void transpose_bf16_multi(TBJob j0, TBJob j1, TBJob j2) {
  TBJob jb = (blockIdx.z == 0) ? j0 : (blockIdx.z == 1) ? j1 : j2;
  int k0 = blockIdx.y * 64, n0 = blockIdx.x * 64;
  if (k0 >= jb.K || n0 >= jb.N) return;
  __shared__ float t[64][65];
  for (int j = 0; j < 16; ++j) {
    int u = threadIdx.x + 256 * j; int r = u >> 6, c = u & 63;
    t[r][c] = (k0 + r < jb.K && n0 + c < jb.N) ? jb.src[(size_t)(k0 + r) * jb.N + n0 + c] : 0.f;
  }
  __syncthreads();
  for (int j = 0; j < 16; ++j) {
    int u = threadIdx.x + 256 * j; int r = u >> 6, c = u & 63;
    if (n0 + r < jb.N && k0 + c < jb.K) jb.out[(size_t)(n0 + r) * jb.K + k0 + c] = f2bf(t[c][r]);
  }
}

__global__ __launch_bounds__(256) void split_f16_k(
    const float* __restrict__ in, u16* __restrict__ hi, u16* __restrict__ lo, long n) {
  for (long i = ((long)blockIdx.x * 256 + threadIdx.x) * 4; i < n; i += (long)gridDim.x * 1024) {
    float4 v = *(const float4*)(in + i);
    f16 a = (f16)v.x, b = (f16)v.y, c = (f16)v.z, d = (f16)v.w;
    *(u32*)(hi + i) = hpack(a, b);
    *(u32*)(hi + i + 2) = hpack(c, d);
    *(u32*)(lo + i) = hpack((f16)(v.x - (float)a), (f16)(v.y - (float)b));
    *(u32*)(lo + i + 2) = hpack((f16)(v.z - (float)c), (f16)(v.w - (float)d));
  }
}

__global__ __launch_bounds__(256) void conv_bf16_k(
    const float* __restrict__ in, u16* __restrict__ out, long n) {
  for (long i = ((long)blockIdx.x * 256 + threadIdx.x) * 4; i < n; i += (long)gridDim.x * 1024) {
    float4 v = *(const float4*)(in + i);
    *(u32*)(out + i) = pack2(v.x, v.y);
    *(u32*)(out + i + 2) = pack2(v.z, v.w);
  }
}

// ---------------------------------------------------------------- strict GEMM from pre-split hi/lo
// C = A @ Bt^T (f16 hi/lo, 3-term). Cols >= bcol0 get (v + bias[col-bcol0]) * bscale.
__global__ __launch_bounds__(256) void gemm_hl(
    const u16* __restrict__ Ah_, const u16* __restrict__ Al_, int lda,
    const u16* __restrict__ Bh_, const u16* __restrict__ Bl_, int ldb,
    float* __restrict__ C, int ldc, const float* __restrict__ bias, int bcol0,
    float bscale, int N, int K) {
  __shared__ u32 Ah[128][20], Al[128][20], Bh[128][20], Bl[128][20];
  const int tid = threadIdx.x;
  const int bm = blockIdx.y * 128, bn = blockIdx.x * 128;
  const int wid = tid >> 6, lane = tid & 63, wr = wid >> 1, wc = wid & 1;
  const int lr = lane & 15, lg = lane >> 4;
  f32x4 acc[4][4] = {};
  for (int k0 = 0; k0 < K; k0 += 32) {
#pragma unroll
    for (int j = 0; j < 2; ++j) {
      int u = tid + 256 * j; int row = u >> 2, p = u & 3;
      size_t ga = (size_t)(bm + row) * lda + k0 + p * 8;
      *(uint4*)&Ah[row][p * 4] = *(const uint4*)(Ah_ + ga);
      *(uint4*)&Al[row][p * 4] = *(const uint4*)(Al_ + ga);
      uint4 vh = make_uint4(0, 0, 0, 0), vl = make_uint4(0, 0, 0, 0);
      if (bn + row < N) {
        size_t gb = (size_t)(bn + row) * ldb + k0 + p * 8;
        vh = *(const uint4*)(Bh_ + gb);
        vl = *(const uint4*)(Bl_ + gb);
      }
      *(uint4*)&Bh[row][p * 4] = vh;
      *(uint4*)&Bl[row][p * 4] = vl;
    }
    __syncthreads();
    f16x8 ah[4], al[4], bh[4], bl[4];
#pragma unroll
    for (int i = 0; i < 4; ++i) {
      ah[i] = ldh8(&Ah[wr * 64 + i * 16 + lr][lg * 4]);
      al[i] = ldh8(&Al[wr * 64 + i * 16 + lr][lg * 4]);
      bh[i] = ldh8(&Bh[wc * 64 + i * 16 + lr][lg * 4]);
      bl[i] = ldh8(&Bl[wc * 64 + i * 16 + lr][lg * 4]);
    }
#pragma unroll
    for (int i = 0; i < 4; ++i)
#pragma unroll
      for (int jn = 0; jn < 4; ++jn) {
        acc[i][jn] = mfmah(ah[i], bh[jn], acc[i][jn]);
        acc[i][jn] = mfmah(ah[i], bl[jn], acc[i][jn]);
        acc[i][jn] = mfmah(al[i], bh[jn], acc[i][jn]);
      }
    __syncthreads();
  }
#pragma unroll
  for (int i = 0; i < 4; ++i)
#pragma unroll
    for (int jn = 0; jn < 4; ++jn)
#pragma unroll
      for (int j = 0; j < 4; ++j) {
        int row = bm + wr * 64 + i * 16 + lg * 4 + j;
        int col = bn + wc * 64 + jn * 16 + lr;
        if (col < N) {
          float v = acc[i][jn][j];
          if (col >= bcol0) v = (v + bias[col - bcol0]) * bscale;
          C[(size_t)row * ldc + col] = v;
        }
      }
}

// ---------------------------------------------------------------- tolerant bf16 GEMM
template <int AF32, int CBF16>
__global__ __launch_bounds__(256) void gemm_t(
    const void* __restrict__ Ap, int lda, long aoz,
    const u16* __restrict__ Bt, int ldb, long boz,
    void* __restrict__ Cp, int ldc, long coz, int N, int K) {
  __shared__ u32 As[128][20], Bs[128][20];
  const int tid = threadIdx.x;
  const int z = blockIdx.z;
  const int bm = blockIdx.y * 128, bn = blockIdx.x * 128;
  const int wid = tid >> 6, lane = tid & 63, wr = wid >> 1, wc = wid & 1;
  const int lr = lane & 15, lg = lane >> 4;
  f32x4 acc[4][4] = {};
  for (int k0 = 0; k0 < K; k0 += 32) {
    if (AF32) {
      const float* A = (const float*)Ap + aoz * z;
#pragma unroll
      for (int j = 0; j < 4; ++j) {
        int u = tid + 256 * j; int row = u >> 3, p = u & 7;
        float4 v = *(const float4*)(A + (size_t)(bm + row) * lda + k0 + p * 4);
        As[row][p * 2] = pack2(v.x, v.y);
        As[row][p * 2 + 1] = pack2(v.z, v.w);
      }
    } else {
      const u16* A = (const u16*)Ap + aoz * z;
#pragma unroll
      for (int j = 0; j < 2; ++j) {
        int u = tid + 256 * j; int row = u >> 2, p = u & 3;
        uint4 v = *(const uint4*)(A + (size_t)(bm + row) * lda + k0 + p * 8);
        *(uint4*)&As[row][p * 4] = v;
      }
    }
#pragma unroll
    for (int j = 0; j < 2; ++j) {
      int u = tid + 256 * j; int row = u >> 2, p = u & 3;
      uint4 v = make_uint4(0, 0, 0, 0);
      if (bn + row < N) v = *(const uint4*)(Bt + boz * z + (size_t)(bn + row) * ldb + k0 + p * 8);
      *(uint4*)&Bs[row][p * 4] = v;
    }
    __syncthreads();
    bf16x8 af[4], bf[4];
#pragma unroll
    for (int i = 0; i < 4; ++i) {
      af[i] = ld8(&As[wr * 64 + i * 16 + lr][lg * 4]);
      bf[i] = ld8(&Bs[wc * 64 + i * 16 + lr][lg * 4]);
    }
#pragma unroll
    for (int i = 0; i < 4; ++i)
#pragma unroll
      for (int jn = 0; jn < 4; ++jn)
        acc[i][jn] = mfma16(af[i], bf[jn], acc[i][jn]);
    __syncthreads();
  }
#pragma unroll
  for (int i = 0; i < 4; ++i)
#pragma unroll
    for (int jn = 0; jn < 4; ++jn)
#pragma unroll
      for (int j = 0; j < 4; ++j) {
        int row = bm + wr * 64 + i * 16 + lg * 4 + j;
        int col = bn + wc * 64 + jn * 16 + lr;
        if (col < N) {
          if (CBF16) ((u16*)Cp)[coz * z + (size_t)row * ldc + col] = f2bf(acc[i][jn][j]);
          else ((float*)Cp)[coz * z + (size_t)row * ldc + col] = acc[i][jn][j];
        }
      }
}

// ---------------------------------------------------------------- RMS norms (+ q_cn f16 split)
__global__ __launch_bounds__(256) void rmsnorm_kernel(
    const float* __restrict__ qkvx, const float* __restrict__ qw,
    const float* __restrict__ kvw, float* __restrict__ q_cn,
    u16* __restrict__ qch, u16* __restrict__ qcl, u16* __restrict__ kv_cn) {
  const int t = blockIdx.x, tid = threadIdx.x;
  const float* row = qkvx + (size_t)t * QKVX_;
  __shared__ float red[256];
  float ss = 0.f;
  for (int i = tid; i < QLR_; i += 256) { float v = row[i]; ss += v * v; }
  red[tid] = ss; __syncthreads();
  for (int s = 128; s; s >>= 1) { if (tid < s) red[tid] += red[tid + s]; __syncthreads(); }
  float scl = 1.0f / sqrtf(red[0] / (float)QLR_ + EPS_);
  for (int i = tid; i < QLR_; i += 256) {
    float val = row[i] * scl * qw[i];
    q_cn[(size_t)t * QLR_ + i] = val;
    f16 h = (f16)val;
    qch[(size_t)t * QLR_ + i] = hbits(h);
    qcl[(size_t)t * QLR_ + i] = hbits((f16)(val - (float)h));
  }
  __syncthreads();
  ss = 0.f;
  for (int i = tid; i < KVLR_; i += 256) { float v = row[QLR_ + i]; ss += v * v; }
  red[tid] = ss; __syncthreads();
  for (int s = 128; s; s >>= 1) { if (tid < s) red[tid] += red[tid + s]; __syncthreads(); }
  scl = 1.0f / sqrtf(red[0] / (float)KVLR_ + EPS_);
  for (int i = tid; i < KVLR_; i += 256)
    kv_cn[(size_t)t * KVLR_ + i] = f2bf(row[QLR_ + i] * scl * kvw[i]);
}

// ---------------------------------------------------------------- RoPE helpers
__device__ __forceinline__ void rope_pair(float pos, int j, float& x0, float& x1) {
  float inv = powf(10000.f, -(float)j * (1.f / 32.f));
  float f = pos * inv;
  float c = cosf(f), s = sinf(f);
  float a = x0, b = x1;
  x0 = a * c - b * s;
  x1 = a * s + b * c;
}

__global__ __launch_bounds__(256) void rope_qi_split_kernel(
    const float* __restrict__ qi, u16* __restrict__ qih, u16* __restrict__ qil) {
  const int t = blockIdx.x, tid = threadIdx.x;
  float pos = (float)t;
  const float* src = qi + (size_t)t * (IDXH_ * IDXD_);
  u16* dh = qih + (size_t)t * (IDXH_ * IDXD_);
  u16* dl = qil + (size_t)t * (IDXH_ * IDXD_);
  for (int p = tid; p < IDXH_ * IDXD_ / 2; p += 256) {
    int d = p & 63;
    float x0 = src[2 * p], x1 = src[2 * p + 1];
    if (d < 32) rope_pair(pos, d, x0, x1);
    f16 h0 = (f16)x0, h1 = (f16)x1;
    *(u32*)(dh + 2 * p) = hpack(h0, h1);
    *(u32*)(dl + 2 * p) = hpack((f16)(x0 - (float)h0), (f16)(x1 - (float)h1));
  }
}

__global__ __launch_bounds__(256) void rope_q_bf_kernel(u16* __restrict__ qfb) {
  const int t = blockIdx.x, tid = threadIdx.x;
  float pos = (float)t;
  for (int idx = tid; idx < H_ * 32; idx += 256) {
    int hh = idx / 32, j = idx % 32;
    u16* p = qfb + (size_t)t * (H_ * QKD_) + hh * QKD_ + NOPE_ + 2 * j;
    float x0 = bf2f(p[0]), x1 = bf2f(p[1]);
    rope_pair(pos, j, x0, x1);
    p[0] = f2bf(x0); p[1] = f2bf(x1);
  }
}

__global__ __launch_bounds__(64) void rope_kpe_kernel(
    const float* __restrict__ qkvx, u16* __restrict__ kper) {
  const int t = blockIdx.x, tid = threadIdx.x;
  if (tid >= 32) return;
  float pos = (float)t;
  const float* p = qkvx + (size_t)t * QKVX_ + (QLR_ + KVLR_);
  float x0 = p[2 * tid], x1 = p[2 * tid + 1];
  rope_pair(pos, tid, x0, x1);
  kper[(size_t)t * ROPE_ + 2 * tid] = f2bf(x0);
  kper[(size_t)t * ROPE_ + 2 * tid + 1] = f2bf(x1);
}

// ---------------------------------------------------------------- ki: LN + rope -> f16 hi/lo
__global__ __launch_bounds__(128) void ki_ln_rope_kernel(
    const float* __restrict__ qkvx, const float* __restrict__ gamma,
    const float* __restrict__ beta, u16* __restrict__ kih, u16* __restrict__ kil) {
  const int t = blockIdx.x, tid = threadIdx.x;
  __shared__ float x[128];
  __shared__ float red[128];
  float v = qkvx[(size_t)t * QKVX_ + QKVN_ + tid];
  red[tid] = v; __syncthreads();
  for (int s = 64; s; s >>= 1) { if (tid < s) red[tid] += red[tid + s]; __syncthreads(); }
  float mu = red[0] / 128.f;
  __syncthreads();
  float d = v - mu;
  red[tid] = d * d; __syncthreads();
  for (int s = 64; s; s >>= 1) { if (tid < s) red[tid] += red[tid + s]; __syncthreads(); }
  float var = red[0] / 128.f;
  float y = d * (1.0f / sqrtf(var + EPS_)) * gamma[tid] + beta[tid];
  x[tid] = y; __syncthreads();
  float pos = (float)t;
  if (tid < 32) {
    float x0 = x[2 * tid], x1 = x[2 * tid + 1];
    rope_pair(pos, tid, x0, x1);
    x[2 * tid] = x0; x[2 * tid + 1] = x1;
  }
  __syncthreads();
  float fv = x[tid];
  f16 h = (f16)fv;
  kih[(size_t)t * IDXD_ + tid] = hbits(h);
  kil[(size_t)t * IDXD_ + tid] = hbits((f16)(fv - (float)h));
}

// ---------------------------------------------------------------- indexer score (pre-split f16 MFMA)
__global__ __launch_bounds__(256) void score_mfma(
    const u16* __restrict__ qih, const u16* __restrict__ qil,
    const u16* __restrict__ kih, const u16* __restrict__ kil,
    const float* __restrict__ wgt, int ldw, float* __restrict__ score) {
  const int s0 = blockIdx.x * 64, t0 = blockIdx.y * 64;
  if (s0 > t0 + 63) return;
  __shared__ u32 Kh[64][68], Kl[64][68], Qh[64][68], Ql[64][68];
  __shared__ float wts[64][33];
  const int tid = threadIdx.x;
  const int wid = tid >> 6, lane = tid & 63, wr = wid >> 1, wc = wid & 1;
  const int lr = lane & 15, lg = lane >> 4;
#pragma unroll
  for (int j = 0; j < 4; ++j) {
    int u = tid + 256 * j; int row = u >> 4, p = u & 15;
    *(uint4*)&Kh[row][p * 4] = *(const uint4*)(kih + (size_t)(s0 + row) * IDXD_ + p * 8);
    *(uint4*)&Kl[row][p * 4] = *(const uint4*)(kil + (size_t)(s0 + row) * IDXD_ + p * 8);
  }
#pragma unroll
  for (int j = 0; j < 8; ++j) {
    int u = tid + 256 * j; int r = u >> 5, c = u & 31;
    wts[r][c] = wgt[(size_t)(t0 + r) * ldw + c];
  }
  __syncthreads();
  f16x8 bh[2][4], bl[2][4];
#pragma unroll
  for (int ni = 0; ni < 2; ++ni)
#pragma unroll
    for (int kb = 0; kb < 4; ++kb) {
      bh[ni][kb] = ldh8(&Kh[wc * 32 + ni * 16 + lr][kb * 16 + lg * 4]);
      bl[ni][kb] = ldh8(&Kl[wc * 32 + ni * 16 + lr][kb * 16 + lg * 4]);
    }
  f32x4 fin[2][2] = {};
  for (int h = 0; h < IDXH_; ++h) {
#pragma unroll
    for (int j = 0; j < 4; ++j) {
      int u = tid + 256 * j; int row = u >> 4, p = u & 15;
      size_t g = (size_t)(t0 + row) * (IDXH_ * IDXD_) + h * IDXD_ + p * 8;
      *(uint4*)&Qh[row][p * 4] = *(const uint4*)(qih + g);
      *(uint4*)&Ql[row][p * 4] = *(const uint4*)(qil + g);
    }
    __syncthreads();
    f32x4 acch[2][2] = {};
#pragma unroll
    for (int kb = 0; kb < 4; ++kb) {
      f16x8 ah0 = ldh8(&Qh[wr * 32 + lr][kb * 16 + lg * 4]);
      f16x8 ah1 = ldh8(&Qh[wr * 32 + 16 + lr][kb * 16 + lg * 4]);
      f16x8 al0 = ldh8(&Ql[wr * 32 + lr][kb * 16 + lg * 4]);
      f16x8 al1 = ldh8(&Ql[wr * 32 + 16 + lr][kb * 16 + lg * 4]);
#pragma unroll
      for (int ni = 0; ni < 2; ++ni) {
        acch[0][ni] = mfmah(ah0, bh[ni][kb], acch[0][ni]);
        acch[0][ni] = mfmah(ah0, bl[ni][kb], acch[0][ni]);
        acch[0][ni] = mfmah(al0, bh[ni][kb], acch[0][ni]);
        acch[1][ni] = mfmah(ah1, bh[ni][kb], acch[1][ni]);
        acch[1][ni] = mfmah(ah1, bl[ni][kb], acch[1][ni]);
        acch[1][ni] = mfmah(al1, bh[ni][kb], acch[1][ni]);
      }
    }
#pragma unroll
    for (int mi = 0; mi < 2; ++mi)
#pragma unroll
      for (int j = 0; j < 4; ++j) {
        float w = wts[wr * 32 + mi * 16 + lg * 4 + j][h];
        fin[mi][0][j] += w * fmaxf(acch[mi][0][j], 0.f);
        fin[mi][1][j] += w * fmaxf(acch[mi][1][j], 0.f);
      }
    __syncthreads();
  }
#pragma unroll
  for (int mi = 0; mi < 2; ++mi)
#pragma unroll
    for (int ni = 0; ni < 2; ++ni)
#pragma unroll
      for (int j = 0; j < 4; ++j) {
        int row = t0 + wr * 32 + mi * 16 + lg * 4 + j;
        int col = s0 + wc * 32 + ni * 16 + lr;
        score[(size_t)row * T_ + col] = fin[mi][ni][j];
      }
}

// ---------------------------------------------------------------- top-k (exact)
__global__ __launch_bounds__(256) void topk_kernel(
    const float* __restrict__ score, int* __restrict__ selidx,
    int* __restrict__ selcnt) {
  const int t = blockIdx.x;
  const int L = t + 1;
  const int tid = threadIdx.x;
  if (L <= TOPK_) {
    for (int j = tid; j < TOPK_; j += 256)
      selidx[(size_t)t * TOPK_ + j] = (j < L) ? j : 0;
    if (tid == 0) selcnt[t] = L;
    return;
  }
  __shared__ unsigned u[T_];
  __shared__ unsigned hist[16];
  __shared__ unsigned sprefix;
  __shared__ int sk;
  __shared__ int part[256];
  for (int i = tid; i < T_; i += 256) {
    float v = (i < L) ? score[(size_t)t * T_ + i] : -FLT_MAX;
    unsigned b = __float_as_uint(v);
    u[i] = (b & 0x80000000u) ? ~b : (b | 0x80000000u);
  }
  if (tid == 0) { sprefix = 0u; sk = TOPK_; }
  __syncthreads();
  for (int pass = 0; pass < 8; ++pass) {
    const int shift = 28 - 4 * pass;
    if (tid < 16) hist[tid] = 0u;
    __syncthreads();
    unsigned pfx = sprefix;
    for (int i = tid; i < L; i += 256) {
      unsigned val = u[i];
      bool match = (pass == 0) || ((val >> (shift + 4)) == pfx);
      if (match) atomicAdd(&hist[(val >> shift) & 15u], 1u);
    }
    __syncthreads();
    if (tid == 0) {
      int k = sk; unsigned cum = 0u; int bsel = 0;
      for (int bb = 15; bb >= 0; --bb) {
        if (cum + hist[bb] >= (unsigned)k) { bsel = bb; sk = k - (int)cum; break; }
        cum += hist[bb];
      }
      sprefix = (sprefix << 4) | (unsigned)bsel;
    }
    __syncthreads();
  }
  const unsigned thr = sprefix;
  const int kEq = sk;
  const int base = tid * 8;
  int eqloc[8]; int esum = 0;
  for (int r = 0; r < 8; ++r) {
    int i = base + r;
    int f = (i < L && u[i] == thr) ? 1 : 0;
    eqloc[r] = esum; esum += f;
  }
  part[tid] = esum; __syncthreads();
  for (int off = 1; off < 256; off <<= 1) {
    int v = (tid >= off) ? part[tid - off] : 0;
    __syncthreads();
    part[tid] += v;
    __syncthreads();
  }
  const int ebase = (tid > 0) ? part[tid - 1] : 0;
  __syncthreads();
  int sloc[8], selflag[8]; int ssum = 0;
  for (int r = 0; r < 8; ++r) {
    int i = base + r;
    int f = 0;
    if (i < L) {
      unsigned ui = u[i];
      if (ui > thr) f = 1;
      else if (ui == thr && (ebase + eqloc[r]) < kEq) f = 1;
    }
    selflag[r] = f; sloc[r] = ssum; ssum += f;
  }
  part[tid] = ssum; __syncthreads();
  for (int off = 1; off < 256; off <<= 1) {
    int v = (tid >= off) ? part[tid - off] : 0;
    __syncthreads();
    part[tid] += v;
    __syncthreads();
  }
  const int sbase = (tid > 0) ? part[tid - 1] : 0;
  for (int r = 0; r < 8; ++r)
    if (selflag[r]) selidx[(size_t)t * TOPK_ + sbase + sloc[r]] = base + r;
  if (tid == 0) selcnt[t] = TOPK_;
}

// ---------------------------------------------------------------- MLA attention (QK prefetch)
__global__ __launch_bounds__(256, 3) void attn_mla_kernel(
    const u16* __restrict__ qeff, const u16* __restrict__ qfb,
    const u16* __restrict__ kvcn, const u16* __restrict__ kper,
    const int* __restrict__ selidx, const int* __restrict__ selcnt,
    u16* __restrict__ Olat) {
  const int t = blockIdx.x;
  const int tid = threadIdx.x;
  const int wid = tid >> 6, lane = tid & 63;
  const int lr = lane & 15, lg = lane >> 4;
  __shared__ int sidxs[512];
  __shared__ u16 Pb[16][520];
  __shared__ u16 Vs[32 * 512];
  __shared__ float redm[4][16];
  __shared__ float reds[4][16];
  const int cnt = selcnt[t];
  for (int j = tid; j < 512; j += 256) sidxs[j] = selidx[(size_t)t * TOPK_ + j];
  __syncthreads();

  // ---- QK^T with 1-deep register double-buffer of K gathers
  int srow[8];
  const u16* kb8[8];
  const u16* kp8[8];
#pragma unroll
  for (int m = 0; m < 8; ++m) {
    srow[m] = sidxs[wid * 128 + m * 16 + lr];
    kb8[m] = kvcn + (size_t)srow[m] * 512 + lg * 8;
    kp8[m] = kper + (size_t)srow[m] * 64 + lg * 8;
  }
  const u16* qe = qeff + (size_t)t * (H_ * 512) + lr * 512 + lg * 8;
  const u16* qp = qfb + (size_t)t * (H_ * QKD_) + lr * QKD_ + NOPE_ + lg * 8;
  f32x4 lgv[8] = {};
  bf16x8 kc[8];
#pragma unroll
  for (int m = 0; m < 8; ++m) kc[m] = ld8(kb8[m]);
#pragma unroll
  for (int kb = 0; kb < 16; ++kb) {
    bf16x8 qfk = ld8(qe + kb * 32);
    bf16x8 kn[8];
#pragma unroll
    for (int m = 0; m < 8; ++m)
      kn[m] = (kb < 15) ? ld8(kb8[m] + (kb + 1) * 32) : ld8(kp8[m]);
#pragma unroll
    for (int m = 0; m < 8; ++m) lgv[m] = mfma16(kc[m], qfk, lgv[m]);
#pragma unroll
    for (int m = 0; m < 8; ++m) kc[m] = kn[m];
  }
  {
    bf16x8 qfk = ld8(qp);
    bf16x8 kn[8];
#pragma unroll
    for (int m = 0; m < 8; ++m) kn[m] = ld8(kp8[m] + 32);
#pragma unroll
    for (int m = 0; m < 8; ++m) lgv[m] = mfma16(kc[m], qfk, lgv[m]);
#pragma unroll
    for (int m = 0; m < 8; ++m) kc[m] = kn[m];
  }
  {
    bf16x8 qfk = ld8(qp + 32);
#pragma unroll
    for (int m = 0; m < 8; ++m) lgv[m] = mfma16(kc[m], qfk, lgv[m]);
  }

  // ---- softmax (head = lr)
  float mx = -FLT_MAX;
#pragma unroll
  for (int m = 0; m < 8; ++m)
#pragma unroll
    for (int j = 0; j < 4; ++j) {
      int slot = wid * 128 + m * 16 + lg * 4 + j;
      float v = (slot < cnt) ? lgv[m][j] * SCALING_ : -FLT_MAX;
      lgv[m][j] = v;
      mx = fmaxf(mx, v);
    }
  mx = fmaxf(mx, __shfl_xor(mx, 16));
  mx = fmaxf(mx, __shfl_xor(mx, 32));
  if (lane < 16) redm[wid][lane] = mx;
  __syncthreads();
  float hm = fmaxf(fmaxf(redm[0][lr], redm[1][lr]), fmaxf(redm[2][lr], redm[3][lr]));
  float sm = 0.f;
#pragma unroll
  for (int m = 0; m < 8; ++m)
#pragma unroll
    for (int j = 0; j < 4; ++j) {
      int slot = wid * 128 + m * 16 + lg * 4 + j;
      float e = (slot < cnt) ? expf(lgv[m][j] - hm) : 0.f;
      lgv[m][j] = e; sm += e;
    }
  sm += __shfl_xor(sm, 16);
  sm += __shfl_xor(sm, 32);
  if (lane < 16) reds[wid][lane] = sm;
  __syncthreads();
  float inv = 1.f / (reds[0][lr] + reds[1][lr] + reds[2][lr] + reds[3][lr]);
#pragma unroll
  for (int m = 0; m < 8; ++m) {
    int sl = wid * 128 + m * 16 + lg * 4;
    *(u32*)&Pb[lr][sl] = pack2(lgv[m][0] * inv, lgv[m][1] * inv);
    *(u32*)&Pb[lr][sl + 2] = pack2(lgv[m][2] * inv, lgv[m][3] * inv);
  }

  // ---- PV via DMA-staged V chunks (pre-swizzled source)
  f32x4 oacc[8] = {};
  const int colb = wid * 128 + lr;
  for (int c = 0; c < 16; ++c) {
#pragma unroll
    for (int i = 0; i < 8; ++i) {
      int row = i * 4 + wid;
      int s = sidxs[c * 32 + row];
      int piece = lane ^ ((((row >> 3) & 3)) << 1);
      gload16(kvcn + (size_t)s * 512 + piece * 8, &Vs[row * 512]);
    }
    __syncthreads();
    bf16x8 pa = ld8(&Pb[lr][c * 32 + lg * 8]);
#pragma unroll
    for (int C = 0; C < 8; ++C) {
      union { u32 u[4]; bf16x8 v; } bb;
#pragma unroll
      for (int e = 0; e < 4; ++e) {
        int r0 = lg * 8 + 2 * e;
        int sw = ((r0 >> 3) & 3) << 4;
        int base = r0 * 512 + colb + C * 16;
        bb.u[e] = (u32)Vs[base ^ sw] | ((u32)Vs[(base + 512) ^ sw] << 16);
      }
      oacc[C] = mfma16(pa, bb.v, oacc[C]);
    }
    __syncthreads();
  }
#pragma unroll
  for (int C = 0; C < 8; ++C)
#pragma unroll
    for (int j = 0; j < 4; ++j) {
      int h = lg * 4 + j;
      Olat[(size_t)t * (H_ * 512) + h * 512 + wid * 128 + C * 16 + lr] = f2bf(oacc[C][j]);
    }
}

// ---------------------------------------------------------------- launch
extern "C" void kernel_launch(void* const* d_in, const int* in_sizes, int n_in,
                              void* d_out, int out_size, void* d_ws, size_t ws_size,
                              hipStream_t stream) {
  const float* hidden    = (const float*)d_in[1];
  const float* w_qkv_a   = (const float*)d_in[2];
  const float* q_a_ln_w  = (const float*)d_in[3];
  const float* w_qb      = (const float*)d_in[4];
  const float* kv_a_ln_w = (const float*)d_in[5];
  const float* w_kvb     = (const float*)d_in[6];
  const float* w_o       = (const float*)d_in[7];
  const float* w_idx_qb  = (const float*)d_in[8];
  const float* w_idx_k   = (const float*)d_in[9];
  const float* idx_g     = (const float*)d_in[10];
  const float* idx_b     = (const float*)d_in[11];
  const float* w_wproj   = (const float*)d_in[12];
  const float* b_wproj   = (const float*)d_in[13];

  char* W = (char*)d_ws;
  size_t o = 0;
  auto alloc = [&](size_t bytes) { void* p = W + o; o += (bytes + 255) & ~(size_t)255; return p; };
  float* q_cn  = (float*)alloc((size_t)T_ * QLR_ * 4);
  u16* kv_cn   = (u16*)alloc((size_t)T_ * KVLR_ * 2);
  u16* kper    = (u16*)alloc((size_t)T_ * ROPE_ * 2);
  int* selidx  = (int*)alloc((size_t)T_ * TOPK_ * 4);
  int* selcnt  = (int*)alloc((size_t)T_ * 4);
  u16* kih     = (u16*)alloc((size_t)T_ * IDXD_ * 2);
  u16* kil     = (u16*)alloc((size_t)T_ * IDXD_ * 2);
  u16* hidh    = (u16*)alloc((size_t)T_ * HID_ * 2);
  u16* hidl    = (u16*)alloc((size_t)T_ * HID_ * 2);
  // region S: q_cn splits + wiq splits; reused later as qi splits
  u16* qch     = (u16*)alloc((size_t)T_ * QLR_ * 2);
  u16* qcl     = (u16*)alloc((size_t)T_ * QLR_ * 2);
  u16* wiqh    = (u16*)alloc((size_t)(IDXH_ * IDXD_) * QLR_ * 2);
  u16* wiql    = (u16*)alloc((size_t)(IDXH_ * IDXD_) * QLR_ * 2);
  u16* qih     = qch;                                   // alias (after qi gemm)
  u16* qil     = qch + (size_t)T_ * IDXH_ * IDXD_;
  float* qi    = (float*)alloc((size_t)T_ * IDXH_ * IDXD_ * 4);   // reused: qeff
  u16* qeff    = (u16*)qi;
  float* score = (float*)alloc((size_t)T_ * T_ * 4);    // reused: qfb then attno
  u16* qfb     = (u16*)score;
  u16* attno   = (u16*)score;
  // region R: wcat splits + qkvx f32; reused as Olat
  u16* wcath   = (u16*)alloc((size_t)QKVX_ * HID_ * 2);
  u16* wcatl   = (u16*)alloc((size_t)QKVX_ * HID_ * 2);
  float* qkvx  = (float*)alloc((size_t)T_ * QKVX_ * 4);
  u16* Olat    = wcath;                                 // alias (after score)
  u16* wqbt    = (u16*)alloc((size_t)(H_ * QKD_) * QLR_ * 2);
  u16* wkvb    = (u16*)alloc((size_t)KVLR_ * (H_ * 256) * 2);
  u16* wkvbt   = (u16*)alloc((size_t)(H_ * 256) * KVLR_ * 2);
  u16* wot     = (u16*)alloc((size_t)(H_ * VD_) * HID_ * 2);

  dim3 blk(256);
  auto g2 = [](int M, int N, int Z) { return dim3((N + 127) / 128, M / 128, Z); };

  // weight / activation prep (batched)
  {
    TSJob j0{w_qkv_a, wcath, wcatl, HID_, QKVN_};
    TSJob j1{w_idx_qb, wiqh, wiql, QLR_, IDXH_ * IDXD_};
    TSJob j2{w_idx_k, wcath + (size_t)QKVN_ * HID_, wcatl + (size_t)QKVN_ * HID_, HID_, IDXD_};
    TSJob j3{w_wproj, wcath + (size_t)(QKVN_ + IDXD_) * HID_, wcatl + (size_t)(QKVN_ + IDXD_) * HID_, HID_, IDXH_};
    transpose_split_multi<<<dim3(64, 32, 4), blk, 0, stream>>>(j0, j1, j2, j3);
  }
  {
    TBJob j0{w_qb, wqbt, QLR_, H_ * QKD_};
    TBJob j1{w_kvb, wkvbt, KVLR_, H_ * 256};
    TBJob j2{w_o, wot, H_ * VD_, HID_};
    transpose_bf16_multi<<<dim3(64, 32, 3), blk, 0, stream>>>(j0, j1, j2);
  }
  split_f16_k<<<2048, blk, 0, stream>>>(hidden, hidh, hidl, (long)T_ * HID_);
  conv_bf16_k<<<2048, blk, 0, stream>>>(w_kvb, wkvb, (long)KVLR_ * H_ * 256);

  // strict path: one fused GEMM -> [qkv | ki | wgt(+bias,scaled)]
  gemm_hl<<<g2(T_, QKVX_, 1), blk, 0, stream>>>(
      hidh, hidl, HID_, wcath, wcatl, HID_, qkvx, QKVX_,
      b_wproj, QKVN_ + IDXD_, 0.015625f, QKVX_, HID_);
  rmsnorm_kernel<<<T_, blk, 0, stream>>>(qkvx, q_a_ln_w, kv_a_ln_w, q_cn, qch, qcl, kv_cn);
  rope_kpe_kernel<<<T_, 64, 0, stream>>>(qkvx, kper);
  ki_ln_rope_kernel<<<T_, 128, 0, stream>>>(qkvx, idx_g, idx_b, kih, kil);

  gemm_hl<<<g2(T_, IDXH_ * IDXD_, 1), blk, 0, stream>>>(
      qch, qcl, QLR_, wiqh, wiql, QLR_, qi, IDXH_ * IDXD_,
      nullptr, 1 << 30, 1.f, IDXH_ * IDXD_, QLR_);
  rope_qi_split_kernel<<<T_, blk, 0, stream>>>(qi, qih, qil);

  score_mfma<<<dim3(32, 32), blk, 0, stream>>>(qih, qil, kih, kil,
                                               qkvx + QKVN_ + IDXD_, QKVX_, score);
  topk_kernel<<<T_, blk, 0, stream>>>(score, selidx, selcnt);

  // tolerant path (bf16 MFMA)
  gemm_t<1, 1><<<g2(T_, H_ * QKD_, 1), blk, 0, stream>>>(q_cn, QLR_, 0, wqbt, QLR_, 0, qfb, H_ * QKD_, 0, H_ * QKD_, QLR_);
  rope_q_bf_kernel<<<T_, blk, 0, stream>>>(qfb);
  gemm_t<0, 1><<<g2(T_, 512, H_), blk, 0, stream>>>(qfb, H_ * QKD_, QKD_, wkvb, H_ * 256, 256, qeff, H_ * 512, 512, 512, NOPE_);
  attn_mla_kernel<<<T_, blk, 0, stream>>>(qeff, qfb, kv_cn, kper, selidx, selcnt, Olat);
  gemm_t<0, 1><<<g2(T_, VD_, H_), blk, 0, stream>>>(Olat, H_ * 512, 512, wkvbt + 128 * 512, KVLR_, 256 * 512, attno, H_ * VD_, VD_, VD_, 512);
  gemm_t<0, 0><<<g2(T_, HID_, 1), blk, 0, stream>>>(attno, H_ * VD_, 0, wot, H_ * VD_, 0, d_out, HID_, 0, HID_, H_ * VD_);
}

// Round 11
// 711.974 us; speedup vs baseline: 7.0448x; 1.1654x over previous
//
#include <hip/hip_runtime.h>
#include <cfloat>
#include <cmath>

#define T_    2048
#define HID_  2048
#define QKVN_ 2112
#define QKVX_ 2272   // fused: 2112 qkv | 128 ki | 32 wgt
#define QLR_  1536
#define KVLR_ 512
#define ROPE_ 64
#define NOPE_ 128
#define QKD_  192
#define VD_   128
#define H_    16
#define IDXH_ 32
#define IDXD_ 128
#define TOPK_ 512
#define EPS_  1e-6f
#define SCALING_ 0.07216878364870323f   // 192^-0.5

typedef unsigned int u32;
typedef unsigned short u16;
typedef __bf16 bf16x8 __attribute__((ext_vector_type(8)));
typedef _Float16 f16;
typedef f16 f16x8 __attribute__((ext_vector_type(8)));
typedef float f32x4 __attribute__((ext_vector_type(4)));

__device__ __forceinline__ u16 f2bf(float x) {
  u32 u = __float_as_uint(x);
  u32 r = (u + 0x7fffu + ((u >> 16) & 1u)) >> 16;
  return (u16)r;
}
__device__ __forceinline__ float bf2f(u16 h) { return __uint_as_float(((u32)h) << 16); }
__device__ __forceinline__ u32 pack2(float a, float b) { return (u32)f2bf(a) | ((u32)f2bf(b) << 16); }
__device__ __forceinline__ bf16x8 ld8(const void* p) { return *(const bf16x8*)p; }
__device__ __forceinline__ f32x4 mfma16(bf16x8 a, bf16x8 b, f32x4 c) {
  return __builtin_amdgcn_mfma_f32_16x16x32_bf16(a, b, c, 0, 0, 0);
}
__device__ __forceinline__ u16 hbits(f16 h) { union { f16 h; u16 u; } c; c.h = h; return c.u; }
__device__ __forceinline__ u32 hpack(f16 a, f16 b) { return (u32)hbits(a) | ((u32)hbits(b) << 16); }
__device__ __forceinline__ f16x8 ldh8(const void* p) { return *(const f16x8*)p; }
__device__ __forceinline__ f32x4 mfmah(f16x8 a, f16x8 b, f32x4 c) {
  return __builtin_amdgcn_mfma_f32_16x16x32_f16(a, b, c, 0, 0, 0);
}
__device__ __forceinline__ void gload16(const u16* g, u16* l) {
  __builtin_amdgcn_global_load_lds(
      (__attribute__((address_space(1))) void*)(g),
      (__attribute__((address_space(3))) void*)(l), 16, 0, 0);
}

// ---------------------------------------------------------------- prep (multi-job)
struct TSJob { const float* src; u16* oh; u16* ol; int K; int N; };
__global__ __launch_bounds__(256) void transpose_split_multi(
    TSJob j0, TSJob j1, TSJob j2, TSJob j3) {
  TSJob jb = (blockIdx.z == 0) ? j0 : (blockIdx.z == 1) ? j1 : (blockIdx.z == 2) ? j2 : j3;
  int k0 = blockIdx.y * 64, n0 = blockIdx.x * 64;
  if (k0 >= jb.K || n0 >= jb.N) return;
  __shared__ float t[64][65];
  for (int j = 0; j < 16; ++j) {
    int u = threadIdx.x + 256 * j; int r = u >> 6, c = u & 63;
    t[r][c] = (k0 + r < jb.K && n0 + c < jb.N) ? jb.src[(size_t)(k0 + r) * jb.N + n0 + c] : 0.f;
  }
  __syncthreads();
  for (int j = 0; j < 16; ++j) {
    int u = threadIdx.x + 256 * j; int r = u >> 6, c = u & 63;
    if (n0 + r < jb.N && k0 + c < jb.K) {
      float v = t[c][r];
      f16 h = (f16)v;
      jb.oh[(size_t)(n0 + r) * jb.K + k0 + c] = hbits(h);
      jb.ol[(size_t)(n0 + r) * jb.K + k0 + c] = hbits((f16)(v - (float)h));
    }
  }
}

struct TBJob { const float* src; u16* out; int K; int N; };
__global__ __launch_bounds__(256) void transpose_bf16_multi(TBJob j0, TBJob j1, TBJob j2) {
  TBJob jb = (blockIdx.z == 0) ? j0 : (blockIdx.z == 1) ? j1 : j2;
  int k0 = blockIdx.y * 64, n0 = blockIdx.x * 64;
  if (k0 >= jb.K || n0 >= jb.N) return;
  __shared__ float t[64][65];
  for (int j = 0; j < 16; ++j) {
    int u = threadIdx.x + 256 * j; int r = u >> 6, c = u & 63;
    t[r][c] = (k0 + r < jb.K && n0 + c < jb.N) ? jb.src[(size_t)(k0 + r) * jb.N + n0 + c] : 0.f;
  }
  __syncthreads();
  for (int j = 0; j < 16; ++j) {
    int u = threadIdx.x + 256 * j; int r = u >> 6, c = u & 63;
    if (n0 + r < jb.N && k0 + c < jb.K) jb.out[(size_t)(n0 + r) * jb.K + k0 + c] = f2bf(t[c][r]);
  }
}

__global__ __launch_bounds__(256) void split_f16_k(
    const float* __restrict__ in, u16* __restrict__ hi, u16* __restrict__ lo, long n) {
  for (long i = ((long)blockIdx.x * 256 + threadIdx.x) * 4; i < n; i += (long)gridDim.x * 1024) {
    float4 v = *(const float4*)(in + i);
    f16 a = (f16)v.x, b = (f16)v.y, c = (f16)v.z, d = (f16)v.w;
    *(u32*)(hi + i) = hpack(a, b);
    *(u32*)(hi + i + 2) = hpack(c, d);
    *(u32*)(lo + i) = hpack((f16)(v.x - (float)a), (f16)(v.y - (float)b));
    *(u32*)(lo + i + 2) = hpack((f16)(v.z - (float)c), (f16)(v.w - (float)d));
  }
}

__global__ __launch_bounds__(256) void conv_bf16_k(
    const float* __restrict__ in, u16* __restrict__ out, long n) {
  for (long i = ((long)blockIdx.x * 256 + threadIdx.x) * 4; i < n; i += (long)gridDim.x * 1024) {
    float4 v = *(const float4*)(in + i);
    *(u32*)(out + i) = pack2(v.x, v.y);
    *(u32*)(out + i + 2) = pack2(v.z, v.w);
  }
}

// ---------------------------------------------------------------- strict GEMM (DMA-staged hi/lo)
__global__ __launch_bounds__(256) void gemm_hl(
    const u16* __restrict__ Ah_, const u16* __restrict__ Al_, int lda,
    const u16* __restrict__ Bh_, const u16* __restrict__ Bl_, int ldb,
    float* __restrict__ C, int ldc, const float* __restrict__ bias, int bcol0,
    float bscale, int N, int K) {
  __shared__ u32 Ah[128][16], Al[128][16], Bh[128][16], Bl[128][16];
  const int tid = threadIdx.x;
  const int bm = blockIdx.y * 128, bn = blockIdx.x * 128;
  const int wid = tid >> 6, lane = tid & 63, wr = wid >> 1, wc = wid & 1;
  const int lr = lane & 15, lg = lane >> 4;
  // wave wid stages one buffer: 0->Ah 1->Al 2->Bh 3->Bl
  const u16* srcb = (wid == 0) ? Ah_ : (wid == 1) ? Al_ : (wid == 2) ? Bh_ : Bl_;
  const int sld = (wid < 2) ? lda : ldb;
  const int rb = (wid < 2) ? bm : bn;
  u16* dst = (u16*)((wid == 0) ? &Ah[0][0] : (wid == 1) ? &Al[0][0]
                                           : (wid == 2) ? &Bh[0][0] : &Bl[0][0]);
  const int rowl = lane >> 2;          // + c*16
  const int offl = (lane & 3) * 8;
  f32x4 acc[4][4] = {};
  for (int k0 = 0; k0 < K; k0 += 32) {
#pragma unroll
    for (int c = 0; c < 8; ++c) {
      int gr = rb + c * 16 + rowl;
      if (wid >= 2) gr = min(gr, N - 1);
      gload16(srcb + (size_t)gr * sld + k0 + offl, dst + c * 512);
    }
    __syncthreads();
    f16x8 ah[4], al[4], bh[4], bl[4];
#pragma unroll
    for (int i = 0; i < 4; ++i) {
      ah[i] = ldh8(&Ah[wr * 64 + i * 16 + lr][lg * 4]);
      al[i] = ldh8(&Al[wr * 64 + i * 16 + lr][lg * 4]);
      bh[i] = ldh8(&Bh[wc * 64 + i * 16 + lr][lg * 4]);
      bl[i] = ldh8(&Bl[wc * 64 + i * 16 + lr][lg * 4]);
    }
#pragma unroll
    for (int i = 0; i < 4; ++i)
#pragma unroll
      for (int jn = 0; jn < 4; ++jn) {
        acc[i][jn] = mfmah(ah[i], bh[jn], acc[i][jn]);
        acc[i][jn] = mfmah(ah[i], bl[jn], acc[i][jn]);
        acc[i][jn] = mfmah(al[i], bh[jn], acc[i][jn]);
      }
    __syncthreads();
  }
#pragma unroll
  for (int i = 0; i < 4; ++i)
#pragma unroll
    for (int jn = 0; jn < 4; ++jn)
#pragma unroll
      for (int j = 0; j < 4; ++j) {
        int row = bm + wr * 64 + i * 16 + lg * 4 + j;
        int col = bn + wc * 64 + jn * 16 + lr;
        if (col < N) {
          float v = acc[i][jn][j];
          if (col >= bcol0) v = (v + bias[col - bcol0]) * bscale;
          C[(size_t)row * ldc + col] = v;
        }
      }
}

// ---------------------------------------------------------------- tolerant bf16 GEMM (DMA-staged)
template <int CBF16>
__global__ __launch_bounds__(256) void gemm_t(
    const u16* __restrict__ Ab, int lda, long aoz,
    const u16* __restrict__ Bt, int ldb, long boz,
    void* __restrict__ Cp, int ldc, long coz, int N, int K) {
  __shared__ u32 As[128][16], Bs[128][16];
  const int tid = threadIdx.x;
  const int z = blockIdx.z;
  const int bm = blockIdx.y * 128, bn = blockIdx.x * 128;
  const int wid = tid >> 6, lane = tid & 63, wr = wid >> 1, wc = wid & 1;
  const int lr = lane & 15, lg = lane >> 4;
  const u16* A = Ab + aoz * z;
  const u16* B = Bt + boz * z;
  // waves 0,1 stage As; waves 2,3 stage Bs
  const u16* srcb = (wid < 2) ? A : B;
  const int sld = (wid < 2) ? lda : ldb;
  const int rb = (wid < 2) ? bm : bn;
  u16* dst = (u16*)((wid < 2) ? &As[0][0] : &Bs[0][0]);
  const int ccb = (wid & 1) * 4;
  const int rowl = lane >> 2;
  const int offl = (lane & 3) * 8;
  f32x4 acc[4][4] = {};
  for (int k0 = 0; k0 < K; k0 += 32) {
#pragma unroll
    for (int c = 0; c < 4; ++c) {
      int cc = ccb + c;
      int gr = rb + cc * 16 + rowl;
      if (wid >= 2) gr = min(gr, N - 1);
      gload16(srcb + (size_t)gr * sld + k0 + offl, dst + cc * 512);
    }
    __syncthreads();
    bf16x8 af[4], bf[4];
#pragma unroll
    for (int i = 0; i < 4; ++i) {
      af[i] = ld8(&As[wr * 64 + i * 16 + lr][lg * 4]);
      bf[i] = ld8(&Bs[wc * 64 + i * 16 + lr][lg * 4]);
    }
#pragma unroll
    for (int i = 0; i < 4; ++i)
#pragma unroll
      for (int jn = 0; jn < 4; ++jn)
        acc[i][jn] = mfma16(af[i], bf[jn], acc[i][jn]);
    __syncthreads();
  }
#pragma unroll
  for (int i = 0; i < 4; ++i)
#pragma unroll
    for (int jn = 0; jn < 4; ++jn)
#pragma unroll
      for (int j = 0; j < 4; ++j) {
        int row = bm + wr * 64 + i * 16 + lg * 4 + j;
        int col = bn + wc * 64 + jn * 16 + lr;
        if (col < N) {
          if (CBF16) ((u16*)Cp)[coz * z + (size_t)row * ldc + col] = f2bf(acc[i][jn][j]);
          else ((float*)Cp)[coz * z + (size_t)row * ldc + col] = acc[i][jn][j];
        }
      }
}

// ---------------------------------------------------------------- RMS norms (q_cn -> f16 hi/lo + bf16)
__global__ __launch_bounds__(256) void rmsnorm_kernel(
    const float* __restrict__ qkvx, const float* __restrict__ qw,
    const float* __restrict__ kvw, u16* __restrict__ qcb,
    u16* __restrict__ qch, u16* __restrict__ qcl, u16* __restrict__ kv_cn) {
  const int t = blockIdx.x, tid = threadIdx.x;
  const float* row = qkvx + (size_t)t * QKVX_;
  __shared__ float red[256];
  float ss = 0.f;
  for (int i = tid; i < QLR_; i += 256) { float v = row[i]; ss += v * v; }
  red[tid] = ss; __syncthreads();
  for (int s = 128; s; s >>= 1) { if (tid < s) red[tid] += red[tid + s]; __syncthreads(); }
  float scl = 1.0f / sqrtf(red[0] / (float)QLR_ + EPS_);
  for (int i = tid; i < QLR_; i += 256) {
    float val = row[i] * scl * qw[i];
    qcb[(size_t)t * QLR_ + i] = f2bf(val);
    f16 h = (f16)val;
    qch[(size_t)t * QLR_ + i] = hbits(h);
    qcl[(size_t)t * QLR_ + i] = hbits((f16)(val - (float)h));
  }
  __syncthreads();
  ss = 0.f;
  for (int i = tid; i < KVLR_; i += 256) { float v = row[QLR_ + i]; ss += v * v; }
  red[tid] = ss; __syncthreads();
  for (int s = 128; s; s >>= 1) { if (tid < s) red[tid] += red[tid + s]; __syncthreads(); }
  scl = 1.0f / sqrtf(red[0] / (float)KVLR_ + EPS_);
  for (int i = tid; i < KVLR_; i += 256)
    kv_cn[(size_t)t * KVLR_ + i] = f2bf(row[QLR_ + i] * scl * kvw[i]);
}

// ---------------------------------------------------------------- RoPE helpers
__device__ __forceinline__ void rope_pair(float pos, int j, float& x0, float& x1) {
  float inv = powf(10000.f, -(float)j * (1.f / 32.f));
  float f = pos * inv;
  float c = cosf(f), s = sinf(f);
  float a = x0, b = x1;
  x0 = a * c - b * s;
  x1 = a * s + b * c;
}

__global__ __launch_bounds__(256) void rope_qi_split_kernel(
    const float* __restrict__ qi, u16* __restrict__ qih, u16* __restrict__ qil) {
  const int t = blockIdx.x, tid = threadIdx.x;
  float pos = (float)t;
  const float* src = qi + (size_t)t * (IDXH_ * IDXD_);
  u16* dh = qih + (size_t)t * (IDXH_ * IDXD_);
  u16* dl = qil + (size_t)t * (IDXH_ * IDXD_);
  for (int p = tid; p < IDXH_ * IDXD_ / 2; p += 256) {
    int d = p & 63;
    float x0 = src[2 * p], x1 = src[2 * p + 1];
    if (d < 32) rope_pair(pos, d, x0, x1);
    f16 h0 = (f16)x0, h1 = (f16)x1;
    *(u32*)(dh + 2 * p) = hpack(h0, h1);
    *(u32*)(dl + 2 * p) = hpack((f16)(x0 - (float)h0), (f16)(x1 - (float)h1));
  }
}

__global__ __launch_bounds__(256) void rope_q_bf_kernel(u16* __restrict__ qfb) {
  const int t = blockIdx.x, tid = threadIdx.x;
  float pos = (float)t;
  for (int idx = tid; idx < H_ * 32; idx += 256) {
    int hh = idx / 32, j = idx % 32;
    u16* p = qfb + (size_t)t * (H_ * QKD_) + hh * QKD_ + NOPE_ + 2 * j;
    float x0 = bf2f(p[0]), x1 = bf2f(p[1]);
    rope_pair(pos, j, x0, x1);
    p[0] = f2bf(x0); p[1] = f2bf(x1);
  }
}

__global__ __launch_bounds__(64) void rope_kpe_kernel(
    const float* __restrict__ qkvx, u16* __restrict__ kper) {
  const int t = blockIdx.x, tid = threadIdx.x;
  if (tid >= 32) return;
  float pos = (float)t;
  const float* p = qkvx + (size_t)t * QKVX_ + (QLR_ + KVLR_);
  float x0 = p[2 * tid], x1 = p[2 * tid + 1];
  rope_pair(pos, tid, x0, x1);
  kper[(size_t)t * ROPE_ + 2 * tid] = f2bf(x0);
  kper[(size_t)t * ROPE_ + 2 * tid + 1] = f2bf(x1);
}

// ---------------------------------------------------------------- ki: LN + rope -> f16 hi/lo
__global__ __launch_bounds__(128) void ki_ln_rope_kernel(
    const float* __restrict__ qkvx, const float* __restrict__ gamma,
    const float* __restrict__ beta, u16* __restrict__ kih, u16* __restrict__ kil) {
  const int t = blockIdx.x, tid = threadIdx.x;
  __shared__ float x[128];
  __shared__ float red[128];
  float v = qkvx[(size_t)t * QKVX_ + QKVN_ + tid];
  red[tid] = v; __syncthreads();
  for (int s = 64; s; s >>= 1) { if (tid < s) red[tid] += red[tid + s]; __syncthreads(); }
  float mu = red[0] / 128.f;
  __syncthreads();
  float d = v - mu;
  red[tid] = d * d; __syncthreads();
  for (int s = 64; s; s >>= 1) { if (tid < s) red[tid] += red[tid + s]; __syncthreads(); }
  float var = red[0] / 128.f;
  float y = d * (1.0f / sqrtf(var + EPS_)) * gamma[tid] + beta[tid];
  x[tid] = y; __syncthreads();
  float pos = (float)t;
  if (tid < 32) {
    float x0 = x[2 * tid], x1 = x[2 * tid + 1];
    rope_pair(pos, tid, x0, x1);
    x[2 * tid] = x0; x[2 * tid + 1] = x1;
  }
  __syncthreads();
  float fv = x[tid];
  f16 h = (f16)fv;
  kih[(size_t)t * IDXD_ + tid] = hbits(h);
  kil[(size_t)t * IDXD_ + tid] = hbits((f16)(fv - (float)h));
}

// ---------------------------------------------------------------- indexer score (pre-split f16 MFMA)
__global__ __launch_bounds__(256) void score_mfma(
    const u16* __restrict__ qih, const u16* __restrict__ qil,
    const u16* __restrict__ kih, const u16* __restrict__ kil,
    const float* __restrict__ wgt, int ldw, float* __restrict__ score) {
  const int s0 = blockIdx.x * 64, t0 = blockIdx.y * 64;
  if (s0 > t0 + 63) return;
  __shared__ u32 Kh[64][68], Kl[64][68], Qh[64][68], Ql[64][68];
  __shared__ float wts[64][33];
  const int tid = threadIdx.x;
  const int wid = tid >> 6, lane = tid & 63, wr = wid >> 1, wc = wid & 1;
  const int lr = lane & 15, lg = lane >> 4;
#pragma unroll
  for (int j = 0; j < 4; ++j) {
    int u = tid + 256 * j; int row = u >> 4, p = u & 15;
    *(uint4*)&Kh[row][p * 4] = *(const uint4*)(kih + (size_t)(s0 + row) * IDXD_ + p * 8);
    *(uint4*)&Kl[row][p * 4] = *(const uint4*)(kil + (size_t)(s0 + row) * IDXD_ + p * 8);
  }
#pragma unroll
  for (int j = 0; j < 8; ++j) {
    int u = tid + 256 * j; int r = u >> 5, c = u & 31;
    wts[r][c] = wgt[(size_t)(t0 + r) * ldw + c];
  }
  __syncthreads();
  f16x8 bh[2][4], bl[2][4];
#pragma unroll
  for (int ni = 0; ni < 2; ++ni)
#pragma unroll
    for (int kb = 0; kb < 4; ++kb) {
      bh[ni][kb] = ldh8(&Kh[wc * 32 + ni * 16 + lr][kb * 16 + lg * 4]);
      bl[ni][kb] = ldh8(&Kl[wc * 32 + ni * 16 + lr][kb * 16 + lg * 4]);
    }
  f32x4 fin[2][2] = {};
  for (int h = 0; h < IDXH_; ++h) {
#pragma unroll
    for (int j = 0; j < 4; ++j) {
      int u = tid + 256 * j; int row = u >> 4, p = u & 15;
      size_t g = (size_t)(t0 + row) * (IDXH_ * IDXD_) + h * IDXD_ + p * 8;
      *(uint4*)&Qh[row][p * 4] = *(const uint4*)(qih + g);
      *(uint4*)&Ql[row][p * 4] = *(const uint4*)(qil + g);
    }
    __syncthreads();
    f32x4 acch[2][2] = {};
#pragma unroll
    for (int kb = 0; kb < 4; ++kb) {
      f16x8 ah0 = ldh8(&Qh[wr * 32 + lr][kb * 16 + lg * 4]);
      f16x8 ah1 = ldh8(&Qh[wr * 32 + 16 + lr][kb * 16 + lg * 4]);
      f16x8 al0 = ldh8(&Ql[wr * 32 + lr][kb * 16 + lg * 4]);
      f16x8 al1 = ldh8(&Ql[wr * 32 + 16 + lr][kb * 16 + lg * 4]);
#pragma unroll
      for (int ni = 0; ni < 2; ++ni) {
        acch[0][ni] = mfmah(ah0, bh[ni][kb], acch[0][ni]);
        acch[0][ni] = mfmah(ah0, bl[ni][kb], acch[0][ni]);
        acch[0][ni] = mfmah(al0, bh[ni][kb], acch[0][ni]);
        acch[1][ni] = mfmah(ah1, bh[ni][kb], acch[1][ni]);
        acch[1][ni] = mfmah(ah1, bl[ni][kb], acch[1][ni]);
        acch[1][ni] = mfmah(al1, bh[ni][kb], acch[1][ni]);
      }
    }
#pragma unroll
    for (int mi = 0; mi < 2; ++mi)
#pragma unroll
      for (int j = 0; j < 4; ++j) {
        float w = wts[wr * 32 + mi * 16 + lg * 4 + j][h];
        fin[mi][0][j] += w * fmaxf(acch[mi][0][j], 0.f);
        fin[mi][1][j] += w * fmaxf(acch[mi][1][j], 0.f);
      }
    __syncthreads();
  }
#pragma unroll
  for (int mi = 0; mi < 2; ++mi)
#pragma unroll
    for (int ni = 0; ni < 2; ++ni)
#pragma unroll
      for (int j = 0; j < 4; ++j) {
        int row = t0 + wr * 32 + mi * 16 + lg * 4 + j;
        int col = s0 + wc * 32 + ni * 16 + lr;
        score[(size_t)row * T_ + col] = fin[mi][ni][j];
      }
}

// ---------------------------------------------------------------- top-k (exact)
__global__ __launch_bounds__(256) void topk_kernel(
    const float* __restrict__ score, int* __restrict__ selidx,
    int* __restrict__ selcnt) {
  const int t = blockIdx.x;
  const int L = t + 1;
  const int tid = threadIdx.x;
  if (L <= TOPK_) {
    for (int j = tid; j < TOPK_; j += 256)
      selidx[(size_t)t * TOPK_ + j] = (j < L) ? j : 0;
    if (tid == 0) selcnt[t] = L;
    return;
  }
  __shared__ unsigned u[T_];
  __shared__ unsigned hist[16];
  __shared__ unsigned sprefix;
  __shared__ int sk;
  __shared__ int part[256];
  for (int i = tid; i < T_; i += 256) {
    float v = (i < L) ? score[(size_t)t * T_ + i] : -FLT_MAX;
    unsigned b = __float_as_uint(v);
    u[i] = (b & 0x80000000u) ? ~b : (b | 0x80000000u);
  }
  if (tid == 0) { sprefix = 0u; sk = TOPK_; }
  __syncthreads();
  for (int pass = 0; pass < 8; ++pass) {
    const int shift = 28 - 4 * pass;
    if (tid < 16) hist[tid] = 0u;
    __syncthreads();
    unsigned pfx = sprefix;
    for (int i = tid; i < L; i += 256) {
      unsigned val = u[i];
      bool match = (pass == 0) || ((val >> (shift + 4)) == pfx);
      if (match) atomicAdd(&hist[(val >> shift) & 15u], 1u);
    }
    __syncthreads();
    if (tid == 0) {
      int k = sk; unsigned cum = 0u; int bsel = 0;
      for (int bb = 15; bb >= 0; --bb) {
        if (cum + hist[bb] >= (unsigned)k) { bsel = bb; sk = k - (int)cum; break; }
        cum += hist[bb];
      }
      sprefix = (sprefix << 4) | (unsigned)bsel;
    }
    __syncthreads();
  }
  const unsigned thr = sprefix;
  const int kEq = sk;
  const int base = tid * 8;
  int eqloc[8]; int esum = 0;
  for (int r = 0; r < 8; ++r) {
    int i = base + r;
    int f = (i < L && u[i] == thr) ? 1 : 0;
    eqloc[r] = esum; esum += f;
  }
  part[tid] = esum; __syncthreads();
  for (int off = 1; off < 256; off <<= 1) {
    int v = (tid >= off) ? part[tid - off] : 0;
    __syncthreads();
    part[tid] += v;
    __syncthreads();
  }
  const int ebase = (tid > 0) ? part[tid - 1] : 0;
  __syncthreads();
  int sloc[8], selflag[8]; int ssum = 0;
  for (int r = 0; r < 8; ++r) {
    int i = base + r;
    int f = 0;
    if (i < L) {
      unsigned ui = u[i];
      if (ui > thr) f = 1;
      else if (ui == thr && (ebase + eqloc[r]) < kEq) f = 1;
    }
    selflag[r] = f; sloc[r] = ssum; ssum += f;
  }
  part[tid] = ssum; __syncthreads();
  for (int off = 1; off < 256; off <<= 1) {
    int v = (tid >= off) ? part[tid - off] : 0;
    __syncthreads();
    part[tid] += v;
    __syncthreads();
  }
  const int sbase = (tid > 0) ? part[tid - 1] : 0;
  for (int r = 0; r < 8; ++r)
    if (selflag[r]) selidx[(size_t)t * TOPK_ + sbase + sloc[r]] = base + r;
  if (tid == 0) selcnt[t] = TOPK_;
}

// ---------------------------------------------------------------- MLA attention (R9 proven version)
__global__ __launch_bounds__(256, 3) void attn_mla_kernel(
    const u16* __restrict__ qeff, const u16* __restrict__ qfb,
    const u16* __restrict__ kvcn, const u16* __restrict__ kper,
    const int* __restrict__ selidx, const int* __restrict__ selcnt,
    u16* __restrict__ Olat) {
  const int t = blockIdx.x;
  const int tid = threadIdx.x;
  const int wid = tid >> 6, lane = tid & 63;
  const int lr = lane & 15, lg = lane >> 4;
  __shared__ int sidxs[512];
  __shared__ u16 Pb[16][520];
  __shared__ u16 Vs[32 * 512];     // XOR-swizzled: idx ^= ((row>>3)&3)<<4
  __shared__ float redm[4][16];
  __shared__ float reds[4][16];
  const int cnt = selcnt[t];
  for (int j = tid; j < 512; j += 256) sidxs[j] = selidx[(size_t)t * TOPK_ + j];
  __syncthreads();

  // ---- QK^T: wave wid owns keys [wid*128, wid*128+128)
  int srow[8];
  const u16* kb8[8];
  const u16* kp8[8];
#pragma unroll
  for (int m = 0; m < 8; ++m) {
    srow[m] = sidxs[wid * 128 + m * 16 + lr];
    kb8[m] = kvcn + (size_t)srow[m] * 512 + lg * 8;
    kp8[m] = kper + (size_t)srow[m] * 64 + lg * 8;
  }
  const u16* qe = qeff + (size_t)t * (H_ * 512) + lr * 512 + lg * 8;
  const u16* qp = qfb + (size_t)t * (H_ * QKD_) + lr * QKD_ + NOPE_ + lg * 8;
  f32x4 lgv[8] = {};
  bf16x8 kc[8];
#pragma unroll
  for (int m = 0; m < 8; ++m) kc[m] = ld8(kb8[m]);
#pragma unroll
  for (int kb = 0; kb < 16; ++kb) {
    bf16x8 qfk = ld8(qe + kb * 32);
    bf16x8 kn[8];
#pragma unroll
    for (int m = 0; m < 8; ++m)
      kn[m] = (kb < 15) ? ld8(kb8[m] + (kb + 1) * 32) : ld8(kp8[m]);
#pragma unroll
    for (int m = 0; m < 8; ++m) lgv[m] = mfma16(kc[m], qfk, lgv[m]);
#pragma unroll
    for (int m = 0; m < 8; ++m) kc[m] = kn[m];
  }
  {
    bf16x8 qfk = ld8(qp);
    bf16x8 kn[8];
#pragma unroll
    for (int m = 0; m < 8; ++m) kn[m] = ld8(kp8[m] + 32);
#pragma unroll
    for (int m = 0; m < 8; ++m) lgv[m] = mfma16(kc[m], qfk, lgv[m]);
#pragma unroll
    for (int m = 0; m < 8; ++m) kc[m] = kn[m];
  }
  {
    bf16x8 qfk = ld8(qp + 32);
#pragma unroll
    for (int m = 0; m < 8; ++m) lgv[m] = mfma16(kc[m], qfk, lgv[m]);
  }

  // ---- softmax (head = lr)
  float mx = -FLT_MAX;
#pragma unroll
  for (int m = 0; m < 8; ++m)
#pragma unroll
    for (int j = 0; j < 4; ++j) {
      int slot = wid * 128 + m * 16 + lg * 4 + j;
      float v = (slot < cnt) ? lgv[m][j] * SCALING_ : -FLT_MAX;
      lgv[m][j] = v;
      mx = fmaxf(mx, v);
    }
  mx = fmaxf(mx, __shfl_xor(mx, 16));
  mx = fmaxf(mx, __shfl_xor(mx, 32));
  if (lane < 16) redm[wid][lane] = mx;
  __syncthreads();
  float hm = fmaxf(fmaxf(redm[0][lr], redm[1][lr]), fmaxf(redm[2][lr], redm[3][lr]));
  float sm = 0.f;
#pragma unroll
  for (int m = 0; m < 8; ++m)
#pragma unroll
    for (int j = 0; j < 4; ++j) {
      int slot = wid * 128 + m * 16 + lg * 4 + j;
      float e = (slot < cnt) ? expf(lgv[m][j] - hm) : 0.f;
      lgv[m][j] = e; sm += e;
    }
  sm += __shfl_xor(sm, 16);
  sm += __shfl_xor(sm, 32);
  if (lane < 16) reds[wid][lane] = sm;
  __syncthreads();
  float inv = 1.f / (reds[0][lr] + reds[1][lr] + reds[2][lr] + reds[3][lr]);
#pragma unroll
  for (int m = 0; m < 8; ++m) {
    int sl = wid * 128 + m * 16 + lg * 4;
    *(u32*)&Pb[lr][sl] = pack2(lgv[m][0] * inv, lgv[m][1] * inv);
    *(u32*)&Pb[lr][sl + 2] = pack2(lgv[m][2] * inv, lgv[m][3] * inv);
  }

  // ---- PV via DMA-staged V chunks (pre-swizzled source)
  f32x4 oacc[8] = {};
  const int colb = wid * 128 + lr;
  for (int c = 0; c < 16; ++c) {
#pragma unroll
    for (int i = 0; i < 8; ++i) {
      int row = i * 4 + wid;
      int s = sidxs[c * 32 + row];
      int piece = lane ^ ((((row >> 3) & 3)) << 1);
      gload16(kvcn + (size_t)s * 512 + piece * 8, &Vs[row * 512]);
    }
    __syncthreads();
    bf16x8 pa = ld8(&Pb[lr][c * 32 + lg * 8]);
#pragma unroll
    for (int C = 0; C < 8; ++C) {
      union { u32 u[4]; bf16x8 v; } bb;
#pragma unroll
      for (int e = 0; e < 4; ++e) {
        int r0 = lg * 8 + 2 * e;
        int sw = ((r0 >> 3) & 3) << 4;
        int base = r0 * 512 + colb + C * 16;
        bb.u[e] = (u32)Vs[base ^ sw] | ((u32)Vs[(base + 512) ^ sw] << 16);
      }
      oacc[C] = mfma16(pa, bb.v, oacc[C]);
    }
    __syncthreads();
  }
#pragma unroll
  for (int C = 0; C < 8; ++C)
#pragma unroll
    for (int j = 0; j < 4; ++j) {
      int h = lg * 4 + j;
      Olat[(size_t)t * (H_ * 512) + h * 512 + wid * 128 + C * 16 + lr] = f2bf(oacc[C][j]);
    }
}

// ---------------------------------------------------------------- launch
extern "C" void kernel_launch(void* const* d_in, const int* in_sizes, int n_in,
                              void* d_out, int out_size, void* d_ws, size_t ws_size,
                              hipStream_t stream) {
  const float* hidden    = (const float*)d_in[1];
  const float* w_qkv_a   = (const float*)d_in[2];
  const float* q_a_ln_w  = (const float*)d_in[3];
  const float* w_qb      = (const float*)d_in[4];
  const float* kv_a_ln_w = (const float*)d_in[5];
  const float* w_kvb     = (const float*)d_in[6];
  const float* w_o       = (const float*)d_in[7];
  const float* w_idx_qb  = (const float*)d_in[8];
  const float* w_idx_k   = (const float*)d_in[9];
  const float* idx_g     = (const float*)d_in[10];
  const float* idx_b     = (const float*)d_in[11];
  const float* w_wproj   = (const float*)d_in[12];
  const float* b_wproj   = (const float*)d_in[13];

  char* W = (char*)d_ws;
  size_t o = 0;
  auto alloc = [&](size_t bytes) { void* p = W + o; o += (bytes + 255) & ~(size_t)255; return p; };
  u16* qcb     = (u16*)alloc((size_t)T_ * QLR_ * 2);
  u16* kv_cn   = (u16*)alloc((size_t)T_ * KVLR_ * 2);
  u16* kper    = (u16*)alloc((size_t)T_ * ROPE_ * 2);
  int* selidx  = (int*)alloc((size_t)T_ * TOPK_ * 4);
  int* selcnt  = (int*)alloc((size_t)T_ * 4);
  u16* kih     = (u16*)alloc((size_t)T_ * IDXD_ * 2);
  u16* kil     = (u16*)alloc((size_t)T_ * IDXD_ * 2);
  u16* hidh    = (u16*)alloc((size_t)T_ * HID_ * 2);
  u16* hidl    = (u16*)alloc((size_t)T_ * HID_ * 2);
  // region S: q_cn splits + wiq splits; reused later as qi splits
  u16* qch     = (u16*)alloc((size_t)T_ * QLR_ * 2);
  u16* qcl     = (u16*)alloc((size_t)T_ * QLR_ * 2);
  u16* wiqh    = (u16*)alloc((size_t)(IDXH_ * IDXD_) * QLR_ * 2);
  u16* wiql    = (u16*)alloc((size_t)(IDXH_ * IDXD_) * QLR_ * 2);
  u16* qih     = qch;                                   // alias (after qi gemm)
  u16* qil     = qch + (size_t)T_ * IDXH_ * IDXD_;
  float* qi    = (float*)alloc((size_t)T_ * IDXH_ * IDXD_ * 4);   // reused: qeff
  u16* qeff    = (u16*)qi;
  float* score = (float*)alloc((size_t)T_ * T_ * 4);    // reused: qfb then attno
  u16* qfb     = (u16*)score;
  u16* attno   = (u16*)score;
  // region R: wcat splits + qkvx f32; reused as Olat
  u16* wcath   = (u16*)alloc((size_t)QKVX_ * HID_ * 2);
  u16* wcatl   = (u16*)alloc((size_t)QKVX_ * HID_ * 2);
  float* qkvx  = (float*)alloc((size_t)T_ * QKVX_ * 4);
  u16* Olat    = wcath;                                 // alias (after score)
  u16* wqbt    = (u16*)alloc((size_t)(H_ * QKD_) * QLR_ * 2);
  u16* wkvb    = (u16*)alloc((size_t)KVLR_ * (H_ * 256) * 2);
  u16* wkvbt   = (u16*)alloc((size_t)(H_ * 256) * KVLR_ * 2);
  u16* wot     = (u16*)alloc((size_t)(H_ * VD_) * HID_ * 2);

  dim3 blk(256);
  auto g2 = [](int M, int N, int Z) { return dim3((N + 127) / 128, M / 128, Z); };

  // weight / activation prep (batched)
  {
    TSJob j0{w_qkv_a, wcath, wcatl, HID_, QKVN_};
    TSJob j1{w_idx_qb, wiqh, wiql, QLR_, IDXH_ * IDXD_};
    TSJob j2{w_idx_k, wcath + (size_t)QKVN_ * HID_, wcatl + (size_t)QKVN_ * HID_, HID_, IDXD_};
    TSJob j3{w_wproj, wcath + (size_t)(QKVN_ + IDXD_) * HID_, wcatl + (size_t)(QKVN_ + IDXD_) * HID_, HID_, IDXH_};
    transpose_split_multi<<<dim3(64, 32, 4), blk, 0, stream>>>(j0, j1, j2, j3);
  }
  {
    TBJob j0{w_qb, wqbt, QLR_, H_ * QKD_};
    TBJob j1{w_kvb, wkvbt, KVLR_, H_ * 256};
    TBJob j2{w_o, wot, H_ * VD_, HID_};
    transpose_bf16_multi<<<dim3(64, 32, 3), blk, 0, stream>>>(j0, j1, j2);
  }
  split_f16_k<<<2048, blk, 0, stream>>>(hidden, hidh, hidl, (long)T_ * HID_);
  conv_bf16_k<<<2048, blk, 0, stream>>>(w_kvb, wkvb, (long)KVLR_ * H_ * 256);

  // strict path: fused GEMM -> [qkv | ki | wgt(+bias,scaled)]
  gemm_hl<<<g2(T_, QKVX_, 1), blk, 0, stream>>>(
      hidh, hidl, HID_, wcath, wcatl, HID_, qkvx, QKVX_,
      b_wproj, QKVN_ + IDXD_, 0.015625f, QKVX_, HID_);
  rmsnorm_kernel<<<T_, blk, 0, stream>>>(qkvx, q_a_ln_w, kv_a_ln_w, qcb, qch, qcl, kv_cn);
  rope_kpe_kernel<<<T_, 64, 0, stream>>>(qkvx, kper);
  ki_ln_rope_kernel<<<T_, 128, 0, stream>>>(qkvx, idx_g, idx_b, kih, kil);

  gemm_hl<<<g2(T_, IDXH_ * IDXD_, 1), blk, 0, stream>>>(
      qch, qcl, QLR_, wiqh, wiql, QLR_, qi, IDXH_ * IDXD_,
      nullptr, 1 << 30, 1.f, IDXH_ * IDXD_, QLR_);
  rope_qi_split_kernel<<<T_, blk, 0, stream>>>(qi, qih, qil);

  score_mfma<<<dim3(32, 32), blk, 0, stream>>>(qih, qil, kih, kil,
                                               qkvx + QKVN_ + IDXD_, QKVX_, score);
  topk_kernel<<<T_, blk, 0, stream>>>(score, selidx, selcnt);

  // tolerant path (bf16 MFMA, DMA-staged)
  gemm_t<1><<<g2(T_, H_ * QKD_, 1), blk, 0, stream>>>(qcb, QLR_, 0, wqbt, QLR_, 0, qfb, H_ * QKD_, 0, H_ * QKD_, QLR_);
  rope_q_bf_kernel<<<T_, blk, 0, stream>>>(qfb);
  gemm_t<1><<<g2(T_, 512, H_), blk, 0, stream>>>(qfb, H_ * QKD_, QKD_, wkvb, H_ * 256, 256, qeff, H_ * 512, 512, 512, NOPE_);
  attn_mla_kernel<<<T_, blk, 0, stream>>>(qeff, qfb, kv_cn, kper, selidx, selcnt, Olat);
  gemm_t<1><<<g2(T_, VD_, H_), blk, 0, stream>>>(Olat, H_ * 512, 512, wkvbt + 128 * 512, KVLR_, 256 * 512, attno, H_ * VD_, VD_, VD_, 512);
  gemm_t<0><<<g2(T_, HID_, 1), blk, 0, stream>>>(attno, H_ * VD_, 0, wot, H_ * VD_, 0, d_out, HID_, 0, HID_, H_ * VD_);
}